// Round 17
// baseline (322.623 us; speedup 1.0000x reference)
//
#include <hip/hip_runtime.h>

constexpr int kNL = 16384, kND = 4096, kNM = 2048;
constexpr int kE = 262144;              // 2^18
constexpr int kFEAT = 256, kHID = 64, kOUTF = 128;
constexpr int kITEMS = 4096, kSIZE = 2048;
constexpr int kHB = 16;                 // histogram chunks per index array
constexpr int kZS = 128;                // z row stride (merged 2-type layout)
constexpr int kXIN = kITEMS + kOUTF;    // 4224

typedef unsigned short ushort_t;
typedef unsigned int uint_t;
typedef __attribute__((ext_vector_type(8))) short short8v;
typedef __attribute__((ext_vector_type(4))) float f32x4;

struct EdgePtrs { const int* p[12]; };
struct I6 { int v[6]; };

__device__ inline ushort_t f2bf(float f) {
  unsigned u = __builtin_bit_cast(unsigned, f);
  unsigned r = u + 0x7fffu + ((u >> 16) & 1u);
  return (ushort_t)(r >> 16);
}
__device__ inline float bf2f(ushort_t b) {
  unsigned u = ((unsigned)b) << 16;
  return __builtin_bit_cast(float, u);
}
__device__ inline float bf2f_lo(uint_t v) { return __builtin_bit_cast(float, v << 16); }
__device__ inline float bf2f_hi(uint_t v) { return __builtin_bit_cast(float, v & 0xffff0000u); }

// async global->LDS, 16 B per lane (global_load_lds_dwordx4)
__device__ __forceinline__ void gload16(const ushort_t* g, ushort_t* l) {
  __builtin_amdgcn_global_load_lds(
      (const __attribute__((address_space(1))) void*)g,
      (__attribute__((address_space(3))) void*)l, 16, 0, 0);
}

// bijective XCD swizzle (m204)
__device__ __forceinline__ void xcd_swizzle(int& bx, int& by) {
  int gx = gridDim.x, gy = gridDim.y;
  int nwg = gx * gy;
  int orig = by * gx + bx;
  int q = nwg >> 3, r = nwg & 7;
  int xcd = orig & 7, loc = orig >> 3;
  int s = ((xcd < r) ? xcd * (q + 1) : r * (q + 1) + (xcd - r) * q) + loc;
  by = s % gy;
  bx = s / gy;
}

// ===== hist: standalone (64 KB LDS only here) ==============================
__global__ __launch_bounds__(256) void hist_kernel(EdgePtrs ep, uint_t* __restrict__ part) {
  __shared__ uint_t bins[16384];
  int k = blockIdx.x >> 4, chunk = blockIdx.x & (kHB - 1);
  for (int i = threadIdx.x; i < 16384; i += 256) bins[i] = 0;
  __syncthreads();
  const int* arr = ep.p[k];
  int base = chunk * (kE / kHB);
  for (int i = threadIdx.x; i < kE / kHB; i += 256)
    atomicAdd(&bins[arr[base + i]], 1u);
  __syncthreads();
  uint_t* o = part + ((size_t)blockIdx.x << 14);
  for (int i = threadIdx.x; i < 16384; i += 256) o[i] = bins[i];
}

// ===== prep: converts/transposes ONLY (4.2 KB LDS -> high occupancy) =======
struct PJob { const float* in; ushort_t* out; int A; int B; int C; int kind; int nblk; };
struct PJobs { PJob j[24]; int n; };

__global__ __launch_bounds__(256) void prep_kernel(PJobs jobs) {
  __shared__ float t[32][33];
  int b = blockIdx.x;
  int ji = 0;
  while (ji < jobs.n && b >= jobs.j[ji].nblk) { b -= jobs.j[ji].nblk; ++ji; }
  if (ji >= jobs.n) return;
  PJob jb = jobs.j[ji];
  if (jb.kind == 0) {                       // flat convert, A = n4
    int idx = b * 256 + threadIdx.x;
    if (idx >= jb.A) return;
    float4 v = ((const float4*)jb.in)[idx];
    ushort_t* o = jb.out + (size_t)idx * 4;
    o[0] = f2bf(v.x); o[1] = f2bf(v.y); o[2] = f2bf(v.z); o[3] = f2bf(v.w);
  } else if (jb.kind == 2) {                // strided convert: A=n4, B=rowLen4, C=outStride
    int idx = b * 256 + threadIdx.x;
    if (idx >= jb.A) return;
    float4 v = ((const float4*)jb.in)[idx];
    int row = idx / jb.B, col4 = idx - row * jb.B;
    ushort_t* o = jb.out + (size_t)row * jb.C + (size_t)col4 * 4;
    o[0] = f2bf(v.x); o[1] = f2bf(v.y); o[2] = f2bf(v.z); o[3] = f2bf(v.w);
  } else {                                  // transpose: in [K][N] -> out [N][K]; A=K, B=N
    int K = jb.A, N = jb.B;
    int tpr = N >> 5;
    int n0 = (b % tpr) * 32, k0 = (b / tpr) * 32;
    int tx = threadIdx.x & 31, ty = threadIdx.x >> 5;
#pragma unroll
    for (int i = 0; i < 32; i += 8)
      t[ty + i][tx] = jb.in[(size_t)(k0 + ty + i) * N + n0 + tx];
    __syncthreads();
#pragma unroll
    for (int i = 0; i < 32; i += 8)
      jb.out[(size_t)(n0 + ty + i) * K + k0 + tx] = f2bf(t[tx][ty + i]);
  }
}

// ===== CSR metadata chain (R12-proven: wide grids) =========================
__global__ void reduce_finalize_kernel(const uint_t* __restrict__ part,
                                       uint_t* __restrict__ cnts,
                                       float* __restrict__ degscale) {
  int idx = blockIdx.x * 256 + threadIdx.x;   // grid = 12*16384/256
  int k = idx >> 14, bin = idx & 16383;
  uint_t s = 0;
  for (int c = 0; c < kHB; ++c) s += part[((size_t)(k * kHB + c) << 14) + bin];
  cnts[idx] = s;
  degscale[idx] = rsqrtf((float)max(s, 1u));
}

__global__ __launch_bounds__(1024) void scan_kernel(const uint_t* __restrict__ cnts,
                                                    uint_t* __restrict__ rp_all,
                                                    I6 rpoff, I6 nd) {
  __shared__ uint_t sums[1024];
  int t = blockIdx.x;
  int n = nd.v[t];
  const uint_t* c = cnts + ((size_t)(2 * t + 1) << 14);
  uint_t* rp = rp_all + rpoff.v[t];
  int tid = threadIdx.x;
  int seg = n >> 10;
  uint_t s = 0;
  for (int j = 0; j < seg; ++j) s += c[tid * seg + j];
  sums[tid] = s;
  __syncthreads();
  for (int o = 1; o < 1024; o <<= 1) {
    uint_t v = (tid >= o) ? sums[tid - o] : 0u;
    __syncthreads();
    sums[tid] += v;
    __syncthreads();
  }
  uint_t run = sums[tid] - s;   // exclusive
  for (int j = 0; j < seg; ++j) { rp[tid * seg + j] = run; run += c[tid * seg + j]; }
  if (tid == 1023) rp[n] = run;
}

__global__ void chunkofs_kernel(const uint_t* __restrict__ part,
                                const uint_t* __restrict__ rp_all,
                                I6 rpoff, I6 nd, uint_t* __restrict__ ofs) {
  int idx = blockIdx.x * 256 + threadIdx.x;   // grid = 6*16384/256
  int t = idx >> 14, bin = idx & 16383;
  if (bin >= nd.v[t]) return;
  uint_t run = (rp_all + rpoff.v[t])[bin];
  for (int c = 0; c < kHB; ++c) {
    ofs[((size_t)(t * kHB + c) << 14) + bin] = run;
    run += part[((size_t)((2 * t + 1) * kHB + c) << 14) + bin];
  }
}

__global__ __launch_bounds__(256) void fill_kernel(EdgePtrs ep,
                                                   const uint_t* __restrict__ ofs,
                                                   uint_t* __restrict__ csr_all) {
  __shared__ uint_t cursor[16384];
  int t = blockIdx.x >> 4, chunk = blockIdx.x & (kHB - 1);
  const uint_t* o = ofs + ((size_t)(t * kHB + chunk) << 14);
  for (int i = threadIdx.x; i < 16384; i += 256) cursor[i] = o[i];
  __syncthreads();
  const int* srcp = ep.p[2 * t];
  const int* dstp = ep.p[2 * t + 1];
  int base = chunk * (kE / kHB);
  uint_t* csr = csr_all + (size_t)t * kE;
  for (int i = threadIdx.x; i < kE / kHB; i += 256) {
    int e = base + i;
    int d = dstp[e];
    uint_t pos = atomicAdd(&cursor[d], 1u);
    csr[pos] = (uint_t)srcp[e];
  }
}

// ===== generic bf16 MFMA GEMM, 128x128 tile, BK=64, 2-buffer (R8) ==========
__global__ __launch_bounds__(256) void gemm_bf16_kernel(
    const ushort_t* __restrict__ A, const ushort_t* __restrict__ Bt,
    const float* __restrict__ Cin, void* __restrict__ out, int outBf16,
    int M, int N, int K, int ldb,
    const float* __restrict__ bias, int act,
    int kChunk, float* __restrict__ partOut) {
  __shared__ ushort_t As[2][8192];   // 2 x 16 KB
  __shared__ ushort_t Bs[2][8192];
  int tid = threadIdx.x;
  int wave = tid >> 6, lane = tid & 63;
  int bx = blockIdx.x, by = blockIdx.y;
  xcd_swizzle(bx, by);
  int brow = by * 128, bcol = bx * 128;
  int kStart = partOut ? blockIdx.z * kChunk : 0;
  int kLen = partOut ? kChunk : K;
  int nsteps = kLen >> 6;              // BK = 64

  int rowBase = tid >> 3;              // 0..31
  int u = (tid & 7) ^ (rowBase & 7);
  const ushort_t* gA = A + (size_t)(brow + rowBase) * K + kStart + u * 8;
  const ushort_t* gB = Bt + (size_t)(bcol + rowBase) * ldb + kStart + u * 8;

  int fr = lane & 15, fq = lane >> 4;
  f32x4 acc[2][8] = {};

#define STAGE_G(buf, koff)                                              \
  do {                                                                  \
    _Pragma("unroll")                                                   \
    for (int j = 0; j < 4; ++j) {                                       \
      gload16(gA + (size_t)j * 32 * K + (koff), &As[buf][j * 2048 + tid * 8]);   \
      gload16(gB + (size_t)j * 32 * ldb + (koff), &Bs[buf][j * 2048 + tid * 8]); \
    }                                                                   \
  } while (0)

  STAGE_G(0, 0);
  int cur = 0;
  for (int i = 0; i < nsteps; ++i) {
    __syncthreads();
    if (i + 1 < nsteps) STAGE_G(cur ^ 1, (i + 1) * 64);
#pragma unroll
    for (int kk = 0; kk < 2; ++kk) {
      short8v af[2], bfr[8];
#pragma unroll
      for (int mi = 0; mi < 2; ++mi) {
        int row = wave * 32 + mi * 16 + fr;
        af[mi] = *(const short8v*)(&As[cur][row * 64 + (((kk * 4 + fq) ^ (row & 7)) * 8)]);
      }
#pragma unroll
      for (int ni = 0; ni < 8; ++ni) {
        int row = ni * 16 + fr;
        bfr[ni] = *(const short8v*)(&Bs[cur][row * 64 + (((kk * 4 + fq) ^ (row & 7)) * 8)]);
      }
#pragma unroll
      for (int mi = 0; mi < 2; ++mi)
#pragma unroll
        for (int ni = 0; ni < 8; ++ni)
          acc[mi][ni] = __builtin_amdgcn_mfma_f32_16x16x32_bf16(af[mi], bfr[ni], acc[mi][ni], 0, 0, 0);
    }
    cur ^= 1;
  }
#undef STAGE_G

  if (partOut) {
    float* o = partOut + (size_t)blockIdx.z * M * N;
#pragma unroll
    for (int mi = 0; mi < 2; ++mi)
#pragma unroll
      for (int ni = 0; ni < 8; ++ni)
#pragma unroll
        for (int r = 0; r < 4; ++r) {
          int row = brow + wave * 32 + mi * 16 + fq * 4 + r;
          int col = bcol + ni * 16 + fr;
          o[(size_t)row * N + col] = acc[mi][ni][r];
        }
    return;
  }
#pragma unroll
  for (int mi = 0; mi < 2; ++mi)
#pragma unroll
    for (int ni = 0; ni < 8; ++ni)
#pragma unroll
      for (int r = 0; r < 4; ++r) {
        int row = brow + wave * 32 + mi * 16 + fq * 4 + r;
        int col = bcol + ni * 16 + fr;
        float v = acc[mi][ni][r];
        if (Cin) v += Cin[(size_t)row * N + col];
        if (bias) v += bias[col];
        if (act == 1) v = fmaxf(v, 0.0f);
        else if (act == 2) v = 1.0f / (1.0f + expf(-v));
        if (outBf16) ((ushort_t*)out)[(size_t)row * N + col] = f2bf(v);
        else ((float*)out)[(size_t)row * N + col] = v;
      }
}

// ===== m201-schedule GEMM for f4: BM=256 BN=128 BK=64, 512 thr, 3-buf ======
__global__ __launch_bounds__(512) void gemm256_kernel(
    const ushort_t* __restrict__ A, const ushort_t* __restrict__ Bt,
    float* __restrict__ out, int M, int N, int K,
    const float* __restrict__ bias) {
  __shared__ ushort_t As[3][16384];   // 3 x 32 KB
  __shared__ ushort_t Bs[3][8192];    // 3 x 16 KB
  int tid = threadIdx.x;
  int wave = tid >> 6, lane = tid & 63;
  int bx = blockIdx.x, by = blockIdx.y;
  xcd_swizzle(bx, by);
  int fr = lane & 15, fq = lane >> 4;
  int wm = wave >> 2, wn = wave & 3;

  int rquot = tid >> 3;                // 0..63
  int uslot = (tid & 7) ^ (rquot & 7); // pre-swizzled global slot
  const ushort_t* gA = A + (size_t)(by * 256 + rquot) * K + uslot * 8;
  const ushort_t* gB = Bt + (size_t)(bx * 128 + rquot) * K + uslot * 8;

  f32x4 acc[8][2] = {};
  int nsteps = K >> 6;

#define SG_A(b_, t_, j_) gload16(gA + (size_t)(j_) * 64 * K + (size_t)(t_) * 64, &As[b_][(j_) * 4096 + tid * 8])
#define SG_B(b_, t_, j_) gload16(gB + (size_t)(j_) * 64 * K + (size_t)(t_) * 64, &Bs[b_][(j_) * 4096 + tid * 8])

  SG_A(0, 0, 0); SG_A(0, 0, 1); SG_A(0, 0, 2); SG_A(0, 0, 3); SG_B(0, 0, 0); SG_B(0, 0, 1);
  SG_A(1, 1, 0); SG_A(1, 1, 1); SG_A(1, 1, 2); SG_A(1, 1, 3); SG_B(1, 1, 0); SG_B(1, 1, 1);
  asm volatile("s_waitcnt vmcnt(6)" ::: "memory");
  __builtin_amdgcn_s_barrier();

  short8v bf[2][2];

#define PHASE(p_)                                                            \
  {                                                                          \
    short8v af[4][2];                                                        \
    _Pragma("unroll")                                                        \
    for (int q = 0; q < 4; ++q) {                                            \
      int row = wm * 128 + (4 * (p_) + q) * 16 + fr;                         \
      int base = row * 64;                                                   \
      af[q][0] = *(const short8v*)(&As[b][base + ((fq ^ (row & 7)) * 8)]);   \
      af[q][1] = *(const short8v*)(&As[b][base + (((4 + fq) ^ (row & 7)) * 8)]); \
    }                                                                        \
    if ((p_) == 0) {                                                         \
      _Pragma("unroll")                                                      \
      for (int q = 0; q < 2; ++q) {                                          \
        int row = wn * 32 + q * 16 + fr;                                     \
        int base = row * 64;                                                 \
        bf[q][0] = *(const short8v*)(&Bs[b][base + ((fq ^ (row & 7)) * 8)]); \
        bf[q][1] = *(const short8v*)(&Bs[b][base + (((4 + fq) ^ (row & 7)) * 8)]); \
      }                                                                      \
      if (doStage) { SG_A(sb, t + 2, 0); SG_A(sb, t + 2, 1); SG_A(sb, t + 2, 2); SG_A(sb, t + 2, 3); } \
    } else {                                                                 \
      if (doStage) { SG_B(sb, t + 2, 0); SG_B(sb, t + 2, 1); }               \
      if (t + 2 < nsteps)      asm volatile("s_waitcnt vmcnt(6)" ::: "memory"); \
      else if (t + 1 < nsteps) asm volatile("s_waitcnt vmcnt(0)" ::: "memory"); \
    }                                                                        \
    __builtin_amdgcn_s_barrier();                                            \
    asm volatile("s_waitcnt lgkmcnt(0)" ::: "memory");                       \
    __builtin_amdgcn_s_setprio(1);                                           \
    _Pragma("unroll")                                                        \
    for (int kk = 0; kk < 2; ++kk)                                           \
      _Pragma("unroll")                                                      \
      for (int q = 0; q < 4; ++q)                                            \
        _Pragma("unroll")                                                    \
        for (int ni = 0; ni < 2; ++ni)                                       \
          acc[4 * (p_) + q][ni] = __builtin_amdgcn_mfma_f32_16x16x32_bf16(af[q][kk], bf[ni][kk], acc[4 * (p_) + q][ni], 0, 0, 0); \
    __builtin_amdgcn_s_setprio(0);                                           \
    __builtin_amdgcn_s_barrier();                                            \
  }

  for (int t = 0; t < nsteps; ++t) {
    int b = t % 3, sb = (t + 2) % 3;
    bool doStage = (t + 2 < nsteps);
    PHASE(0);
    PHASE(1);
  }
#undef PHASE
#undef SG_A
#undef SG_B

#pragma unroll
  for (int mi = 0; mi < 8; ++mi)
#pragma unroll
    for (int ni = 0; ni < 2; ++ni)
#pragma unroll
      for (int r = 0; r < 4; ++r) {
        int row = by * 256 + wm * 128 + mi * 16 + fq * 4 + r;
        int col = bx * 128 + wn * 32 + ni * 16 + fr;
        float v = acc[mi][ni][r] + bias[col];
        out[(size_t)row * N + col] = 1.0f / (1.0f + expf(-v));
      }
}

// ===== batched z GEMM: DIRECT no-LDS (R9-proven), 64x64 per wave ===========
// out cols [16*nlo, 16*nhi); waves outside exit. Zero barriers.
struct ZDesc { const ushort_t* A; const ushort_t* Bt; ushort_t* out;
               const float* rs0; const float* rs1; int M; int K; int nlo; int nhi; };
struct ZDescs { ZDesc d[3]; };

__global__ __launch_bounds__(256) void zgemm_batched_kernel(ZDescs ds) {
  ZDesc de = ds.d[blockIdx.z];
  int wave = threadIdx.x >> 6, lane = threadIdx.x & 63;
  int wrow = blockIdx.y * 256 + wave * 64;
  if (wrow >= de.M) return;
  int wcol = blockIdx.x * 64;                // 0 or 64
  int ni0 = wcol >> 4;
  if (ni0 < de.nlo * 1 || ni0 + 4 > de.nhi) {
    if (ni0 < de.nlo || ni0 >= de.nhi) return;
  }
  int K = de.K;
  int fr = lane & 15, fq = lane >> 4;

  const ushort_t* pA = de.A + (size_t)(wrow + fr) * K + fq * 8;
  const ushort_t* pB = de.Bt + (size_t)(wcol + fr) * K + fq * 8;

  f32x4 acc[4][4] = {};
#pragma unroll 2
  for (int k0 = 0; k0 < K; k0 += 32) {
    short8v af[4], bf[4];
#pragma unroll
    for (int i = 0; i < 4; ++i) {
      af[i] = *(const short8v*)(pA + (size_t)i * 16 * K + k0);
      bf[i] = *(const short8v*)(pB + (size_t)i * 16 * K + k0);
    }
#pragma unroll
    for (int mi = 0; mi < 4; ++mi)
#pragma unroll
      for (int ni = 0; ni < 4; ++ni)
        acc[mi][ni] = __builtin_amdgcn_mfma_f32_16x16x32_bf16(af[mi], bf[ni], acc[mi][ni], 0, 0, 0);
  }

  const float* rs = (wcol == 0) ? de.rs0 : de.rs1;
#pragma unroll
  for (int mi = 0; mi < 4; ++mi)
#pragma unroll
    for (int ni = 0; ni < 4; ++ni)
#pragma unroll
      for (int r = 0; r < 4; ++r) {
        int row = wrow + mi * 16 + fq * 4 + r;
        int col = wcol + ni * 16 + fr;
        de.out[(size_t)row * 128 + col] = f2bf(acc[mi][ni][r] * rs[row]);
      }
}

// ===== batched CSR gather: 2 edges per dword load ==========================
struct GDesc { const ushort_t* z0; const uint_t* rp0; const uint_t* cs0; const float* s0;
               const ushort_t* z1; const uint_t* rp1; const uint_t* cs1; const float* s1;
               const float* b0; const float* b1; ushort_t* out; int nd; };
struct GDescs { GDesc d[3]; };

__device__ __forceinline__ void gpair(const ushort_t* __restrict__ z,
                                      const uint_t* __restrict__ cs,
                                      uint_t e, uint_t ee, int h, int cp,
                                      float& ax, float& ay) {
  float x0 = 0, y0 = 0, x1 = 0, y1 = 0, x2 = 0, y2 = 0, x3 = 0, y3 = 0;
  for (; e + 8 <= ee; e += 8) {
    uint_t s0 = cs[e + 0 + h], s1 = cs[e + 2 + h], s2 = cs[e + 4 + h], s3 = cs[e + 6 + h];
    uint_t v0 = *(const uint_t*)(z + (size_t)s0 * kZS + 2 * cp);
    uint_t v1 = *(const uint_t*)(z + (size_t)s1 * kZS + 2 * cp);
    uint_t v2 = *(const uint_t*)(z + (size_t)s2 * kZS + 2 * cp);
    uint_t v3 = *(const uint_t*)(z + (size_t)s3 * kZS + 2 * cp);
    x0 += bf2f_lo(v0); y0 += bf2f_hi(v0);
    x1 += bf2f_lo(v1); y1 += bf2f_hi(v1);
    x2 += bf2f_lo(v2); y2 += bf2f_hi(v2);
    x3 += bf2f_lo(v3); y3 += bf2f_hi(v3);
  }
  for (; e + 2 <= ee; e += 2) {
    uint_t v = *(const uint_t*)(z + (size_t)cs[e + h] * kZS + 2 * cp);
    x0 += bf2f_lo(v); y0 += bf2f_hi(v);
  }
  if (h == 0 && e < ee) {
    uint_t v = *(const uint_t*)(z + (size_t)cs[e] * kZS + 2 * cp);
    x0 += bf2f_lo(v); y0 += bf2f_hi(v);
  }
  ax = (x0 + x1) + (x2 + x3);
  ay = (y0 + y1) + (y2 + y3);
}

__global__ __launch_bounds__(256) void gather_batched_kernel(GDescs ds) {
  GDesc de = ds.d[blockIdx.z];
  int d = blockIdx.x * 4 + (threadIdx.x >> 6);
  if (d >= de.nd) return;
  int lane = threadIdx.x & 63;
  int h = lane >> 5, cp = lane & 31;
  float ax0, ay0, ax1, ay1;
  gpair(de.z0, de.cs0, de.rp0[d], de.rp0[d + 1], h, cp, ax0, ay0);
  gpair(de.z1, de.cs1, de.rp1[d], de.rp1[d + 1], h, cp, ax1, ay1);
  float s0 = de.s0[d], s1 = de.s1[d];
  float vx = ax0 * s0 + ax1 * s1;
  float vy = ay0 * s0 + ay1 * s1;
  vx += __shfl_xor(vx, 32);
  vy += __shfl_xor(vy, 32);
  if (h == 0) {
    int c0 = 2 * cp;
    vx += de.b0[c0] + de.b1[c0];
    vy += de.b0[c0 + 1] + de.b1[c0 + 1];
    uint_t pack = (uint_t)f2bf(vx) | ((uint_t)f2bf(vy) << 16);
    *(uint_t*)(de.out + (size_t)d * 64 + c0) = pack;
  }
}

// ===== layer-3 gather (width 128, d<2048) + L1 norm: 1 dword/edge/lane =====
__device__ __forceinline__ void gone128(const ushort_t* __restrict__ z,
                                        const uint_t* __restrict__ cs,
                                        uint_t e, uint_t ee, int l,
                                        float& ax, float& ay) {
  float x0 = 0, y0 = 0, x1 = 0, y1 = 0, x2 = 0, y2 = 0, x3 = 0, y3 = 0;
  for (; e + 4 <= ee; e += 4) {
    uint_t s0 = cs[e], s1 = cs[e + 1], s2 = cs[e + 2], s3 = cs[e + 3];
    uint_t v0 = *(const uint_t*)(z + (size_t)s0 * 128 + 2 * l);
    uint_t v1 = *(const uint_t*)(z + (size_t)s1 * 128 + 2 * l);
    uint_t v2 = *(const uint_t*)(z + (size_t)s2 * 128 + 2 * l);
    uint_t v3 = *(const uint_t*)(z + (size_t)s3 * 128 + 2 * l);
    x0 += bf2f_lo(v0); y0 += bf2f_hi(v0);
    x1 += bf2f_lo(v1); y1 += bf2f_hi(v1);
    x2 += bf2f_lo(v2); y2 += bf2f_hi(v2);
    x3 += bf2f_lo(v3); y3 += bf2f_hi(v3);
  }
  for (; e < ee; ++e) {
    uint_t v = *(const uint_t*)(z + (size_t)cs[e] * 128 + 2 * l);
    x0 += bf2f_lo(v); y0 += bf2f_hi(v);
  }
  ax = (x0 + x1) + (x2 + x3);
  ay = (y0 + y1) + (y2 + y3);
}

__global__ __launch_bounds__(256) void gather128_l1_kernel(
    const ushort_t* __restrict__ zD, const uint_t* __restrict__ rpD, const uint_t* __restrict__ csD,
    const float* __restrict__ sInD,
    const ushort_t* __restrict__ zM, const uint_t* __restrict__ rpM, const uint_t* __restrict__ csM,
    const float* __restrict__ sInM,
    const float* __restrict__ bD, const float* __restrict__ bM,
    float* __restrict__ emb, ushort_t* __restrict__ embb, int embStride) {
  int d = blockIdx.x * 4 + (threadIdx.x >> 6);
  int l = threadIdx.x & 63;          // covers cols {2l, 2l+1}
  float axD, ayD, axM, ayM;
  gone128(zD, csD, rpD[d], rpD[d + 1], l, axD, ayD);
  gone128(zM, csM, rpM[d], rpM[d + 1], l, axM, ayM);
  float sD = sInD[d], sM = sInM[d];
  int c0 = 2 * l;
  float v0 = axD * sD + axM * sM + bD[c0] + bM[c0];
  float v1 = ayD * sD + ayM * sM + bD[c0 + 1] + bM[c0 + 1];
  float a = fabsf(v0) + fabsf(v1);
#pragma unroll
  for (int o = 32; o > 0; o >>= 1) a += __shfl_xor(a, o);
  float l1 = fmaxf(a, 1e-12f);
  float e0 = v0 / l1, e1 = v1 / l1;
  float2 fe = {e0, e1};
  *(float2*)(emb + (size_t)d * kOUTF + c0) = fe;
  uint_t pack = (uint_t)f2bf(e0) | ((uint_t)f2bf(e1) << 16);
  *(uint_t*)(embb + (size_t)d * embStride + c0) = pack;
}

// ===== split-K reduce with fused bias/act/bf16-out =========================
__global__ void reducek_kernel(const float* __restrict__ P, void* __restrict__ out,
                               int outBf16, int n4, int S, int N,
                               const float* __restrict__ bias, int act) {
  int idx = blockIdx.x * 256 + threadIdx.x;
  if (idx >= n4) return;
  float4 a = ((const float4*)P)[idx];
  for (int s = 1; s < S; ++s) {
    float4 b = ((const float4*)P)[(size_t)s * n4 + idx];
    a.x += b.x; a.y += b.y; a.z += b.z; a.w += b.w;
  }
  float v[4] = {a.x, a.y, a.z, a.w};
  int c0 = (idx * 4) % N;
#pragma unroll
  for (int j = 0; j < 4; ++j) {
    if (bias) v[j] += bias[c0 + j];
    if (act == 1) v[j] = fmaxf(v[j], 0.0f);
    else if (act == 2) v[j] = 1.0f / (1.0f + expf(-v[j]));
  }
  if (outBf16) {
    ushort_t* o = (ushort_t*)out + (size_t)idx * 4;
    o[0] = f2bf(v[0]); o[1] = f2bf(v[1]); o[2] = f2bf(v[2]); o[3] = f2bf(v[3]);
  } else {
    float4 r = {v[0], v[1], v[2], v[3]};
    ((float4*)out)[idx] = r;
  }
}

extern "C" void kernel_launch(void* const* d_in, const int* in_sizes, int n_in,
                              void* d_out, int out_size, void* d_ws, size_t ws_size,
                              hipStream_t stream) {
  const float* h_L = (const float*)d_in[0];
  const float* h_D = (const float*)d_in[1];
  const float* h_M = (const float*)d_in[2];
  const float* Adj = (const float*)d_in[3];
  EdgePtrs ep;
  for (int i = 0; i < 12; ++i) ep.p[i] = (const int*)d_in[4 + i];
  const float* W[3]  = {(const float*)d_in[16], (const float*)d_in[18], (const float*)d_in[20]};
  const float* Bb[3] = {(const float*)d_in[17], (const float*)d_in[19], (const float*)d_in[21]};
  const float* f1_w = (const float*)d_in[22];
  const float* f1_b = (const float*)d_in[23];
  const float* f2_w = (const float*)d_in[24];
  const float* f2_b = (const float*)d_in[25];
  const float* f3_w = (const float*)d_in[26];
  const float* f3_b = (const float*)d_in[27];
  const float* f4_w = (const float*)d_in[28];
  const float* f4_b = (const float*)d_in[29];

  // ---- workspace layout ----
  float* ws = (float*)d_ws;
  size_t off = 0;
  auto allocF = [&](size_t n) { float* p = ws + off; off += (n + 3) & ~(size_t)3; return p; };
  auto allocU = [&](size_t n) { return (uint_t*)allocF(n); };
  auto allocB = [&](size_t n) { return (ushort_t*)allocF((n + 1) / 2); };

  uint_t* part   = allocU((size_t)12 * kHB * 16384);   // 12.6 MB, reused as z bufs
  uint_t* cnts   = allocU((size_t)12 * 16384);
  float*  degscale = allocF((size_t)12 * 16384);
  uint_t* rp_all = allocU(45062 + 2);
  uint_t* ofs    = allocU((size_t)6 * kHB * 16384);
  uint_t* csr    = allocU((size_t)6 * kE);
  ushort_t* hLb  = allocB((size_t)kNL * kFEAT);
  ushort_t* hDb  = allocB((size_t)kND * kFEAT);
  ushort_t* hMb  = allocB((size_t)kNM * kFEAT);
  ushort_t* xin  = allocB((size_t)kSIZE * kXIN);   // [Adj | emb] bf16, stride 4224
  ushort_t* aLb  = allocB((size_t)kNL * kHID);
  ushort_t* aDb  = allocB((size_t)kND * kHID);
  ushort_t* aMb  = allocB((size_t)kNM * kHID);
  ushort_t* WLt  = allocB((size_t)128 * kFEAT);
  ushort_t* WDt  = allocB((size_t)128 * kFEAT);
  ushort_t* WMt  = allocB((size_t)128 * kFEAT);
  ushort_t* WL2t = allocB((size_t)128 * kHID);
  ushort_t* WD2t = allocB((size_t)128 * kHID);
  ushort_t* WM2t = allocB((size_t)128 * kHID);
  ushort_t* W3t1 = allocB((size_t)kOUTF * kHID);
  ushort_t* W3t3 = allocB((size_t)kOUTF * kHID);
  ushort_t* f1t  = allocB((size_t)256 * kXIN);
  ushort_t* f2t  = allocB((size_t)512 * 256);
  ushort_t* f3t  = allocB((size_t)1024 * 512);
  ushort_t* f4t  = allocB((size_t)kITEMS * 1024);
  ushort_t* x1b  = allocB((size_t)kSIZE * 256);
  ushort_t* x2b  = allocB((size_t)kSIZE * 512);
  ushort_t* x3b  = allocB((size_t)kSIZE * 1024);

  // shared split-K partials (f1 S=6: 3.15M, f2 S=4: 4.19M, f3 S=2: 4.19M floats)
  int S1 = 1, S2 = 1, S3 = 1;
  float* partK = nullptr;
  size_t avail = (ws_size / 4 > off) ? ws_size / 4 - off - 64 : 0;
  if (avail >= (size_t)4 * kSIZE * 512 + 16) {
    partK = allocF((size_t)4 * kSIZE * 512);
    S1 = 6; S2 = 4; S3 = 2;
  }

  // z buffers alias `part` (dead after chunkofs/fill)
  ushort_t* zL  = (ushort_t*)part;                       // 16384 x 128
  ushort_t* zD  = zL + (size_t)kNL * kZS;                // 4096 x 128
  ushort_t* zM  = zD + (size_t)kND * kZS;                // 2048 x 128
  ushort_t* zD3 = zM + (size_t)kNM * kZS;                // 4096 x 128
  ushort_t* zM3 = zD3 + (size_t)kND * kZS;               // 2048 x 128

  I6 ndI; const int ndst_[6] = {kND, kNL, kNM, kNL, kNM, kND};
  for (int t = 0; t < 6; ++t) ndI.v[t] = ndst_[t];
  I6 rpo; { int r = 0; for (int t = 0; t < 6; ++t) { rpo.v[t] = r; r += ndst_[t] + 1; } }
  auto dsc = [&](int k) { return degscale + ((size_t)k << 14); };

  // ---- 1) hist (64KB LDS) then prep (4.2KB LDS, high occupancy) ----
  hist_kernel<<<12 * kHB, 256, 0, stream>>>(ep, part);

  PJobs pj; int nj = 0; int totblk = 0;
  auto addCvt = [&](const float* in, ushort_t* out, size_t n) {
    int n4 = (int)(n / 4);
    pj.j[nj] = {in, out, n4, 0, 0, 0, (n4 + 255) / 256}; totblk += pj.j[nj].nblk; ++nj;
  };
  auto addStrided = [&](const float* in, ushort_t* out, size_t n, int rowLen, int stride) {
    int n4 = (int)(n / 4);
    pj.j[nj] = {in, out, n4, rowLen / 4, stride, 2, (n4 + 255) / 256}; totblk += pj.j[nj].nblk; ++nj;
  };
  auto addT = [&](const float* in, ushort_t* out, int K, int N) {
    pj.j[nj] = {in, out, K, N, 0, 1, (N / 32) * (K / 32)}; totblk += pj.j[nj].nblk; ++nj;
  };
  addCvt(h_L, hLb, (size_t)kNL * kFEAT);
  addCvt(h_D, hDb, (size_t)kND * kFEAT);
  addCvt(h_M, hMb, (size_t)kNM * kFEAT);
  addStrided(Adj, xin, (size_t)kSIZE * kITEMS, kITEMS, kXIN);
  addT(W[0] + (size_t)0 * kFEAT * kHID, WLt + (size_t)0 * kFEAT, kFEAT, kHID);
  addT(W[0] + (size_t)2 * kFEAT * kHID, WLt + (size_t)64 * kFEAT, kFEAT, kHID);
  addT(W[0] + (size_t)1 * kFEAT * kHID, WDt + (size_t)0 * kFEAT, kFEAT, kHID);
  addT(W[0] + (size_t)4 * kFEAT * kHID, WDt + (size_t)64 * kFEAT, kFEAT, kHID);
  addT(W[0] + (size_t)3 * kFEAT * kHID, WMt + (size_t)0 * kFEAT, kFEAT, kHID);
  addT(W[0] + (size_t)5 * kFEAT * kHID, WMt + (size_t)64 * kFEAT, kFEAT, kHID);
  addT(W[1] + (size_t)0 * kHID * kHID, WL2t + (size_t)0 * kHID, kHID, kHID);
  addT(W[1] + (size_t)2 * kHID * kHID, WL2t + (size_t)64 * kHID, kHID, kHID);
  addT(W[1] + (size_t)1 * kHID * kHID, WD2t + (size_t)0 * kHID, kHID, kHID);
  addT(W[1] + (size_t)4 * kHID * kHID, WD2t + (size_t)64 * kHID, kHID, kHID);
  addT(W[1] + (size_t)3 * kHID * kHID, WM2t + (size_t)0 * kHID, kHID, kHID);
  addT(W[1] + (size_t)5 * kHID * kHID, WM2t + (size_t)64 * kHID, kHID, kHID);
  addT(W[2] + (size_t)1 * kHID * kOUTF, W3t1, kHID, kOUTF);
  addT(W[2] + (size_t)3 * kHID * kOUTF, W3t3, kHID, kOUTF);
  addT(f1_w, f1t, kXIN, 256);
  addT(f2_w, f2t, 256, 512);
  addT(f3_w, f3t, 512, 1024);
  addT(f4_w, f4t, 1024, kITEMS);
  pj.n = nj;
  prep_kernel<<<totblk, 256, 0, stream>>>(pj);

  // ---- 2) CSR metadata chain + fill ----
  reduce_finalize_kernel<<<12 * 16384 / 256, 256, 0, stream>>>(part, cnts, degscale);
  scan_kernel<<<6, 1024, 0, stream>>>(cnts, rp_all, rpo, ndI);
  chunkofs_kernel<<<6 * 16384 / 256, 256, 0, stream>>>(part, rp_all, rpo, ndI, ofs);
  fill_kernel<<<6 * kHB, 256, 0, stream>>>(ep, ofs, csr);

  // ---- 3) GNN layers 1 & 2 (direct z-GEMMs, no LDS/barriers) ----
  const ushort_t* curb[3] = {hLb, hDb, hMb};
  for (int layer = 0; layer < 2; ++layer) {
    int K = (layer == 0) ? kFEAT : kHID;
    const ushort_t* WtL = (layer == 0) ? WLt : WL2t;
    const ushort_t* WtD = (layer == 0) ? WDt : WD2t;
    const ushort_t* WtM = (layer == 0) ? WMt : WM2t;
    const float* bl = Bb[layer];
    ZDescs zd;
    if (layer == 0) {
      zd.d[0] = {curb[0], WtL, zL, dsc(0), dsc(4),  kNL, K, 0, 8};
      zd.d[1] = {curb[1], WtD, zD, dsc(2), dsc(8),  kND, K, 0, 8};
      zd.d[2] = {curb[2], WtM, zM, dsc(6), dsc(10), kNM, K, 0, 8};
    } else {
      zd.d[0] = {curb[0], WtL, zL, dsc(0), dsc(4),  kNL, K, 0, 8};
      zd.d[1] = {curb[1], WtD, zD, dsc(2), dsc(8),  kND, K, 4, 8};  // only cols 64-127 live
      zd.d[2] = {curb[2], WtM, zM, dsc(6), dsc(10), kNM, K, 4, 8};  // only cols 64-127 live
    }
    zgemm_batched_kernel<<<dim3(2, kNL / 256, 3), 256, 0, stream>>>(zd);
    if (layer == 0) {
      GDescs gd;
      gd.d[0] = {zD, rp_all + rpo.v[1], csr + (size_t)1 * kE, dsc(3),
                 zM, rp_all + rpo.v[3], csr + (size_t)3 * kE, dsc(7),
                 bl + 1 * kHID, bl + 3 * kHID, aLb, kNL};
      gd.d[1] = {zL, rp_all + rpo.v[0], csr + (size_t)0 * kE, dsc(1),
                 zM + 64, rp_all + rpo.v[5], csr + (size_t)5 * kE, dsc(11),
                 bl + 0 * kHID, bl + 5 * kHID, aDb, kND};
      gd.d[2] = {zL + 64, rp_all + rpo.v[2], csr + (size_t)2 * kE, dsc(5),
                 zD + 64, rp_all + rpo.v[4], csr + (size_t)4 * kE, dsc(9),
                 bl + 2 * kHID, bl + 4 * kHID, aMb, kNM};
      gather_batched_kernel<<<dim3(kNL / 4, 1, 3), 256, 0, stream>>>(gd);
    } else {
      GDescs gd;
      gd.d[0] = {zL, rp_all + rpo.v[0], csr + (size_t)0 * kE, dsc(1),
                 zM + 64, rp_all + rpo.v[5], csr + (size_t)5 * kE, dsc(11),
                 bl + 0 * kHID, bl + 5 * kHID, aDb, kND};
      gd.d[1] = {zL + 64, rp_all + rpo.v[2], csr + (size_t)2 * kE, dsc(5),
                 zD + 64, rp_all + rpo.v[4], csr + (size_t)4 * kE, dsc(9),
                 bl + 2 * kHID, bl + 4 * kHID, aMb, kNM};
      gd.d[2] = gd.d[1];
      gather_batched_kernel<<<dim3(kND / 4, 1, 2), 256, 0, stream>>>(gd);
    }
    curb[0] = aLb; curb[1] = aDb; curb[2] = aMb;
  }

  // ---- 4) layer 3 (types 1: D->L, 3: M->L; rows < 2048) + L1 norm ----
  float* emb  = (float*)d_out;
  float* outx = (float*)d_out + (size_t)kSIZE * kOUTF;
  {
    ZDescs zd;
    zd.d[0] = {curb[1], W3t1, zD3, dsc(2), dsc(2), kND, kHID, 0, 8};
    zd.d[1] = {curb[2], W3t3, zM3, dsc(6), dsc(6), kNM, kHID, 0, 8};
    zd.d[2] = zd.d[1];
    zgemm_batched_kernel<<<dim3(2, kND / 256, 2), 256, 0, stream>>>(zd);
    gather128_l1_kernel<<<kSIZE / 4, 256, 0, stream>>>(
        zD3, rp_all + rpo.v[1], csr + (size_t)1 * kE, dsc(3),
        zM3, rp_all + rpo.v[3], csr + (size_t)3 * kE, dsc(7),
        Bb[2] + 1 * kOUTF, Bb[2] + 3 * kOUTF, emb, xin + kITEMS, kXIN);
  }

  // ---- 5) MLP ----
  if (S1 > 1) {
    gemm_bf16_kernel<<<dim3(2, 16, S1), 256, 0, stream>>>(
        xin, f1t, nullptr, nullptr, 0, kSIZE, 256, kXIN, kXIN,
        nullptr, 0, kXIN / S1, partK);
    int n4 = kSIZE * 256 / 4;
    reducek_kernel<<<(n4 + 255) / 256, 256, 0, stream>>>(
        partK, x1b, 1, n4, S1, 256, f1_b, 1);
  } else {
    gemm_bf16_kernel<<<dim3(2, 16, 1), 256, 0, stream>>>(
        xin, f1t, nullptr, x1b, 1, kSIZE, 256, kXIN, kXIN, f1_b, 1, 0, nullptr);
  }
  if (S2 > 1) {
    gemm_bf16_kernel<<<dim3(4, 16, S2), 256, 0, stream>>>(
        x1b, f2t, nullptr, nullptr, 0, kSIZE, 512, 256, 256,
        nullptr, 0, 256 / S2, partK);
    int n4 = kSIZE * 512 / 4;
    reducek_kernel<<<(n4 + 255) / 256, 256, 0, stream>>>(
        partK, x2b, 1, n4, S2, 512, f2_b, 1);
  } else {
    gemm_bf16_kernel<<<dim3(4, 16, 1), 256, 0, stream>>>(
        x1b, f2t, nullptr, x2b, 1, kSIZE, 512, 256, 256, f2_b, 1, 0, nullptr);
  }
  if (S3 > 1) {
    gemm_bf16_kernel<<<dim3(8, 16, S3), 256, 0, stream>>>(
        x2b, f3t, nullptr, nullptr, 0, kSIZE, 1024, 512, 512,
        nullptr, 0, 512 / S3, partK);
    int n4 = kSIZE * 1024 / 4;
    reducek_kernel<<<(n4 + 255) / 256, 256, 0, stream>>>(
        partK, x3b, 1, n4, S3, 1024, f3_b, 1);
  } else {
    gemm_bf16_kernel<<<dim3(8, 16, 1), 256, 0, stream>>>(
        x2b, f3t, nullptr, x3b, 1, kSIZE, 1024, 512, 512, f3_b, 1, 0, nullptr);
  }
  // f4: m201-schedule 256x128 kernel, fused bias+sigmoid, fp32 out
  gemm256_kernel<<<dim3(kITEMS / 128, kSIZE / 256), 512, 0, stream>>>(
      x3b, f4t, outx, kSIZE, kITEMS, 1024, f4_b);
}

// Round 18
// 312.570 us; speedup vs baseline: 1.0322x; 1.0322x over previous
//
#include <hip/hip_runtime.h>

constexpr int kNL = 16384, kND = 4096, kNM = 2048;
constexpr int kE = 262144;              // 2^18
constexpr int kFEAT = 256, kHID = 64, kOUTF = 128;
constexpr int kITEMS = 4096, kSIZE = 2048;
constexpr int kHB = 16;                 // histogram chunks per index array
constexpr int kZS = 128;                // z row stride (merged 2-type layout)
constexpr int kXIN = kITEMS + kOUTF;    // 4224

typedef unsigned short ushort_t;
typedef unsigned int uint_t;
typedef __attribute__((ext_vector_type(8))) short short8v;
typedef __attribute__((ext_vector_type(4))) float f32x4;

struct EdgePtrs { const int* p[12]; };
struct I6 { int v[6]; };

__device__ inline ushort_t f2bf(float f) {
  unsigned u = __builtin_bit_cast(unsigned, f);
  unsigned r = u + 0x7fffu + ((u >> 16) & 1u);
  return (ushort_t)(r >> 16);
}
__device__ inline float bf2f(ushort_t b) {
  unsigned u = ((unsigned)b) << 16;
  return __builtin_bit_cast(float, u);
}
__device__ inline float bf2f_lo(uint_t v) { return __builtin_bit_cast(float, v << 16); }
__device__ inline float bf2f_hi(uint_t v) { return __builtin_bit_cast(float, v & 0xffff0000u); }

// async global->LDS, 16 B per lane (global_load_lds_dwordx4)
__device__ __forceinline__ void gload16(const ushort_t* g, ushort_t* l) {
  __builtin_amdgcn_global_load_lds(
      (const __attribute__((address_space(1))) void*)g,
      (__attribute__((address_space(3))) void*)l, 16, 0, 0);
}

// bijective XCD swizzle (m204)
__device__ __forceinline__ void xcd_swizzle(int& bx, int& by) {
  int gx = gridDim.x, gy = gridDim.y;
  int nwg = gx * gy;
  int orig = by * gx + bx;
  int q = nwg >> 3, r = nwg & 7;
  int xcd = orig & 7, loc = orig >> 3;
  int s = ((xcd < r) ? xcd * (q + 1) : r * (q + 1) + (xcd - r) * q) + loc;
  by = s % gy;
  bx = s / gy;
}

// ===== hist: standalone (64 KB LDS only here) ==============================
__global__ __launch_bounds__(256) void hist_kernel(EdgePtrs ep, uint_t* __restrict__ part) {
  __shared__ uint_t bins[16384];
  int k = blockIdx.x >> 4, chunk = blockIdx.x & (kHB - 1);
  for (int i = threadIdx.x; i < 16384; i += 256) bins[i] = 0;
  __syncthreads();
  const int* arr = ep.p[k];
  int base = chunk * (kE / kHB);
  for (int i = threadIdx.x; i < kE / kHB; i += 256)
    atomicAdd(&bins[arr[base + i]], 1u);
  __syncthreads();
  uint_t* o = part + ((size_t)blockIdx.x << 14);
  for (int i = threadIdx.x; i < 16384; i += 256) o[i] = bins[i];
}

// ===== prep: converts/transposes ONLY (4.2 KB LDS -> high occupancy) =======
struct PJob { const float* in; ushort_t* out; int A; int B; int C; int kind; int nblk; };
struct PJobs { PJob j[24]; int n; };

__global__ __launch_bounds__(256) void prep_kernel(PJobs jobs) {
  __shared__ float t[32][33];
  int b = blockIdx.x;
  int ji = 0;
  while (ji < jobs.n && b >= jobs.j[ji].nblk) { b -= jobs.j[ji].nblk; ++ji; }
  if (ji >= jobs.n) return;
  PJob jb = jobs.j[ji];
  if (jb.kind == 0) {                       // flat convert, A = n4
    int idx = b * 256 + threadIdx.x;
    if (idx >= jb.A) return;
    float4 v = ((const float4*)jb.in)[idx];
    ushort_t* o = jb.out + (size_t)idx * 4;
    o[0] = f2bf(v.x); o[1] = f2bf(v.y); o[2] = f2bf(v.z); o[3] = f2bf(v.w);
  } else if (jb.kind == 2) {                // strided convert: A=n4, B=rowLen4, C=outStride
    int idx = b * 256 + threadIdx.x;
    if (idx >= jb.A) return;
    float4 v = ((const float4*)jb.in)[idx];
    int row = idx / jb.B, col4 = idx - row * jb.B;
    ushort_t* o = jb.out + (size_t)row * jb.C + (size_t)col4 * 4;
    o[0] = f2bf(v.x); o[1] = f2bf(v.y); o[2] = f2bf(v.z); o[3] = f2bf(v.w);
  } else {                                  // transpose: in [K][N] -> out [N][K]; A=K, B=N
    int K = jb.A, N = jb.B;
    int tpr = N >> 5;
    int n0 = (b % tpr) * 32, k0 = (b / tpr) * 32;
    int tx = threadIdx.x & 31, ty = threadIdx.x >> 5;
#pragma unroll
    for (int i = 0; i < 32; i += 8)
      t[ty + i][tx] = jb.in[(size_t)(k0 + ty + i) * N + n0 + tx];
    __syncthreads();
#pragma unroll
    for (int i = 0; i < 32; i += 8)
      jb.out[(size_t)(n0 + ty + i) * K + k0 + tx] = f2bf(t[tx][ty + i]);
  }
}

// ===== CSR metadata chain (R12-proven: wide grids) =========================
__global__ void reduce_finalize_kernel(const uint_t* __restrict__ part,
                                       uint_t* __restrict__ cnts,
                                       float* __restrict__ degscale) {
  int idx = blockIdx.x * 256 + threadIdx.x;   // grid = 12*16384/256
  int k = idx >> 14, bin = idx & 16383;
  uint_t s = 0;
  for (int c = 0; c < kHB; ++c) s += part[((size_t)(k * kHB + c) << 14) + bin];
  cnts[idx] = s;
  degscale[idx] = rsqrtf((float)max(s, 1u));
}

__global__ __launch_bounds__(1024) void scan_kernel(const uint_t* __restrict__ cnts,
                                                    uint_t* __restrict__ rp_all,
                                                    I6 rpoff, I6 nd) {
  __shared__ uint_t sums[1024];
  int t = blockIdx.x;
  int n = nd.v[t];
  const uint_t* c = cnts + ((size_t)(2 * t + 1) << 14);
  uint_t* rp = rp_all + rpoff.v[t];
  int tid = threadIdx.x;
  int seg = n >> 10;
  uint_t s = 0;
  for (int j = 0; j < seg; ++j) s += c[tid * seg + j];
  sums[tid] = s;
  __syncthreads();
  for (int o = 1; o < 1024; o <<= 1) {
    uint_t v = (tid >= o) ? sums[tid - o] : 0u;
    __syncthreads();
    sums[tid] += v;
    __syncthreads();
  }
  uint_t run = sums[tid] - s;   // exclusive
  for (int j = 0; j < seg; ++j) { rp[tid * seg + j] = run; run += c[tid * seg + j]; }
  if (tid == 1023) rp[n] = run;
}

__global__ void chunkofs_kernel(const uint_t* __restrict__ part,
                                const uint_t* __restrict__ rp_all,
                                I6 rpoff, I6 nd, uint_t* __restrict__ ofs) {
  int idx = blockIdx.x * 256 + threadIdx.x;   // grid = 6*16384/256
  int t = idx >> 14, bin = idx & 16383;
  if (bin >= nd.v[t]) return;
  uint_t run = (rp_all + rpoff.v[t])[bin];
  for (int c = 0; c < kHB; ++c) {
    ofs[((size_t)(t * kHB + c) << 14) + bin] = run;
    run += part[((size_t)((2 * t + 1) * kHB + c) << 14) + bin];
  }
}

__global__ __launch_bounds__(256) void fill_kernel(EdgePtrs ep,
                                                   const uint_t* __restrict__ ofs,
                                                   uint_t* __restrict__ csr_all) {
  __shared__ uint_t cursor[16384];
  int t = blockIdx.x >> 4, chunk = blockIdx.x & (kHB - 1);
  const uint_t* o = ofs + ((size_t)(t * kHB + chunk) << 14);
  for (int i = threadIdx.x; i < 16384; i += 256) cursor[i] = o[i];
  __syncthreads();
  const int* srcp = ep.p[2 * t];
  const int* dstp = ep.p[2 * t + 1];
  int base = chunk * (kE / kHB);
  uint_t* csr = csr_all + (size_t)t * kE;
  for (int i = threadIdx.x; i < kE / kHB; i += 256) {
    int e = base + i;
    int d = dstp[e];
    uint_t pos = atomicAdd(&cursor[d], 1u);
    csr[pos] = (uint_t)srcp[e];
  }
}

// ===== generic bf16 MFMA GEMM, 128x128 tile, BK=64, 2-buffer (R8) ==========
__global__ __launch_bounds__(256) void gemm_bf16_kernel(
    const ushort_t* __restrict__ A, const ushort_t* __restrict__ Bt,
    const float* __restrict__ Cin, void* __restrict__ out, int outBf16,
    int M, int N, int K, int ldb,
    const float* __restrict__ bias, int act,
    int kChunk, float* __restrict__ partOut) {
  __shared__ ushort_t As[2][8192];   // 2 x 16 KB
  __shared__ ushort_t Bs[2][8192];
  int tid = threadIdx.x;
  int wave = tid >> 6, lane = tid & 63;
  int bx = blockIdx.x, by = blockIdx.y;
  xcd_swizzle(bx, by);
  int brow = by * 128, bcol = bx * 128;
  int kStart = partOut ? blockIdx.z * kChunk : 0;
  int kLen = partOut ? kChunk : K;
  int nsteps = kLen >> 6;              // BK = 64

  int rowBase = tid >> 3;              // 0..31
  int u = (tid & 7) ^ (rowBase & 7);
  const ushort_t* gA = A + (size_t)(brow + rowBase) * K + kStart + u * 8;
  const ushort_t* gB = Bt + (size_t)(bcol + rowBase) * ldb + kStart + u * 8;

  int fr = lane & 15, fq = lane >> 4;
  f32x4 acc[2][8] = {};

#define STAGE_G(buf, koff)                                              \
  do {                                                                  \
    _Pragma("unroll")                                                   \
    for (int j = 0; j < 4; ++j) {                                       \
      gload16(gA + (size_t)j * 32 * K + (koff), &As[buf][j * 2048 + tid * 8]);   \
      gload16(gB + (size_t)j * 32 * ldb + (koff), &Bs[buf][j * 2048 + tid * 8]); \
    }                                                                   \
  } while (0)

  STAGE_G(0, 0);
  int cur = 0;
  for (int i = 0; i < nsteps; ++i) {
    __syncthreads();
    if (i + 1 < nsteps) STAGE_G(cur ^ 1, (i + 1) * 64);
#pragma unroll
    for (int kk = 0; kk < 2; ++kk) {
      short8v af[2], bfr[8];
#pragma unroll
      for (int mi = 0; mi < 2; ++mi) {
        int row = wave * 32 + mi * 16 + fr;
        af[mi] = *(const short8v*)(&As[cur][row * 64 + (((kk * 4 + fq) ^ (row & 7)) * 8)]);
      }
#pragma unroll
      for (int ni = 0; ni < 8; ++ni) {
        int row = ni * 16 + fr;
        bfr[ni] = *(const short8v*)(&Bs[cur][row * 64 + (((kk * 4 + fq) ^ (row & 7)) * 8)]);
      }
#pragma unroll
      for (int mi = 0; mi < 2; ++mi)
#pragma unroll
        for (int ni = 0; ni < 8; ++ni)
          acc[mi][ni] = __builtin_amdgcn_mfma_f32_16x16x32_bf16(af[mi], bfr[ni], acc[mi][ni], 0, 0, 0);
    }
    cur ^= 1;
  }
#undef STAGE_G

  if (partOut) {
    float* o = partOut + (size_t)blockIdx.z * M * N;
#pragma unroll
    for (int mi = 0; mi < 2; ++mi)
#pragma unroll
      for (int ni = 0; ni < 8; ++ni)
#pragma unroll
        for (int r = 0; r < 4; ++r) {
          int row = brow + wave * 32 + mi * 16 + fq * 4 + r;
          int col = bcol + ni * 16 + fr;
          o[(size_t)row * N + col] = acc[mi][ni][r];
        }
    return;
  }
#pragma unroll
  for (int mi = 0; mi < 2; ++mi)
#pragma unroll
    for (int ni = 0; ni < 8; ++ni)
#pragma unroll
      for (int r = 0; r < 4; ++r) {
        int row = brow + wave * 32 + mi * 16 + fq * 4 + r;
        int col = bcol + ni * 16 + fr;
        float v = acc[mi][ni][r];
        if (Cin) v += Cin[(size_t)row * N + col];
        if (bias) v += bias[col];
        if (act == 1) v = fmaxf(v, 0.0f);
        else if (act == 2) v = 1.0f / (1.0f + expf(-v));
        if (outBf16) ((ushort_t*)out)[(size_t)row * N + col] = f2bf(v);
        else ((float*)out)[(size_t)row * N + col] = v;
      }
}

// ===== m201-schedule GEMM for f4: BM=256 BN=128 BK=64, 512 thr, 3-buf ======
__global__ __launch_bounds__(512) void gemm256_kernel(
    const ushort_t* __restrict__ A, const ushort_t* __restrict__ Bt,
    float* __restrict__ out, int M, int N, int K,
    const float* __restrict__ bias) {
  __shared__ ushort_t As[3][16384];   // 3 x 32 KB
  __shared__ ushort_t Bs[3][8192];    // 3 x 16 KB
  int tid = threadIdx.x;
  int wave = tid >> 6, lane = tid & 63;
  int bx = blockIdx.x, by = blockIdx.y;
  xcd_swizzle(bx, by);
  int fr = lane & 15, fq = lane >> 4;
  int wm = wave >> 2, wn = wave & 3;

  int rquot = tid >> 3;                // 0..63
  int uslot = (tid & 7) ^ (rquot & 7); // pre-swizzled global slot
  const ushort_t* gA = A + (size_t)(by * 256 + rquot) * K + uslot * 8;
  const ushort_t* gB = Bt + (size_t)(bx * 128 + rquot) * K + uslot * 8;

  f32x4 acc[8][2] = {};
  int nsteps = K >> 6;

#define SG_A(b_, t_, j_) gload16(gA + (size_t)(j_) * 64 * K + (size_t)(t_) * 64, &As[b_][(j_) * 4096 + tid * 8])
#define SG_B(b_, t_, j_) gload16(gB + (size_t)(j_) * 64 * K + (size_t)(t_) * 64, &Bs[b_][(j_) * 4096 + tid * 8])

  SG_A(0, 0, 0); SG_A(0, 0, 1); SG_A(0, 0, 2); SG_A(0, 0, 3); SG_B(0, 0, 0); SG_B(0, 0, 1);
  SG_A(1, 1, 0); SG_A(1, 1, 1); SG_A(1, 1, 2); SG_A(1, 1, 3); SG_B(1, 1, 0); SG_B(1, 1, 1);
  asm volatile("s_waitcnt vmcnt(6)" ::: "memory");
  __builtin_amdgcn_s_barrier();

  short8v bf[2][2];

#define PHASE(p_)                                                            \
  {                                                                          \
    short8v af[4][2];                                                        \
    _Pragma("unroll")                                                        \
    for (int q = 0; q < 4; ++q) {                                            \
      int row = wm * 128 + (4 * (p_) + q) * 16 + fr;                         \
      int base = row * 64;                                                   \
      af[q][0] = *(const short8v*)(&As[b][base + ((fq ^ (row & 7)) * 8)]);   \
      af[q][1] = *(const short8v*)(&As[b][base + (((4 + fq) ^ (row & 7)) * 8)]); \
    }                                                                        \
    if ((p_) == 0) {                                                         \
      _Pragma("unroll")                                                      \
      for (int q = 0; q < 2; ++q) {                                          \
        int row = wn * 32 + q * 16 + fr;                                     \
        int base = row * 64;                                                 \
        bf[q][0] = *(const short8v*)(&Bs[b][base + ((fq ^ (row & 7)) * 8)]); \
        bf[q][1] = *(const short8v*)(&Bs[b][base + (((4 + fq) ^ (row & 7)) * 8)]); \
      }                                                                      \
      if (doStage) { SG_A(sb, t + 2, 0); SG_A(sb, t + 2, 1); SG_A(sb, t + 2, 2); SG_A(sb, t + 2, 3); } \
    } else {                                                                 \
      if (doStage) { SG_B(sb, t + 2, 0); SG_B(sb, t + 2, 1); }               \
      if (t + 2 < nsteps)      asm volatile("s_waitcnt vmcnt(6)" ::: "memory"); \
      else if (t + 1 < nsteps) asm volatile("s_waitcnt vmcnt(0)" ::: "memory"); \
    }                                                                        \
    __builtin_amdgcn_s_barrier();                                            \
    asm volatile("s_waitcnt lgkmcnt(0)" ::: "memory");                       \
    __builtin_amdgcn_s_setprio(1);                                           \
    _Pragma("unroll")                                                        \
    for (int kk = 0; kk < 2; ++kk)                                           \
      _Pragma("unroll")                                                      \
      for (int q = 0; q < 4; ++q)                                            \
        _Pragma("unroll")                                                    \
        for (int ni = 0; ni < 2; ++ni)                                       \
          acc[4 * (p_) + q][ni] = __builtin_amdgcn_mfma_f32_16x16x32_bf16(af[q][kk], bf[ni][kk], acc[4 * (p_) + q][ni], 0, 0, 0); \
    __builtin_amdgcn_s_setprio(0);                                           \
    __builtin_amdgcn_s_barrier();                                            \
  }

  for (int t = 0; t < nsteps; ++t) {
    int b = t % 3, sb = (t + 2) % 3;
    bool doStage = (t + 2 < nsteps);
    PHASE(0);
    PHASE(1);
  }
#undef PHASE
#undef SG_A
#undef SG_B

#pragma unroll
  for (int mi = 0; mi < 8; ++mi)
#pragma unroll
    for (int ni = 0; ni < 2; ++ni)
#pragma unroll
      for (int r = 0; r < 4; ++r) {
        int row = by * 256 + wm * 128 + mi * 16 + fq * 4 + r;
        int col = bx * 128 + wn * 32 + ni * 16 + fr;
        float v = acc[mi][ni][r] + bias[col];
        out[(size_t)row * N + col] = 1.0f / (1.0f + expf(-v));
      }
}

// ===== batched z GEMM (R16-proven): N=128, BK=64, 2-buffer LDS =============
struct ZDesc { const ushort_t* A; const ushort_t* Bt; ushort_t* out;
               const float* rs0; const float* rs1; int M; int K; };
struct ZDescs { ZDesc d[3]; };

__global__ __launch_bounds__(256) void zgemm_batched_kernel(ZDescs ds) {
  __shared__ ushort_t As[2][8192];
  __shared__ ushort_t Bs[2][8192];
  ZDesc de = ds.d[blockIdx.z];
  int gy = gridDim.y;
  int yq = gy >> 3;
  int ys = (blockIdx.y & 7) * yq + (blockIdx.y >> 3);
  int brow = ys * 128;
  if (brow >= de.M) return;
  int K = de.K;
  int nsteps = K >> 6;
  if (nsteps == 0) nsteps = 1;
  int kkMax = (K >= 64) ? 2 : 1;
  int tid = threadIdx.x;
  int wave = tid >> 6, lane = tid & 63;

  int rowBase = tid >> 3;
  int u = (tid & 7) ^ (rowBase & 7);
  const ushort_t* gA = de.A + (size_t)(brow + rowBase) * K + u * 8;
  const ushort_t* gB = de.Bt + (size_t)rowBase * K + u * 8;

  int fr = lane & 15, fq = lane >> 4;
  f32x4 acc[2][8] = {};

#define STAGE_Z(buf, koff)                                              \
  do {                                                                  \
    _Pragma("unroll")                                                   \
    for (int j = 0; j < 4; ++j) {                                       \
      gload16(gA + (size_t)j * 32 * K + (koff), &As[buf][j * 2048 + tid * 8]); \
      gload16(gB + (size_t)j * 32 * K + (koff), &Bs[buf][j * 2048 + tid * 8]); \
    }                                                                   \
  } while (0)

  STAGE_Z(0, 0);
  int cur = 0;
  for (int i = 0; i < nsteps; ++i) {
    __syncthreads();
    if (i + 1 < nsteps) STAGE_Z(cur ^ 1, (i + 1) * 64);
#pragma unroll
    for (int kk = 0; kk < 2; ++kk) {
      if (kk >= kkMax) break;
      short8v af[2], bfr[8];
#pragma unroll
      for (int mi = 0; mi < 2; ++mi) {
        int row = wave * 32 + mi * 16 + fr;
        af[mi] = *(const short8v*)(&As[cur][row * 64 + (((kk * 4 + fq) ^ (row & 7)) * 8)]);
      }
#pragma unroll
      for (int ni = 0; ni < 8; ++ni) {
        int row = ni * 16 + fr;
        bfr[ni] = *(const short8v*)(&Bs[cur][row * 64 + (((kk * 4 + fq) ^ (row & 7)) * 8)]);
      }
#pragma unroll
      for (int mi = 0; mi < 2; ++mi)
#pragma unroll
        for (int ni = 0; ni < 8; ++ni)
          acc[mi][ni] = __builtin_amdgcn_mfma_f32_16x16x32_bf16(af[mi], bfr[ni], acc[mi][ni], 0, 0, 0);
    }
    cur ^= 1;
  }
#undef STAGE_Z

#pragma unroll
  for (int mi = 0; mi < 2; ++mi)
#pragma unroll
    for (int ni = 0; ni < 8; ++ni) {
      const float* rs = (ni < 4) ? de.rs0 : de.rs1;
#pragma unroll
      for (int r = 0; r < 4; ++r) {
        int row = brow + wave * 32 + mi * 16 + fq * 4 + r;
        int col = ni * 16 + fr;
        de.out[(size_t)row * 128 + col] = f2bf(acc[mi][ni][r] * rs[row]);
      }
    }
}

// ===== batched CSR gather: 2 edges per dword load ==========================
struct GDesc { const ushort_t* z0; const uint_t* rp0; const uint_t* cs0; const float* s0;
               const ushort_t* z1; const uint_t* rp1; const uint_t* cs1; const float* s1;
               const float* b0; const float* b1; ushort_t* out; int nd; };
struct GDescs { GDesc d[3]; };

__device__ __forceinline__ void gpair(const ushort_t* __restrict__ z,
                                      const uint_t* __restrict__ cs,
                                      uint_t e, uint_t ee, int h, int cp,
                                      float& ax, float& ay) {
  float x0 = 0, y0 = 0, x1 = 0, y1 = 0, x2 = 0, y2 = 0, x3 = 0, y3 = 0;
  for (; e + 8 <= ee; e += 8) {
    uint_t s0 = cs[e + 0 + h], s1 = cs[e + 2 + h], s2 = cs[e + 4 + h], s3 = cs[e + 6 + h];
    uint_t v0 = *(const uint_t*)(z + (size_t)s0 * kZS + 2 * cp);
    uint_t v1 = *(const uint_t*)(z + (size_t)s1 * kZS + 2 * cp);
    uint_t v2 = *(const uint_t*)(z + (size_t)s2 * kZS + 2 * cp);
    uint_t v3 = *(const uint_t*)(z + (size_t)s3 * kZS + 2 * cp);
    x0 += bf2f_lo(v0); y0 += bf2f_hi(v0);
    x1 += bf2f_lo(v1); y1 += bf2f_hi(v1);
    x2 += bf2f_lo(v2); y2 += bf2f_hi(v2);
    x3 += bf2f_lo(v3); y3 += bf2f_hi(v3);
  }
  for (; e + 2 <= ee; e += 2) {
    uint_t v = *(const uint_t*)(z + (size_t)cs[e + h] * kZS + 2 * cp);
    x0 += bf2f_lo(v); y0 += bf2f_hi(v);
  }
  if (h == 0 && e < ee) {
    uint_t v = *(const uint_t*)(z + (size_t)cs[e] * kZS + 2 * cp);
    x0 += bf2f_lo(v); y0 += bf2f_hi(v);
  }
  ax = (x0 + x1) + (x2 + x3);
  ay = (y0 + y1) + (y2 + y3);
}

__global__ __launch_bounds__(256) void gather_batched_kernel(GDescs ds) {
  GDesc de = ds.d[blockIdx.z];
  int d = blockIdx.x * 4 + (threadIdx.x >> 6);
  if (d >= de.nd) return;
  int lane = threadIdx.x & 63;
  int h = lane >> 5, cp = lane & 31;
  float ax0, ay0, ax1, ay1;
  gpair(de.z0, de.cs0, de.rp0[d], de.rp0[d + 1], h, cp, ax0, ay0);
  gpair(de.z1, de.cs1, de.rp1[d], de.rp1[d + 1], h, cp, ax1, ay1);
  float s0 = de.s0[d], s1 = de.s1[d];
  float vx = ax0 * s0 + ax1 * s1;
  float vy = ay0 * s0 + ay1 * s1;
  vx += __shfl_xor(vx, 32);
  vy += __shfl_xor(vy, 32);
  if (h == 0) {
    int c0 = 2 * cp;
    vx += de.b0[c0] + de.b1[c0];
    vy += de.b0[c0 + 1] + de.b1[c0 + 1];
    uint_t pack = (uint_t)f2bf(vx) | ((uint_t)f2bf(vy) << 16);
    *(uint_t*)(de.out + (size_t)d * 64 + c0) = pack;
  }
}

// ===== layer-3 gather (width 128, d<2048) + L1 norm: 1 dword/edge/lane =====
__device__ __forceinline__ void gone128(const ushort_t* __restrict__ z,
                                        const uint_t* __restrict__ cs,
                                        uint_t e, uint_t ee, int l,
                                        float& ax, float& ay) {
  float x0 = 0, y0 = 0, x1 = 0, y1 = 0, x2 = 0, y2 = 0, x3 = 0, y3 = 0;
  for (; e + 4 <= ee; e += 4) {
    uint_t s0 = cs[e], s1 = cs[e + 1], s2 = cs[e + 2], s3 = cs[e + 3];
    uint_t v0 = *(const uint_t*)(z + (size_t)s0 * 128 + 2 * l);
    uint_t v1 = *(const uint_t*)(z + (size_t)s1 * 128 + 2 * l);
    uint_t v2 = *(const uint_t*)(z + (size_t)s2 * 128 + 2 * l);
    uint_t v3 = *(const uint_t*)(z + (size_t)s3 * 128 + 2 * l);
    x0 += bf2f_lo(v0); y0 += bf2f_hi(v0);
    x1 += bf2f_lo(v1); y1 += bf2f_hi(v1);
    x2 += bf2f_lo(v2); y2 += bf2f_hi(v2);
    x3 += bf2f_lo(v3); y3 += bf2f_hi(v3);
  }
  for (; e < ee; ++e) {
    uint_t v = *(const uint_t*)(z + (size_t)cs[e] * 128 + 2 * l);
    x0 += bf2f_lo(v); y0 += bf2f_hi(v);
  }
  ax = (x0 + x1) + (x2 + x3);
  ay = (y0 + y1) + (y2 + y3);
}

__global__ __launch_bounds__(256) void gather128_l1_kernel(
    const ushort_t* __restrict__ zD, const uint_t* __restrict__ rpD, const uint_t* __restrict__ csD,
    const float* __restrict__ sInD,
    const ushort_t* __restrict__ zM, const uint_t* __restrict__ rpM, const uint_t* __restrict__ csM,
    const float* __restrict__ sInM,
    const float* __restrict__ bD, const float* __restrict__ bM,
    float* __restrict__ emb, ushort_t* __restrict__ embb, int embStride) {
  int d = blockIdx.x * 4 + (threadIdx.x >> 6);
  int l = threadIdx.x & 63;          // covers cols {2l, 2l+1}
  float axD, ayD, axM, ayM;
  gone128(zD, csD, rpD[d], rpD[d + 1], l, axD, ayD);
  gone128(zM, csM, rpM[d], rpM[d + 1], l, axM, ayM);
  float sD = sInD[d], sM = sInM[d];
  int c0 = 2 * l;
  float v0 = axD * sD + axM * sM + bD[c0] + bM[c0];
  float v1 = ayD * sD + ayM * sM + bD[c0 + 1] + bM[c0 + 1];
  float a = fabsf(v0) + fabsf(v1);
#pragma unroll
  for (int o = 32; o > 0; o >>= 1) a += __shfl_xor(a, o);
  float l1 = fmaxf(a, 1e-12f);
  float e0 = v0 / l1, e1 = v1 / l1;
  float2 fe = {e0, e1};
  *(float2*)(emb + (size_t)d * kOUTF + c0) = fe;
  uint_t pack = (uint_t)f2bf(e0) | ((uint_t)f2bf(e1) << 16);
  *(uint_t*)(embb + (size_t)d * embStride + c0) = pack;
}

// ===== split-K reduce with fused bias/act/bf16-out =========================
__global__ void reducek_kernel(const float* __restrict__ P, void* __restrict__ out,
                               int outBf16, int n4, int S, int N,
                               const float* __restrict__ bias, int act) {
  int idx = blockIdx.x * 256 + threadIdx.x;
  if (idx >= n4) return;
  float4 a = ((const float4*)P)[idx];
  for (int s = 1; s < S; ++s) {
    float4 b = ((const float4*)P)[(size_t)s * n4 + idx];
    a.x += b.x; a.y += b.y; a.z += b.z; a.w += b.w;
  }
  float v[4] = {a.x, a.y, a.z, a.w};
  int c0 = (idx * 4) % N;
#pragma unroll
  for (int j = 0; j < 4; ++j) {
    if (bias) v[j] += bias[c0 + j];
    if (act == 1) v[j] = fmaxf(v[j], 0.0f);
    else if (act == 2) v[j] = 1.0f / (1.0f + expf(-v[j]));
  }
  if (outBf16) {
    ushort_t* o = (ushort_t*)out + (size_t)idx * 4;
    o[0] = f2bf(v[0]); o[1] = f2bf(v[1]); o[2] = f2bf(v[2]); o[3] = f2bf(v[3]);
  } else {
    float4 r = {v[0], v[1], v[2], v[3]};
    ((float4*)out)[idx] = r;
  }
}

extern "C" void kernel_launch(void* const* d_in, const int* in_sizes, int n_in,
                              void* d_out, int out_size, void* d_ws, size_t ws_size,
                              hipStream_t stream) {
  const float* h_L = (const float*)d_in[0];
  const float* h_D = (const float*)d_in[1];
  const float* h_M = (const float*)d_in[2];
  const float* Adj = (const float*)d_in[3];
  EdgePtrs ep;
  for (int i = 0; i < 12; ++i) ep.p[i] = (const int*)d_in[4 + i];
  const float* W[3]  = {(const float*)d_in[16], (const float*)d_in[18], (const float*)d_in[20]};
  const float* Bb[3] = {(const float*)d_in[17], (const float*)d_in[19], (const float*)d_in[21]};
  const float* f1_w = (const float*)d_in[22];
  const float* f1_b = (const float*)d_in[23];
  const float* f2_w = (const float*)d_in[24];
  const float* f2_b = (const float*)d_in[25];
  const float* f3_w = (const float*)d_in[26];
  const float* f3_b = (const float*)d_in[27];
  const float* f4_w = (const float*)d_in[28];
  const float* f4_b = (const float*)d_in[29];

  // ---- workspace layout ----
  float* ws = (float*)d_ws;
  size_t off = 0;
  auto allocF = [&](size_t n) { float* p = ws + off; off += (n + 3) & ~(size_t)3; return p; };
  auto allocU = [&](size_t n) { return (uint_t*)allocF(n); };
  auto allocB = [&](size_t n) { return (ushort_t*)allocF((n + 1) / 2); };

  uint_t* part   = allocU((size_t)12 * kHB * 16384);   // 12.6 MB, reused as z bufs
  uint_t* cnts   = allocU((size_t)12 * 16384);
  float*  degscale = allocF((size_t)12 * 16384);
  uint_t* rp_all = allocU(45062 + 2);
  uint_t* ofs    = allocU((size_t)6 * kHB * 16384);
  uint_t* csr    = allocU((size_t)6 * kE);
  ushort_t* hLb  = allocB((size_t)kNL * kFEAT);
  ushort_t* hDb  = allocB((size_t)kND * kFEAT);
  ushort_t* hMb  = allocB((size_t)kNM * kFEAT);
  ushort_t* xin  = allocB((size_t)kSIZE * kXIN);   // [Adj | emb] bf16, stride 4224
  ushort_t* aLb  = allocB((size_t)kNL * kHID);
  ushort_t* aDb  = allocB((size_t)kND * kHID);
  ushort_t* aMb  = allocB((size_t)kNM * kHID);
  ushort_t* WLt  = allocB((size_t)128 * kFEAT);
  ushort_t* WDt  = allocB((size_t)128 * kFEAT);
  ushort_t* WMt  = allocB((size_t)128 * kFEAT);
  ushort_t* WL2t = allocB((size_t)128 * kHID);
  ushort_t* WD2t = allocB((size_t)128 * kHID);
  ushort_t* WM2t = allocB((size_t)128 * kHID);
  ushort_t* W3t1 = allocB((size_t)kOUTF * kHID);
  ushort_t* W3t3 = allocB((size_t)kOUTF * kHID);
  ushort_t* f1t  = allocB((size_t)256 * kXIN);
  ushort_t* f2t  = allocB((size_t)512 * 256);
  ushort_t* f3t  = allocB((size_t)1024 * 512);
  ushort_t* f4t  = allocB((size_t)kITEMS * 1024);
  ushort_t* x1b  = allocB((size_t)kSIZE * 256);
  ushort_t* x2b  = allocB((size_t)kSIZE * 512);
  ushort_t* x3b  = allocB((size_t)kSIZE * 1024);

  // shared split-K partials (f1 S=6: 3.15M, f2 S=4: 4.19M, f3 S=2: 4.19M floats)
  int S1 = 1, S2 = 1, S3 = 1;
  float* partK = nullptr;
  size_t avail = (ws_size / 4 > off) ? ws_size / 4 - off - 64 : 0;
  if (avail >= (size_t)4 * kSIZE * 512 + 16) {
    partK = allocF((size_t)4 * kSIZE * 512);
    S1 = 6; S2 = 4; S3 = 2;
  }

  // z buffers alias `part` (dead after chunkofs/fill)
  ushort_t* zL  = (ushort_t*)part;                       // 16384 x 128
  ushort_t* zD  = zL + (size_t)kNL * kZS;                // 4096 x 128
  ushort_t* zM  = zD + (size_t)kND * kZS;                // 2048 x 128
  ushort_t* zD3 = zM + (size_t)kNM * kZS;                // 4096 x 128
  ushort_t* zM3 = zD3 + (size_t)kND * kZS;               // 2048 x 128

  I6 ndI; const int ndst_[6] = {kND, kNL, kNM, kNL, kNM, kND};
  for (int t = 0; t < 6; ++t) ndI.v[t] = ndst_[t];
  I6 rpo; { int r = 0; for (int t = 0; t < 6; ++t) { rpo.v[t] = r; r += ndst_[t] + 1; } }
  auto dsc = [&](int k) { return degscale + ((size_t)k << 14); };

  // ---- 1) hist (64KB LDS) then prep (4.2KB LDS, high occupancy) ----
  hist_kernel<<<12 * kHB, 256, 0, stream>>>(ep, part);

  PJobs pj; int nj = 0; int totblk = 0;
  auto addCvt = [&](const float* in, ushort_t* out, size_t n) {
    int n4 = (int)(n / 4);
    pj.j[nj] = {in, out, n4, 0, 0, 0, (n4 + 255) / 256}; totblk += pj.j[nj].nblk; ++nj;
  };
  auto addStrided = [&](const float* in, ushort_t* out, size_t n, int rowLen, int stride) {
    int n4 = (int)(n / 4);
    pj.j[nj] = {in, out, n4, rowLen / 4, stride, 2, (n4 + 255) / 256}; totblk += pj.j[nj].nblk; ++nj;
  };
  auto addT = [&](const float* in, ushort_t* out, int K, int N) {
    pj.j[nj] = {in, out, K, N, 0, 1, (N / 32) * (K / 32)}; totblk += pj.j[nj].nblk; ++nj;
  };
  addCvt(h_L, hLb, (size_t)kNL * kFEAT);
  addCvt(h_D, hDb, (size_t)kND * kFEAT);
  addCvt(h_M, hMb, (size_t)kNM * kFEAT);
  addStrided(Adj, xin, (size_t)kSIZE * kITEMS, kITEMS, kXIN);
  addT(W[0] + (size_t)0 * kFEAT * kHID, WLt + (size_t)0 * kFEAT, kFEAT, kHID);
  addT(W[0] + (size_t)2 * kFEAT * kHID, WLt + (size_t)64 * kFEAT, kFEAT, kHID);
  addT(W[0] + (size_t)1 * kFEAT * kHID, WDt + (size_t)0 * kFEAT, kFEAT, kHID);
  addT(W[0] + (size_t)4 * kFEAT * kHID, WDt + (size_t)64 * kFEAT, kFEAT, kHID);
  addT(W[0] + (size_t)3 * kFEAT * kHID, WMt + (size_t)0 * kFEAT, kFEAT, kHID);
  addT(W[0] + (size_t)5 * kFEAT * kHID, WMt + (size_t)64 * kFEAT, kFEAT, kHID);
  addT(W[1] + (size_t)0 * kHID * kHID, WL2t + (size_t)0 * kHID, kHID, kHID);
  addT(W[1] + (size_t)2 * kHID * kHID, WL2t + (size_t)64 * kHID, kHID, kHID);
  addT(W[1] + (size_t)1 * kHID * kHID, WD2t + (size_t)0 * kHID, kHID, kHID);
  addT(W[1] + (size_t)4 * kHID * kHID, WD2t + (size_t)64 * kHID, kHID, kHID);
  addT(W[1] + (size_t)3 * kHID * kHID, WM2t + (size_t)0 * kHID, kHID, kHID);
  addT(W[1] + (size_t)5 * kHID * kHID, WM2t + (size_t)64 * kHID, kHID, kHID);
  addT(W[2] + (size_t)1 * kHID * kOUTF, W3t1, kHID, kOUTF);
  addT(W[2] + (size_t)3 * kHID * kOUTF, W3t3, kHID, kOUTF);
  addT(f1_w, f1t, kXIN, 256);
  addT(f2_w, f2t, 256, 512);
  addT(f3_w, f3t, 512, 1024);
  addT(f4_w, f4t, 1024, kITEMS);
  pj.n = nj;
  prep_kernel<<<totblk, 256, 0, stream>>>(pj);

  // ---- 2) CSR metadata chain + fill ----
  reduce_finalize_kernel<<<12 * 16384 / 256, 256, 0, stream>>>(part, cnts, degscale);
  scan_kernel<<<6, 1024, 0, stream>>>(cnts, rp_all, rpo, ndI);
  chunkofs_kernel<<<6 * 16384 / 256, 256, 0, stream>>>(part, rp_all, rpo, ndI, ofs);
  fill_kernel<<<6 * kHB, 256, 0, stream>>>(ep, ofs, csr);

  // ---- 3) GNN layers 1 & 2 ----
  const ushort_t* curb[3] = {hLb, hDb, hMb};
  for (int layer = 0; layer < 2; ++layer) {
    int K = (layer == 0) ? kFEAT : kHID;
    const ushort_t* WtL = (layer == 0) ? WLt : WL2t;
    const ushort_t* WtD = (layer == 0) ? WDt : WD2t;
    const ushort_t* WtM = (layer == 0) ? WMt : WM2t;
    const float* bl = Bb[layer];
    ZDescs zd;
    zd.d[0] = {curb[0], WtL, zL, dsc(0), dsc(4),  kNL, K};
    zd.d[1] = {curb[1], WtD, zD, dsc(2), dsc(8),  kND, K};
    zd.d[2] = {curb[2], WtM, zM, dsc(6), dsc(10), kNM, K};
    zgemm_batched_kernel<<<dim3(1, kNL / 128, 3), 256, 0, stream>>>(zd);
    if (layer == 0) {
      GDescs gd;
      gd.d[0] = {zD, rp_all + rpo.v[1], csr + (size_t)1 * kE, dsc(3),
                 zM, rp_all + rpo.v[3], csr + (size_t)3 * kE, dsc(7),
                 bl + 1 * kHID, bl + 3 * kHID, aLb, kNL};
      gd.d[1] = {zL, rp_all + rpo.v[0], csr + (size_t)0 * kE, dsc(1),
                 zM + 64, rp_all + rpo.v[5], csr + (size_t)5 * kE, dsc(11),
                 bl + 0 * kHID, bl + 5 * kHID, aDb, kND};
      gd.d[2] = {zL + 64, rp_all + rpo.v[2], csr + (size_t)2 * kE, dsc(5),
                 zD + 64, rp_all + rpo.v[4], csr + (size_t)4 * kE, dsc(9),
                 bl + 2 * kHID, bl + 4 * kHID, aMb, kNM};
      gather_batched_kernel<<<dim3(kNL / 4, 1, 3), 256, 0, stream>>>(gd);
    } else {
      // layer-3 consumes only aDb/aMb -> skip dead aLb gather (70% of work)
      GDescs gd;
      gd.d[0] = {zL, rp_all + rpo.v[0], csr + (size_t)0 * kE, dsc(1),
                 zM + 64, rp_all + rpo.v[5], csr + (size_t)5 * kE, dsc(11),
                 bl + 0 * kHID, bl + 5 * kHID, aDb, kND};
      gd.d[1] = {zL + 64, rp_all + rpo.v[2], csr + (size_t)2 * kE, dsc(5),
                 zD + 64, rp_all + rpo.v[4], csr + (size_t)4 * kE, dsc(9),
                 bl + 2 * kHID, bl + 4 * kHID, aMb, kNM};
      gd.d[2] = gd.d[1];
      gather_batched_kernel<<<dim3(kND / 4, 1, 2), 256, 0, stream>>>(gd);
    }
    curb[0] = aLb; curb[1] = aDb; curb[2] = aMb;
  }

  // ---- 4) layer 3 (types 1: D->L, 3: M->L; rows < 2048) + L1 norm ----
  float* emb  = (float*)d_out;
  float* outx = (float*)d_out + (size_t)kSIZE * kOUTF;
  {
    ZDescs zd;
    zd.d[0] = {curb[1], W3t1, zD3, dsc(2), dsc(2), kND, kHID};
    zd.d[1] = {curb[2], W3t3, zM3, dsc(6), dsc(6), kNM, kHID};
    zd.d[2] = zd.d[1];
    zgemm_batched_kernel<<<dim3(1, kND / 128, 2), 256, 0, stream>>>(zd);
    gather128_l1_kernel<<<kSIZE / 4, 256, 0, stream>>>(
        zD3, rp_all + rpo.v[1], csr + (size_t)1 * kE, dsc(3),
        zM3, rp_all + rpo.v[3], csr + (size_t)3 * kE, dsc(7),
        Bb[2] + 1 * kOUTF, Bb[2] + 3 * kOUTF, emb, xin + kITEMS, kXIN);
  }

  // ---- 5) MLP ----
  if (S1 > 1) {
    gemm_bf16_kernel<<<dim3(2, 16, S1), 256, 0, stream>>>(
        xin, f1t, nullptr, nullptr, 0, kSIZE, 256, kXIN, kXIN,
        nullptr, 0, kXIN / S1, partK);
    int n4 = kSIZE * 256 / 4;
    reducek_kernel<<<(n4 + 255) / 256, 256, 0, stream>>>(
        partK, x1b, 1, n4, S1, 256, f1_b, 1);
  } else {
    gemm_bf16_kernel<<<dim3(2, 16, 1), 256, 0, stream>>>(
        xin, f1t, nullptr, x1b, 1, kSIZE, 256, kXIN, kXIN, f1_b, 1, 0, nullptr);
  }
  if (S2 > 1) {
    gemm_bf16_kernel<<<dim3(4, 16, S2), 256, 0, stream>>>(
        x1b, f2t, nullptr, nullptr, 0, kSIZE, 512, 256, 256,
        nullptr, 0, 256 / S2, partK);
    int n4 = kSIZE * 512 / 4;
    reducek_kernel<<<(n4 + 255) / 256, 256, 0, stream>>>(
        partK, x2b, 1, n4, S2, 512, f2_b, 1);
  } else {
    gemm_bf16_kernel<<<dim3(4, 16, 1), 256, 0, stream>>>(
        x1b, f2t, nullptr, x2b, 1, kSIZE, 512, 256, 256, f2_b, 1, 0, nullptr);
  }
  if (S3 > 1) {
    gemm_bf16_kernel<<<dim3(8, 16, S3), 256, 0, stream>>>(
        x2b, f3t, nullptr, nullptr, 0, kSIZE, 1024, 512, 512,
        nullptr, 0, 512 / S3, partK);
    int n4 = kSIZE * 1024 / 4;
    reducek_kernel<<<(n4 + 255) / 256, 256, 0, stream>>>(
        partK, x3b, 1, n4, S3, 1024, f3_b, 1);
  } else {
    gemm_bf16_kernel<<<dim3(8, 16, 1), 256, 0, stream>>>(
        x2b, f3t, nullptr, x3b, 1, kSIZE, 1024, 512, 512, f3_b, 1, 0, nullptr);
  }
  // f4: m201-schedule 256x128 kernel, fused bias+sigmoid, fp32 out
  gemm256_kernel<<<dim3(kITEMS / 128, kSIZE / 256), 512, 0, stream>>>(
      x3b, f4t, outx, kSIZE, kITEMS, 1024, f4_b);
}

// Round 19
// 310.609 us; speedup vs baseline: 1.0387x; 1.0063x over previous
//
#include <hip/hip_runtime.h>

constexpr int kNL = 16384, kND = 4096, kNM = 2048;
constexpr int kE = 262144;              // 2^18
constexpr int kFEAT = 256, kHID = 64, kOUTF = 128;
constexpr int kITEMS = 4096, kSIZE = 2048;
constexpr int kHB = 16;                 // histogram chunks per index array
constexpr int kZS = 128;                // z row stride (merged 2-type layout)
constexpr int kXIN = kITEMS + kOUTF;    // 4224

typedef unsigned short ushort_t;
typedef unsigned int uint_t;
typedef __attribute__((ext_vector_type(8))) short short8v;
typedef __attribute__((ext_vector_type(4))) float f32x4;

struct EdgePtrs { const int* p[12]; };
struct I6 { int v[6]; };

__device__ inline ushort_t f2bf(float f) {
  unsigned u = __builtin_bit_cast(unsigned, f);
  unsigned r = u + 0x7fffu + ((u >> 16) & 1u);
  return (ushort_t)(r >> 16);
}
__device__ inline float bf2f(ushort_t b) {
  unsigned u = ((unsigned)b) << 16;
  return __builtin_bit_cast(float, u);
}
__device__ inline float bf2f_lo(uint_t v) { return __builtin_bit_cast(float, v << 16); }
__device__ inline float bf2f_hi(uint_t v) { return __builtin_bit_cast(float, v & 0xffff0000u); }

// async global->LDS, 16 B per lane (global_load_lds_dwordx4)
__device__ __forceinline__ void gload16(const ushort_t* g, ushort_t* l) {
  __builtin_amdgcn_global_load_lds(
      (const __attribute__((address_space(1))) void*)g,
      (__attribute__((address_space(3))) void*)l, 16, 0, 0);
}

// bijective XCD swizzle (m204)
__device__ __forceinline__ void xcd_swizzle(int& bx, int& by) {
  int gx = gridDim.x, gy = gridDim.y;
  int nwg = gx * gy;
  int orig = by * gx + bx;
  int q = nwg >> 3, r = nwg & 7;
  int xcd = orig & 7, loc = orig >> 3;
  int s = ((xcd < r) ? xcd * (q + 1) : r * (q + 1) + (xcd - r) * q) + loc;
  by = s % gy;
  bx = s / gy;
}

// ===== hist: standalone (64 KB LDS only here) ==============================
__global__ __launch_bounds__(256) void hist_kernel(EdgePtrs ep, uint_t* __restrict__ part) {
  __shared__ uint_t bins[16384];
  int k = blockIdx.x >> 4, chunk = blockIdx.x & (kHB - 1);
  for (int i = threadIdx.x; i < 16384; i += 256) bins[i] = 0;
  __syncthreads();
  const int* arr = ep.p[k];
  int base = chunk * (kE / kHB);
  for (int i = threadIdx.x; i < kE / kHB; i += 256)
    atomicAdd(&bins[arr[base + i]], 1u);
  __syncthreads();
  uint_t* o = part + ((size_t)blockIdx.x << 14);
  for (int i = threadIdx.x; i < 16384; i += 256) o[i] = bins[i];
}

// ===== prep: converts/transposes ONLY (4.2 KB LDS -> high occupancy) =======
struct PJob { const float* in; ushort_t* out; int A; int B; int C; int kind; int nblk; };
struct PJobs { PJob j[24]; int n; };

__global__ __launch_bounds__(256) void prep_kernel(PJobs jobs) {
  __shared__ float t[32][33];
  int b = blockIdx.x;
  int ji = 0;
  while (ji < jobs.n && b >= jobs.j[ji].nblk) { b -= jobs.j[ji].nblk; ++ji; }
  if (ji >= jobs.n) return;
  PJob jb = jobs.j[ji];
  if (jb.kind == 0) {                       // flat convert, A = n4
    int idx = b * 256 + threadIdx.x;
    if (idx >= jb.A) return;
    float4 v = ((const float4*)jb.in)[idx];
    ushort_t* o = jb.out + (size_t)idx * 4;
    o[0] = f2bf(v.x); o[1] = f2bf(v.y); o[2] = f2bf(v.z); o[3] = f2bf(v.w);
  } else if (jb.kind == 2) {                // strided convert: A=n4, B=rowLen4, C=outStride
    int idx = b * 256 + threadIdx.x;
    if (idx >= jb.A) return;
    float4 v = ((const float4*)jb.in)[idx];
    int row = idx / jb.B, col4 = idx - row * jb.B;
    ushort_t* o = jb.out + (size_t)row * jb.C + (size_t)col4 * 4;
    o[0] = f2bf(v.x); o[1] = f2bf(v.y); o[2] = f2bf(v.z); o[3] = f2bf(v.w);
  } else {                                  // transpose: in [K][N] -> out [N][K]; A=K, B=N
    int K = jb.A, N = jb.B;
    int tpr = N >> 5;
    int n0 = (b % tpr) * 32, k0 = (b / tpr) * 32;
    int tx = threadIdx.x & 31, ty = threadIdx.x >> 5;
#pragma unroll
    for (int i = 0; i < 32; i += 8)
      t[ty + i][tx] = jb.in[(size_t)(k0 + ty + i) * N + n0 + tx];
    __syncthreads();
#pragma unroll
    for (int i = 0; i < 32; i += 8)
      jb.out[(size_t)(n0 + ty + i) * K + k0 + tx] = f2bf(t[tx][ty + i]);
  }
}

// ===== CSR metadata chain (R12-proven: wide grids) =========================
__global__ void reduce_finalize_kernel(const uint_t* __restrict__ part,
                                       uint_t* __restrict__ cnts,
                                       float* __restrict__ degscale) {
  int idx = blockIdx.x * 256 + threadIdx.x;   // grid = 12*16384/256
  int k = idx >> 14, bin = idx & 16383;
  uint_t s = 0;
  for (int c = 0; c < kHB; ++c) s += part[((size_t)(k * kHB + c) << 14) + bin];
  cnts[idx] = s;
  degscale[idx] = rsqrtf((float)max(s, 1u));
}

__global__ __launch_bounds__(1024) void scan_kernel(const uint_t* __restrict__ cnts,
                                                    uint_t* __restrict__ rp_all,
                                                    I6 rpoff, I6 nd) {
  __shared__ uint_t sums[1024];
  int t = blockIdx.x;
  int n = nd.v[t];
  const uint_t* c = cnts + ((size_t)(2 * t + 1) << 14);
  uint_t* rp = rp_all + rpoff.v[t];
  int tid = threadIdx.x;
  int seg = n >> 10;
  uint_t s = 0;
  for (int j = 0; j < seg; ++j) s += c[tid * seg + j];
  sums[tid] = s;
  __syncthreads();
  for (int o = 1; o < 1024; o <<= 1) {
    uint_t v = (tid >= o) ? sums[tid - o] : 0u;
    __syncthreads();
    sums[tid] += v;
    __syncthreads();
  }
  uint_t run = sums[tid] - s;   // exclusive
  for (int j = 0; j < seg; ++j) { rp[tid * seg + j] = run; run += c[tid * seg + j]; }
  if (tid == 1023) rp[n] = run;
}

__global__ void chunkofs_kernel(const uint_t* __restrict__ part,
                                const uint_t* __restrict__ rp_all,
                                I6 rpoff, I6 nd, uint_t* __restrict__ ofs) {
  int idx = blockIdx.x * 256 + threadIdx.x;   // grid = 6*16384/256
  int t = idx >> 14, bin = idx & 16383;
  if (bin >= nd.v[t]) return;
  uint_t run = (rp_all + rpoff.v[t])[bin];
  for (int c = 0; c < kHB; ++c) {
    ofs[((size_t)(t * kHB + c) << 14) + bin] = run;
    run += part[((size_t)((2 * t + 1) * kHB + c) << 14) + bin];
  }
}

__global__ __launch_bounds__(256) void fill_kernel(EdgePtrs ep,
                                                   const uint_t* __restrict__ ofs,
                                                   ushort_t* __restrict__ csr_all) {
  __shared__ uint_t cursor[16384];
  int t = blockIdx.x >> 4, chunk = blockIdx.x & (kHB - 1);
  const uint_t* o = ofs + ((size_t)(t * kHB + chunk) << 14);
  for (int i = threadIdx.x; i < 16384; i += 256) cursor[i] = o[i];
  __syncthreads();
  const int* srcp = ep.p[2 * t];
  const int* dstp = ep.p[2 * t + 1];
  int base = chunk * (kE / kHB);
  ushort_t* csr = csr_all + (size_t)t * kE;
  for (int i = threadIdx.x; i < kE / kHB; i += 256) {
    int e = base + i;
    int d = dstp[e];
    uint_t pos = atomicAdd(&cursor[d], 1u);
    csr[pos] = (ushort_t)srcp[e];
  }
}

// ===== generic bf16 MFMA GEMM, 128x128 tile, BK=64, 2-buffer (R8) ==========
__global__ __launch_bounds__(256) void gemm_bf16_kernel(
    const ushort_t* __restrict__ A, const ushort_t* __restrict__ Bt,
    const float* __restrict__ Cin, void* __restrict__ out, int outBf16,
    int M, int N, int K, int ldb,
    const float* __restrict__ bias, int act,
    int kChunk, float* __restrict__ partOut) {
  __shared__ ushort_t As[2][8192];   // 2 x 16 KB
  __shared__ ushort_t Bs[2][8192];
  int tid = threadIdx.x;
  int wave = tid >> 6, lane = tid & 63;
  int bx = blockIdx.x, by = blockIdx.y;
  xcd_swizzle(bx, by);
  int brow = by * 128, bcol = bx * 128;
  int kStart = partOut ? blockIdx.z * kChunk : 0;
  int kLen = partOut ? kChunk : K;
  int nsteps = kLen >> 6;              // BK = 64

  int rowBase = tid >> 3;              // 0..31
  int u = (tid & 7) ^ (rowBase & 7);
  const ushort_t* gA = A + (size_t)(brow + rowBase) * K + kStart + u * 8;
  const ushort_t* gB = Bt + (size_t)(bcol + rowBase) * ldb + kStart + u * 8;

  int fr = lane & 15, fq = lane >> 4;
  f32x4 acc[2][8] = {};

#define STAGE_G(buf, koff)                                              \
  do {                                                                  \
    _Pragma("unroll")                                                   \
    for (int j = 0; j < 4; ++j) {                                       \
      gload16(gA + (size_t)j * 32 * K + (koff), &As[buf][j * 2048 + tid * 8]);   \
      gload16(gB + (size_t)j * 32 * ldb + (koff), &Bs[buf][j * 2048 + tid * 8]); \
    }                                                                   \
  } while (0)

  STAGE_G(0, 0);
  int cur = 0;
  for (int i = 0; i < nsteps; ++i) {
    __syncthreads();
    if (i + 1 < nsteps) STAGE_G(cur ^ 1, (i + 1) * 64);
#pragma unroll
    for (int kk = 0; kk < 2; ++kk) {
      short8v af[2], bfr[8];
#pragma unroll
      for (int mi = 0; mi < 2; ++mi) {
        int row = wave * 32 + mi * 16 + fr;
        af[mi] = *(const short8v*)(&As[cur][row * 64 + (((kk * 4 + fq) ^ (row & 7)) * 8)]);
      }
#pragma unroll
      for (int ni = 0; ni < 8; ++ni) {
        int row = ni * 16 + fr;
        bfr[ni] = *(const short8v*)(&Bs[cur][row * 64 + (((kk * 4 + fq) ^ (row & 7)) * 8)]);
      }
#pragma unroll
      for (int mi = 0; mi < 2; ++mi)
#pragma unroll
        for (int ni = 0; ni < 8; ++ni)
          acc[mi][ni] = __builtin_amdgcn_mfma_f32_16x16x32_bf16(af[mi], bfr[ni], acc[mi][ni], 0, 0, 0);
    }
    cur ^= 1;
  }
#undef STAGE_G

  if (partOut) {
    float* o = partOut + (size_t)blockIdx.z * M * N;
#pragma unroll
    for (int mi = 0; mi < 2; ++mi)
#pragma unroll
      for (int ni = 0; ni < 8; ++ni)
#pragma unroll
        for (int r = 0; r < 4; ++r) {
          int row = brow + wave * 32 + mi * 16 + fq * 4 + r;
          int col = bcol + ni * 16 + fr;
          o[(size_t)row * N + col] = acc[mi][ni][r];
        }
    return;
  }
#pragma unroll
  for (int mi = 0; mi < 2; ++mi)
#pragma unroll
    for (int ni = 0; ni < 8; ++ni)
#pragma unroll
      for (int r = 0; r < 4; ++r) {
        int row = brow + wave * 32 + mi * 16 + fq * 4 + r;
        int col = bcol + ni * 16 + fr;
        float v = acc[mi][ni][r];
        if (Cin) v += Cin[(size_t)row * N + col];
        if (bias) v += bias[col];
        if (act == 1) v = fmaxf(v, 0.0f);
        else if (act == 2) v = 1.0f / (1.0f + expf(-v));
        if (outBf16) ((ushort_t*)out)[(size_t)row * N + col] = f2bf(v);
        else ((float*)out)[(size_t)row * N + col] = v;
      }
}

// ===== m201-schedule GEMM for f4: BM=256 BN=128 BK=64, 512 thr, 3-buf ======
__global__ __launch_bounds__(512) void gemm256_kernel(
    const ushort_t* __restrict__ A, const ushort_t* __restrict__ Bt,
    float* __restrict__ out, int M, int N, int K,
    const float* __restrict__ bias) {
  __shared__ ushort_t As[3][16384];   // 3 x 32 KB
  __shared__ ushort_t Bs[3][8192];    // 3 x 16 KB
  int tid = threadIdx.x;
  int wave = tid >> 6, lane = tid & 63;
  int bx = blockIdx.x, by = blockIdx.y;
  xcd_swizzle(bx, by);
  int fr = lane & 15, fq = lane >> 4;
  int wm = wave >> 2, wn = wave & 3;

  int rquot = tid >> 3;                // 0..63
  int uslot = (tid & 7) ^ (rquot & 7); // pre-swizzled global slot
  const ushort_t* gA = A + (size_t)(by * 256 + rquot) * K + uslot * 8;
  const ushort_t* gB = Bt + (size_t)(bx * 128 + rquot) * K + uslot * 8;

  f32x4 acc[8][2] = {};
  int nsteps = K >> 6;

#define SG_A(b_, t_, j_) gload16(gA + (size_t)(j_) * 64 * K + (size_t)(t_) * 64, &As[b_][(j_) * 4096 + tid * 8])
#define SG_B(b_, t_, j_) gload16(gB + (size_t)(j_) * 64 * K + (size_t)(t_) * 64, &Bs[b_][(j_) * 4096 + tid * 8])

  SG_A(0, 0, 0); SG_A(0, 0, 1); SG_A(0, 0, 2); SG_A(0, 0, 3); SG_B(0, 0, 0); SG_B(0, 0, 1);
  SG_A(1, 1, 0); SG_A(1, 1, 1); SG_A(1, 1, 2); SG_A(1, 1, 3); SG_B(1, 1, 0); SG_B(1, 1, 1);
  asm volatile("s_waitcnt vmcnt(6)" ::: "memory");
  __builtin_amdgcn_s_barrier();

  short8v bf[2][2];

#define PHASE(p_)                                                            \
  {                                                                          \
    short8v af[4][2];                                                        \
    _Pragma("unroll")                                                        \
    for (int q = 0; q < 4; ++q) {                                            \
      int row = wm * 128 + (4 * (p_) + q) * 16 + fr;                         \
      int base = row * 64;                                                   \
      af[q][0] = *(const short8v*)(&As[b][base + ((fq ^ (row & 7)) * 8)]);   \
      af[q][1] = *(const short8v*)(&As[b][base + (((4 + fq) ^ (row & 7)) * 8)]); \
    }                                                                        \
    if ((p_) == 0) {                                                         \
      _Pragma("unroll")                                                      \
      for (int q = 0; q < 2; ++q) {                                          \
        int row = wn * 32 + q * 16 + fr;                                     \
        int base = row * 64;                                                 \
        bf[q][0] = *(const short8v*)(&Bs[b][base + ((fq ^ (row & 7)) * 8)]); \
        bf[q][1] = *(const short8v*)(&Bs[b][base + (((4 + fq) ^ (row & 7)) * 8)]); \
      }                                                                      \
      if (doStage) { SG_A(sb, t + 2, 0); SG_A(sb, t + 2, 1); SG_A(sb, t + 2, 2); SG_A(sb, t + 2, 3); } \
    } else {                                                                 \
      if (doStage) { SG_B(sb, t + 2, 0); SG_B(sb, t + 2, 1); }               \
      if (t + 2 < nsteps)      asm volatile("s_waitcnt vmcnt(6)" ::: "memory"); \
      else if (t + 1 < nsteps) asm volatile("s_waitcnt vmcnt(0)" ::: "memory"); \
    }                                                                        \
    __builtin_amdgcn_s_barrier();                                            \
    asm volatile("s_waitcnt lgkmcnt(0)" ::: "memory");                       \
    __builtin_amdgcn_s_setprio(1);                                           \
    _Pragma("unroll")                                                        \
    for (int kk = 0; kk < 2; ++kk)                                           \
      _Pragma("unroll")                                                      \
      for (int q = 0; q < 4; ++q)                                            \
        _Pragma("unroll")                                                    \
        for (int ni = 0; ni < 2; ++ni)                                       \
          acc[4 * (p_) + q][ni] = __builtin_amdgcn_mfma_f32_16x16x32_bf16(af[q][kk], bf[ni][kk], acc[4 * (p_) + q][ni], 0, 0, 0); \
    __builtin_amdgcn_s_setprio(0);                                           \
    __builtin_amdgcn_s_barrier();                                            \
  }

  for (int t = 0; t < nsteps; ++t) {
    int b = t % 3, sb = (t + 2) % 3;
    bool doStage = (t + 2 < nsteps);
    PHASE(0);
    PHASE(1);
  }
#undef PHASE
#undef SG_A
#undef SG_B

#pragma unroll
  for (int mi = 0; mi < 8; ++mi)
#pragma unroll
    for (int ni = 0; ni < 2; ++ni)
#pragma unroll
      for (int r = 0; r < 4; ++r) {
        int row = by * 256 + wm * 128 + mi * 16 + fq * 4 + r;
        int col = bx * 128 + wn * 32 + ni * 16 + fr;
        float v = acc[mi][ni][r] + bias[col];
        out[(size_t)row * N + col] = 1.0f / (1.0f + expf(-v));
      }
}

// ===== batched z GEMM (R16-proven): N=128, BK=64, 2-buffer LDS =============
struct ZDesc { const ushort_t* A; const ushort_t* Bt; ushort_t* out;
               const float* rs0; const float* rs1; int M; int K; };
struct ZDescs { ZDesc d[3]; };

__global__ __launch_bounds__(256) void zgemm_batched_kernel(ZDescs ds) {
  __shared__ ushort_t As[2][8192];
  __shared__ ushort_t Bs[2][8192];
  ZDesc de = ds.d[blockIdx.z];
  int gy = gridDim.y;
  int yq = gy >> 3;
  int ys = (blockIdx.y & 7) * yq + (blockIdx.y >> 3);
  int brow = ys * 128;
  if (brow >= de.M) return;
  int K = de.K;
  int nsteps = K >> 6;
  if (nsteps == 0) nsteps = 1;
  int kkMax = (K >= 64) ? 2 : 1;
  int tid = threadIdx.x;
  int wave = tid >> 6, lane = tid & 63;

  int rowBase = tid >> 3;
  int u = (tid & 7) ^ (rowBase & 7);
  const ushort_t* gA = de.A + (size_t)(brow + rowBase) * K + u * 8;
  const ushort_t* gB = de.Bt + (size_t)rowBase * K + u * 8;

  int fr = lane & 15, fq = lane >> 4;
  f32x4 acc[2][8] = {};

#define STAGE_Z(buf, koff)                                              \
  do {                                                                  \
    _Pragma("unroll")                                                   \
    for (int j = 0; j < 4; ++j) {                                       \
      gload16(gA + (size_t)j * 32 * K + (koff), &As[buf][j * 2048 + tid * 8]); \
      gload16(gB + (size_t)j * 32 * K + (koff), &Bs[buf][j * 2048 + tid * 8]); \
    }                                                                   \
  } while (0)

  STAGE_Z(0, 0);
  int cur = 0;
  for (int i = 0; i < nsteps; ++i) {
    __syncthreads();
    if (i + 1 < nsteps) STAGE_Z(cur ^ 1, (i + 1) * 64);
#pragma unroll
    for (int kk = 0; kk < 2; ++kk) {
      if (kk >= kkMax) break;
      short8v af[2], bfr[8];
#pragma unroll
      for (int mi = 0; mi < 2; ++mi) {
        int row = wave * 32 + mi * 16 + fr;
        af[mi] = *(const short8v*)(&As[cur][row * 64 + (((kk * 4 + fq) ^ (row & 7)) * 8)]);
      }
#pragma unroll
      for (int ni = 0; ni < 8; ++ni) {
        int row = ni * 16 + fr;
        bfr[ni] = *(const short8v*)(&Bs[cur][row * 64 + (((kk * 4 + fq) ^ (row & 7)) * 8)]);
      }
#pragma unroll
      for (int mi = 0; mi < 2; ++mi)
#pragma unroll
        for (int ni = 0; ni < 8; ++ni)
          acc[mi][ni] = __builtin_amdgcn_mfma_f32_16x16x32_bf16(af[mi], bfr[ni], acc[mi][ni], 0, 0, 0);
    }
    cur ^= 1;
  }
#undef STAGE_Z

#pragma unroll
  for (int mi = 0; mi < 2; ++mi)
#pragma unroll
    for (int ni = 0; ni < 8; ++ni) {
      const float* rs = (ni < 4) ? de.rs0 : de.rs1;
#pragma unroll
      for (int r = 0; r < 4; ++r) {
        int row = brow + wave * 32 + mi * 16 + fq * 4 + r;
        int col = ni * 16 + fr;
        de.out[(size_t)row * 128 + col] = f2bf(acc[mi][ni][r] * rs[row]);
      }
    }
}

// ===== batched CSR gather: 2 edges per dword load; u16 indices =============
struct GDesc { const ushort_t* z0; const uint_t* rp0; const ushort_t* cs0; const float* s0;
               const ushort_t* z1; const uint_t* rp1; const ushort_t* cs1; const float* s1;
               const float* b0; const float* b1; ushort_t* out; int nd; };
struct GDescs { GDesc d[3]; };

__device__ __forceinline__ void gpair(const ushort_t* __restrict__ z,
                                      const ushort_t* __restrict__ cs,
                                      uint_t e, uint_t ee, int h, int cp,
                                      float& ax, float& ay) {
  float x0 = 0, y0 = 0, x1 = 0, y1 = 0, x2 = 0, y2 = 0, x3 = 0, y3 = 0;
  for (; e + 8 <= ee; e += 8) {
    uint_t s0 = cs[e + 0 + h], s1 = cs[e + 2 + h], s2 = cs[e + 4 + h], s3 = cs[e + 6 + h];
    uint_t v0 = *(const uint_t*)(z + (size_t)s0 * kZS + 2 * cp);
    uint_t v1 = *(const uint_t*)(z + (size_t)s1 * kZS + 2 * cp);
    uint_t v2 = *(const uint_t*)(z + (size_t)s2 * kZS + 2 * cp);
    uint_t v3 = *(const uint_t*)(z + (size_t)s3 * kZS + 2 * cp);
    x0 += bf2f_lo(v0); y0 += bf2f_hi(v0);
    x1 += bf2f_lo(v1); y1 += bf2f_hi(v1);
    x2 += bf2f_lo(v2); y2 += bf2f_hi(v2);
    x3 += bf2f_lo(v3); y3 += bf2f_hi(v3);
  }
  for (; e + 2 <= ee; e += 2) {
    uint_t v = *(const uint_t*)(z + (size_t)cs[e + h] * kZS + 2 * cp);
    x0 += bf2f_lo(v); y0 += bf2f_hi(v);
  }
  if (h == 0 && e < ee) {
    uint_t v = *(const uint_t*)(z + (size_t)cs[e] * kZS + 2 * cp);
    x0 += bf2f_lo(v); y0 += bf2f_hi(v);
  }
  ax = (x0 + x1) + (x2 + x3);
  ay = (y0 + y1) + (y2 + y3);
}

__global__ __launch_bounds__(256) void gather_batched_kernel(GDescs ds) {
  GDesc de = ds.d[blockIdx.z];
  int d = blockIdx.x * 4 + (threadIdx.x >> 6);
  if (d >= de.nd) return;
  int lane = threadIdx.x & 63;
  int h = lane >> 5, cp = lane & 31;
  float ax0, ay0, ax1, ay1;
  gpair(de.z0, de.cs0, de.rp0[d], de.rp0[d + 1], h, cp, ax0, ay0);
  gpair(de.z1, de.cs1, de.rp1[d], de.rp1[d + 1], h, cp, ax1, ay1);
  float s0 = de.s0[d], s1 = de.s1[d];
  float vx = ax0 * s0 + ax1 * s1;
  float vy = ay0 * s0 + ay1 * s1;
  vx += __shfl_xor(vx, 32);
  vy += __shfl_xor(vy, 32);
  if (h == 0) {
    int c0 = 2 * cp;
    vx += de.b0[c0] + de.b1[c0];
    vy += de.b0[c0 + 1] + de.b1[c0 + 1];
    uint_t pack = (uint_t)f2bf(vx) | ((uint_t)f2bf(vy) << 16);
    *(uint_t*)(de.out + (size_t)d * 64 + c0) = pack;
  }
}

// ===== layer-3 gather (width 128, d<2048) + L1 norm: u16 indices ===========
__device__ __forceinline__ void gone128(const ushort_t* __restrict__ z,
                                        const ushort_t* __restrict__ cs,
                                        uint_t e, uint_t ee, int l,
                                        float& ax, float& ay) {
  float x0 = 0, y0 = 0, x1 = 0, y1 = 0, x2 = 0, y2 = 0, x3 = 0, y3 = 0;
  for (; e + 4 <= ee; e += 4) {
    uint_t s0 = cs[e], s1 = cs[e + 1], s2 = cs[e + 2], s3 = cs[e + 3];
    uint_t v0 = *(const uint_t*)(z + (size_t)s0 * 128 + 2 * l);
    uint_t v1 = *(const uint_t*)(z + (size_t)s1 * 128 + 2 * l);
    uint_t v2 = *(const uint_t*)(z + (size_t)s2 * 128 + 2 * l);
    uint_t v3 = *(const uint_t*)(z + (size_t)s3 * 128 + 2 * l);
    x0 += bf2f_lo(v0); y0 += bf2f_hi(v0);
    x1 += bf2f_lo(v1); y1 += bf2f_hi(v1);
    x2 += bf2f_lo(v2); y2 += bf2f_hi(v2);
    x3 += bf2f_lo(v3); y3 += bf2f_hi(v3);
  }
  for (; e < ee; ++e) {
    uint_t v = *(const uint_t*)(z + (size_t)cs[e] * 128 + 2 * l);
    x0 += bf2f_lo(v); y0 += bf2f_hi(v);
  }
  ax = (x0 + x1) + (x2 + x3);
  ay = (y0 + y1) + (y2 + y3);
}

__global__ __launch_bounds__(256) void gather128_l1_kernel(
    const ushort_t* __restrict__ zD, const uint_t* __restrict__ rpD, const ushort_t* __restrict__ csD,
    const float* __restrict__ sInD,
    const ushort_t* __restrict__ zM, const uint_t* __restrict__ rpM, const ushort_t* __restrict__ csM,
    const float* __restrict__ sInM,
    const float* __restrict__ bD, const float* __restrict__ bM,
    float* __restrict__ emb, ushort_t* __restrict__ embb, int embStride) {
  int d = blockIdx.x * 4 + (threadIdx.x >> 6);
  int l = threadIdx.x & 63;          // covers cols {2l, 2l+1}
  float axD, ayD, axM, ayM;
  gone128(zD, csD, rpD[d], rpD[d + 1], l, axD, ayD);
  gone128(zM, csM, rpM[d], rpM[d + 1], l, axM, ayM);
  float sD = sInD[d], sM = sInM[d];
  int c0 = 2 * l;
  float v0 = axD * sD + axM * sM + bD[c0] + bM[c0];
  float v1 = ayD * sD + ayM * sM + bD[c0 + 1] + bM[c0 + 1];
  float a = fabsf(v0) + fabsf(v1);
#pragma unroll
  for (int o = 32; o > 0; o >>= 1) a += __shfl_xor(a, o);
  float l1 = fmaxf(a, 1e-12f);
  float e0 = v0 / l1, e1 = v1 / l1;
  float2 fe = {e0, e1};
  *(float2*)(emb + (size_t)d * kOUTF + c0) = fe;
  uint_t pack = (uint_t)f2bf(e0) | ((uint_t)f2bf(e1) << 16);
  *(uint_t*)(embb + (size_t)d * embStride + c0) = pack;
}

// ===== split-K reduce with fused bias/act/bf16-out =========================
__global__ void reducek_kernel(const float* __restrict__ P, void* __restrict__ out,
                               int outBf16, int n4, int S, int N,
                               const float* __restrict__ bias, int act) {
  int idx = blockIdx.x * 256 + threadIdx.x;
  if (idx >= n4) return;
  float4 a = ((const float4*)P)[idx];
  for (int s = 1; s < S; ++s) {
    float4 b = ((const float4*)P)[(size_t)s * n4 + idx];
    a.x += b.x; a.y += b.y; a.z += b.z; a.w += b.w;
  }
  float v[4] = {a.x, a.y, a.z, a.w};
  int c0 = (idx * 4) % N;
#pragma unroll
  for (int j = 0; j < 4; ++j) {
    if (bias) v[j] += bias[c0 + j];
    if (act == 1) v[j] = fmaxf(v[j], 0.0f);
    else if (act == 2) v[j] = 1.0f / (1.0f + expf(-v[j]));
  }
  if (outBf16) {
    ushort_t* o = (ushort_t*)out + (size_t)idx * 4;
    o[0] = f2bf(v[0]); o[1] = f2bf(v[1]); o[2] = f2bf(v[2]); o[3] = f2bf(v[3]);
  } else {
    float4 r = {v[0], v[1], v[2], v[3]};
    ((float4*)out)[idx] = r;
  }
}

extern "C" void kernel_launch(void* const* d_in, const int* in_sizes, int n_in,
                              void* d_out, int out_size, void* d_ws, size_t ws_size,
                              hipStream_t stream) {
  const float* h_L = (const float*)d_in[0];
  const float* h_D = (const float*)d_in[1];
  const float* h_M = (const float*)d_in[2];
  const float* Adj = (const float*)d_in[3];
  EdgePtrs ep;
  for (int i = 0; i < 12; ++i) ep.p[i] = (const int*)d_in[4 + i];
  const float* W[3]  = {(const float*)d_in[16], (const float*)d_in[18], (const float*)d_in[20]};
  const float* Bb[3] = {(const float*)d_in[17], (const float*)d_in[19], (const float*)d_in[21]};
  const float* f1_w = (const float*)d_in[22];
  const float* f1_b = (const float*)d_in[23];
  const float* f2_w = (const float*)d_in[24];
  const float* f2_b = (const float*)d_in[25];
  const float* f3_w = (const float*)d_in[26];
  const float* f3_b = (const float*)d_in[27];
  const float* f4_w = (const float*)d_in[28];
  const float* f4_b = (const float*)d_in[29];

  // ---- workspace layout ----
  float* ws = (float*)d_ws;
  size_t off = 0;
  auto allocF = [&](size_t n) { float* p = ws + off; off += (n + 3) & ~(size_t)3; return p; };
  auto allocU = [&](size_t n) { return (uint_t*)allocF(n); };
  auto allocB = [&](size_t n) { return (ushort_t*)allocF((n + 1) / 2); };

  uint_t* part   = allocU((size_t)12 * kHB * 16384);   // 12.6 MB, reused as z bufs
  uint_t* cnts   = allocU((size_t)12 * 16384);
  float*  degscale = allocF((size_t)12 * 16384);
  uint_t* rp_all = allocU(45062 + 2);
  uint_t* ofs    = allocU((size_t)6 * kHB * 16384);
  ushort_t* csr  = allocB((size_t)6 * kE);            // u16 CSR (src ids < 16384)
  ushort_t* hLb  = allocB((size_t)kNL * kFEAT);
  ushort_t* hDb  = allocB((size_t)kND * kFEAT);
  ushort_t* hMb  = allocB((size_t)kNM * kFEAT);
  ushort_t* xin  = allocB((size_t)kSIZE * kXIN);   // [Adj | emb] bf16, stride 4224
  ushort_t* aLb  = allocB((size_t)kNL * kHID);
  ushort_t* aDb  = allocB((size_t)kND * kHID);
  ushort_t* aMb  = allocB((size_t)kNM * kHID);
  ushort_t* WLt  = allocB((size_t)128 * kFEAT);
  ushort_t* WDt  = allocB((size_t)128 * kFEAT);
  ushort_t* WMt  = allocB((size_t)128 * kFEAT);
  ushort_t* WL2t = allocB((size_t)128 * kHID);
  ushort_t* WD2t = allocB((size_t)128 * kHID);
  ushort_t* WM2t = allocB((size_t)128 * kHID);
  ushort_t* W3t1 = allocB((size_t)kOUTF * kHID);
  ushort_t* W3t3 = allocB((size_t)kOUTF * kHID);
  ushort_t* f1t  = allocB((size_t)256 * kXIN);
  ushort_t* f2t  = allocB((size_t)512 * 256);
  ushort_t* f3t  = allocB((size_t)1024 * 512);
  ushort_t* f4t  = allocB((size_t)kITEMS * 1024);
  ushort_t* x1b  = allocB((size_t)kSIZE * 256);
  ushort_t* x2b  = allocB((size_t)kSIZE * 512);
  ushort_t* x3b  = allocB((size_t)kSIZE * 1024);

  // shared split-K partials (f1 S=6: 3.15M, f2 S=4: 4.19M, f3 S=2: 4.19M floats)
  int S1 = 1, S2 = 1, S3 = 1;
  float* partK = nullptr;
  size_t avail = (ws_size / 4 > off) ? ws_size / 4 - off - 64 : 0;
  if (avail >= (size_t)4 * kSIZE * 512 + 16) {
    partK = allocF((size_t)4 * kSIZE * 512);
    S1 = 6; S2 = 4; S3 = 2;
  }

  // z buffers alias `part` (dead after chunkofs/fill)
  ushort_t* zL  = (ushort_t*)part;                       // 16384 x 128
  ushort_t* zD  = zL + (size_t)kNL * kZS;                // 4096 x 128
  ushort_t* zM  = zD + (size_t)kND * kZS;                // 2048 x 128
  ushort_t* zD3 = zM + (size_t)kNM * kZS;                // 4096 x 128
  ushort_t* zM3 = zD3 + (size_t)kND * kZS;               // 2048 x 128

  I6 ndI; const int ndst_[6] = {kND, kNL, kNM, kNL, kNM, kND};
  for (int t = 0; t < 6; ++t) ndI.v[t] = ndst_[t];
  I6 rpo; { int r = 0; for (int t = 0; t < 6; ++t) { rpo.v[t] = r; r += ndst_[t] + 1; } }
  auto dsc = [&](int k) { return degscale + ((size_t)k << 14); };

  // ---- 1) hist (64KB LDS) then prep (4.2KB LDS, high occupancy) ----
  hist_kernel<<<12 * kHB, 256, 0, stream>>>(ep, part);

  PJobs pj; int nj = 0; int totblk = 0;
  auto addCvt = [&](const float* in, ushort_t* out, size_t n) {
    int n4 = (int)(n / 4);
    pj.j[nj] = {in, out, n4, 0, 0, 0, (n4 + 255) / 256}; totblk += pj.j[nj].nblk; ++nj;
  };
  auto addStrided = [&](const float* in, ushort_t* out, size_t n, int rowLen, int stride) {
    int n4 = (int)(n / 4);
    pj.j[nj] = {in, out, n4, rowLen / 4, stride, 2, (n4 + 255) / 256}; totblk += pj.j[nj].nblk; ++nj;
  };
  auto addT = [&](const float* in, ushort_t* out, int K, int N) {
    pj.j[nj] = {in, out, K, N, 0, 1, (N / 32) * (K / 32)}; totblk += pj.j[nj].nblk; ++nj;
  };
  addCvt(h_L, hLb, (size_t)kNL * kFEAT);
  addCvt(h_D, hDb, (size_t)kND * kFEAT);
  addCvt(h_M, hMb, (size_t)kNM * kFEAT);
  addStrided(Adj, xin, (size_t)kSIZE * kITEMS, kITEMS, kXIN);
  addT(W[0] + (size_t)0 * kFEAT * kHID, WLt + (size_t)0 * kFEAT, kFEAT, kHID);
  addT(W[0] + (size_t)2 * kFEAT * kHID, WLt + (size_t)64 * kFEAT, kFEAT, kHID);
  addT(W[0] + (size_t)1 * kFEAT * kHID, WDt + (size_t)0 * kFEAT, kFEAT, kHID);
  addT(W[0] + (size_t)4 * kFEAT * kHID, WDt + (size_t)64 * kFEAT, kFEAT, kHID);
  addT(W[0] + (size_t)3 * kFEAT * kHID, WMt + (size_t)0 * kFEAT, kFEAT, kHID);
  addT(W[0] + (size_t)5 * kFEAT * kHID, WMt + (size_t)64 * kFEAT, kFEAT, kHID);
  addT(W[1] + (size_t)0 * kHID * kHID, WL2t + (size_t)0 * kHID, kHID, kHID);
  addT(W[1] + (size_t)2 * kHID * kHID, WL2t + (size_t)64 * kHID, kHID, kHID);
  addT(W[1] + (size_t)1 * kHID * kHID, WD2t + (size_t)0 * kHID, kHID, kHID);
  addT(W[1] + (size_t)4 * kHID * kHID, WD2t + (size_t)64 * kHID, kHID, kHID);
  addT(W[1] + (size_t)3 * kHID * kHID, WM2t + (size_t)0 * kHID, kHID, kHID);
  addT(W[1] + (size_t)5 * kHID * kHID, WM2t + (size_t)64 * kHID, kHID, kHID);
  addT(W[2] + (size_t)1 * kHID * kOUTF, W3t1, kHID, kOUTF);
  addT(W[2] + (size_t)3 * kHID * kOUTF, W3t3, kHID, kOUTF);
  addT(f1_w, f1t, kXIN, 256);
  addT(f2_w, f2t, 256, 512);
  addT(f3_w, f3t, 512, 1024);
  addT(f4_w, f4t, 1024, kITEMS);
  pj.n = nj;
  prep_kernel<<<totblk, 256, 0, stream>>>(pj);

  // ---- 2) CSR metadata chain + fill ----
  reduce_finalize_kernel<<<12 * 16384 / 256, 256, 0, stream>>>(part, cnts, degscale);
  scan_kernel<<<6, 1024, 0, stream>>>(cnts, rp_all, rpo, ndI);
  chunkofs_kernel<<<6 * 16384 / 256, 256, 0, stream>>>(part, rp_all, rpo, ndI, ofs);
  fill_kernel<<<6 * kHB, 256, 0, stream>>>(ep, ofs, csr);

  // ---- 3) GNN layers 1 & 2 ----
  const ushort_t* curb[3] = {hLb, hDb, hMb};
  for (int layer = 0; layer < 2; ++layer) {
    int K = (layer == 0) ? kFEAT : kHID;
    const ushort_t* WtL = (layer == 0) ? WLt : WL2t;
    const ushort_t* WtD = (layer == 0) ? WDt : WD2t;
    const ushort_t* WtM = (layer == 0) ? WMt : WM2t;
    const float* bl = Bb[layer];
    ZDescs zd;
    zd.d[0] = {curb[0], WtL, zL, dsc(0), dsc(4),  kNL, K};
    zd.d[1] = {curb[1], WtD, zD, dsc(2), dsc(8),  kND, K};
    zd.d[2] = {curb[2], WtM, zM, dsc(6), dsc(10), kNM, K};
    zgemm_batched_kernel<<<dim3(1, kNL / 128, 3), 256, 0, stream>>>(zd);
    if (layer == 0) {
      GDescs gd;
      gd.d[0] = {zD, rp_all + rpo.v[1], csr + (size_t)1 * kE, dsc(3),
                 zM, rp_all + rpo.v[3], csr + (size_t)3 * kE, dsc(7),
                 bl + 1 * kHID, bl + 3 * kHID, aLb, kNL};
      gd.d[1] = {zL, rp_all + rpo.v[0], csr + (size_t)0 * kE, dsc(1),
                 zM + 64, rp_all + rpo.v[5], csr + (size_t)5 * kE, dsc(11),
                 bl + 0 * kHID, bl + 5 * kHID, aDb, kND};
      gd.d[2] = {zL + 64, rp_all + rpo.v[2], csr + (size_t)2 * kE, dsc(5),
                 zD + 64, rp_all + rpo.v[4], csr + (size_t)4 * kE, dsc(9),
                 bl + 2 * kHID, bl + 4 * kHID, aMb, kNM};
      gather_batched_kernel<<<dim3(kNL / 4, 1, 3), 256, 0, stream>>>(gd);
    } else {
      // layer-3 consumes only aDb/aMb -> skip dead aLb gather (70% of work)
      GDescs gd;
      gd.d[0] = {zL, rp_all + rpo.v[0], csr + (size_t)0 * kE, dsc(1),
                 zM + 64, rp_all + rpo.v[5], csr + (size_t)5 * kE, dsc(11),
                 bl + 0 * kHID, bl + 5 * kHID, aDb, kND};
      gd.d[1] = {zL + 64, rp_all + rpo.v[2], csr + (size_t)2 * kE, dsc(5),
                 zD + 64, rp_all + rpo.v[4], csr + (size_t)4 * kE, dsc(9),
                 bl + 2 * kHID, bl + 4 * kHID, aMb, kNM};
      gd.d[2] = gd.d[1];
      gather_batched_kernel<<<dim3(kND / 4, 1, 2), 256, 0, stream>>>(gd);
    }
    curb[0] = aLb; curb[1] = aDb; curb[2] = aMb;
  }

  // ---- 4) layer 3 (types 1: D->L, 3: M->L; rows < 2048) + L1 norm ----
  float* emb  = (float*)d_out;
  float* outx = (float*)d_out + (size_t)kSIZE * kOUTF;
  {
    ZDescs zd;
    zd.d[0] = {curb[1], W3t1, zD3, dsc(2), dsc(2), kND, kHID};
    zd.d[1] = {curb[2], W3t3, zM3, dsc(6), dsc(6), kNM, kHID};
    zd.d[2] = zd.d[1];
    zgemm_batched_kernel<<<dim3(1, kND / 128, 2), 256, 0, stream>>>(zd);
    gather128_l1_kernel<<<kSIZE / 4, 256, 0, stream>>>(
        zD3, rp_all + rpo.v[1], csr + (size_t)1 * kE, dsc(3),
        zM3, rp_all + rpo.v[3], csr + (size_t)3 * kE, dsc(7),
        Bb[2] + 1 * kOUTF, Bb[2] + 3 * kOUTF, emb, xin + kITEMS, kXIN);
  }

  // ---- 5) MLP ----
  if (S1 > 1) {
    gemm_bf16_kernel<<<dim3(2, 16, S1), 256, 0, stream>>>(
        xin, f1t, nullptr, nullptr, 0, kSIZE, 256, kXIN, kXIN,
        nullptr, 0, kXIN / S1, partK);
    int n4 = kSIZE * 256 / 4;
    reducek_kernel<<<(n4 + 255) / 256, 256, 0, stream>>>(
        partK, x1b, 1, n4, S1, 256, f1_b, 1);
  } else {
    gemm_bf16_kernel<<<dim3(2, 16, 1), 256, 0, stream>>>(
        xin, f1t, nullptr, x1b, 1, kSIZE, 256, kXIN, kXIN, f1_b, 1, 0, nullptr);
  }
  if (S2 > 1) {
    gemm_bf16_kernel<<<dim3(4, 16, S2), 256, 0, stream>>>(
        x1b, f2t, nullptr, nullptr, 0, kSIZE, 512, 256, 256,
        nullptr, 0, 256 / S2, partK);
    int n4 = kSIZE * 512 / 4;
    reducek_kernel<<<(n4 + 255) / 256, 256, 0, stream>>>(
        partK, x2b, 1, n4, S2, 512, f2_b, 1);
  } else {
    gemm_bf16_kernel<<<dim3(4, 16, 1), 256, 0, stream>>>(
        x1b, f2t, nullptr, x2b, 1, kSIZE, 512, 256, 256, f2_b, 1, 0, nullptr);
  }
  if (S3 > 1) {
    gemm_bf16_kernel<<<dim3(8, 16, S3), 256, 0, stream>>>(
        x2b, f3t, nullptr, nullptr, 0, kSIZE, 1024, 512, 512,
        nullptr, 0, 512 / S3, partK);
    int n4 = kSIZE * 1024 / 4;
    reducek_kernel<<<(n4 + 255) / 256, 256, 0, stream>>>(
        partK, x3b, 1, n4, S3, 1024, f3_b, 1);
  } else {
    gemm_bf16_kernel<<<dim3(8, 16, 1), 256, 0, stream>>>(
        x2b, f3t, nullptr, x3b, 1, kSIZE, 1024, 512, 512, f3_b, 1, 0, nullptr);
  }
  // f4: m201-schedule 256x128 kernel, fused bias+sigmoid, fp32 out
  gemm256_kernel<<<dim3(kITEMS / 128, kSIZE / 256), 512, 0, stream>>>(
      x3b, f4t, outx, kSIZE, kITEMS, 1024, f4_b);
}

// Round 20
// 288.455 us; speedup vs baseline: 1.1185x; 1.0768x over previous
//
#include <hip/hip_runtime.h>

constexpr int kNL = 16384, kND = 4096, kNM = 2048;
constexpr int kE = 262144;              // 2^18
constexpr int kFEAT = 256, kHID = 64, kOUTF = 128;
constexpr int kITEMS = 4096, kSIZE = 2048;
constexpr int kHB = 16;                 // histogram chunks per index array
constexpr int kZS = 128;                // z row stride (merged 2-type layout)
constexpr int kXIN = kITEMS + kOUTF;    // 4224

typedef unsigned short ushort_t;
typedef unsigned int uint_t;
typedef __attribute__((ext_vector_type(8))) short short8v;
typedef __attribute__((ext_vector_type(4))) float f32x4;
typedef __attribute__((ext_vector_type(4))) uint_t uint4v;

struct EdgePtrs { const int* p[12]; };
struct I6 { int v[6]; };

__device__ inline ushort_t f2bf(float f) {
  unsigned u = __builtin_bit_cast(unsigned, f);
  unsigned r = u + 0x7fffu + ((u >> 16) & 1u);
  return (ushort_t)(r >> 16);
}
__device__ inline float bf2f(ushort_t b) {
  unsigned u = ((unsigned)b) << 16;
  return __builtin_bit_cast(float, u);
}
__device__ inline float bf2f_lo(uint_t v) { return __builtin_bit_cast(float, v << 16); }
__device__ inline float bf2f_hi(uint_t v) { return __builtin_bit_cast(float, v & 0xffff0000u); }

// async global->LDS, 16 B per lane (global_load_lds_dwordx4)
__device__ __forceinline__ void gload16(const ushort_t* g, ushort_t* l) {
  __builtin_amdgcn_global_load_lds(
      (const __attribute__((address_space(1))) void*)g,
      (__attribute__((address_space(3))) void*)l, 16, 0, 0);
}

// bijective XCD swizzle (m204)
__device__ __forceinline__ void xcd_swizzle(int& bx, int& by) {
  int gx = gridDim.x, gy = gridDim.y;
  int nwg = gx * gy;
  int orig = by * gx + bx;
  int q = nwg >> 3, r = nwg & 7;
  int xcd = orig & 7, loc = orig >> 3;
  int s = ((xcd < r) ? xcd * (q + 1) : r * (q + 1) + (xcd - r) * q) + loc;
  by = s % gy;
  bx = s / gy;
}

// ===== hist: standalone (64 KB LDS only here) ==============================
__global__ __launch_bounds__(256) void hist_kernel(EdgePtrs ep, uint_t* __restrict__ part) {
  __shared__ uint_t bins[16384];
  int k = blockIdx.x >> 4, chunk = blockIdx.x & (kHB - 1);
  for (int i = threadIdx.x; i < 16384; i += 256) bins[i] = 0;
  __syncthreads();
  const int* arr = ep.p[k];
  int base = chunk * (kE / kHB);
  for (int i = threadIdx.x; i < kE / kHB; i += 256)
    atomicAdd(&bins[arr[base + i]], 1u);
  __syncthreads();
  uint_t* o = part + ((size_t)blockIdx.x << 14);
  for (int i = threadIdx.x; i < 16384; i += 256) o[i] = bins[i];
}

// ===== prep: converts/transposes ONLY (4.2 KB LDS -> high occupancy) =======
struct PJob { const float* in; ushort_t* out; int A; int B; int C; int kind; int nblk; };
struct PJobs { PJob j[24]; int n; };

__global__ __launch_bounds__(256) void prep_kernel(PJobs jobs) {
  __shared__ float t[32][33];
  int b = blockIdx.x;
  int ji = 0;
  while (ji < jobs.n && b >= jobs.j[ji].nblk) { b -= jobs.j[ji].nblk; ++ji; }
  if (ji >= jobs.n) return;
  PJob jb = jobs.j[ji];
  if (jb.kind == 0) {                       // flat convert, A = n4
    int idx = b * 256 + threadIdx.x;
    if (idx >= jb.A) return;
    float4 v = ((const float4*)jb.in)[idx];
    ushort_t* o = jb.out + (size_t)idx * 4;
    o[0] = f2bf(v.x); o[1] = f2bf(v.y); o[2] = f2bf(v.z); o[3] = f2bf(v.w);
  } else if (jb.kind == 2) {                // strided convert: A=n4, B=rowLen4, C=outStride
    int idx = b * 256 + threadIdx.x;
    if (idx >= jb.A) return;
    float4 v = ((const float4*)jb.in)[idx];
    int row = idx / jb.B, col4 = idx - row * jb.B;
    ushort_t* o = jb.out + (size_t)row * jb.C + (size_t)col4 * 4;
    o[0] = f2bf(v.x); o[1] = f2bf(v.y); o[2] = f2bf(v.z); o[3] = f2bf(v.w);
  } else {                                  // transpose: in [K][N] -> out [N][K]; A=K, B=N
    int K = jb.A, N = jb.B;
    int tpr = N >> 5;
    int n0 = (b % tpr) * 32, k0 = (b / tpr) * 32;
    int tx = threadIdx.x & 31, ty = threadIdx.x >> 5;
#pragma unroll
    for (int i = 0; i < 32; i += 8)
      t[ty + i][tx] = jb.in[(size_t)(k0 + ty + i) * N + n0 + tx];
    __syncthreads();
#pragma unroll
    for (int i = 0; i < 32; i += 8)
      jb.out[(size_t)(n0 + ty + i) * K + k0 + tx] = f2bf(t[tx][ty + i]);
  }
}

// ===== CSR metadata chain (R12-proven: wide grids) =========================
__global__ void reduce_finalize_kernel(const uint_t* __restrict__ part,
                                       uint_t* __restrict__ cnts,
                                       float* __restrict__ degscale) {
  int idx = blockIdx.x * 256 + threadIdx.x;   // grid = 12*16384/256
  int k = idx >> 14, bin = idx & 16383;
  uint_t s = 0;
  for (int c = 0; c < kHB; ++c) s += part[((size_t)(k * kHB + c) << 14) + bin];
  cnts[idx] = s;
  degscale[idx] = rsqrtf((float)max(s, 1u));
}

__global__ __launch_bounds__(1024) void scan_kernel(const uint_t* __restrict__ cnts,
                                                    uint_t* __restrict__ rp_all,
                                                    I6 rpoff, I6 nd) {
  __shared__ uint_t sums[1024];
  int t = blockIdx.x;
  int n = nd.v[t];
  const uint_t* c = cnts + ((size_t)(2 * t + 1) << 14);
  uint_t* rp = rp_all + rpoff.v[t];
  int tid = threadIdx.x;
  int seg = n >> 10;
  uint_t s = 0;
  for (int j = 0; j < seg; ++j) s += c[tid * seg + j];
  sums[tid] = s;
  __syncthreads();
  for (int o = 1; o < 1024; o <<= 1) {
    uint_t v = (tid >= o) ? sums[tid - o] : 0u;
    __syncthreads();
    sums[tid] += v;
    __syncthreads();
  }
  uint_t run = sums[tid] - s;   // exclusive
  for (int j = 0; j < seg; ++j) { rp[tid * seg + j] = run; run += c[tid * seg + j]; }
  if (tid == 1023) rp[n] = run;
}

__global__ void chunkofs_kernel(const uint_t* __restrict__ part,
                                const uint_t* __restrict__ rp_all,
                                I6 rpoff, I6 nd, uint_t* __restrict__ ofs) {
  int idx = blockIdx.x * 256 + threadIdx.x;   // grid = 6*16384/256
  int t = idx >> 14, bin = idx & 16383;
  if (bin >= nd.v[t]) return;
  uint_t run = (rp_all + rpoff.v[t])[bin];
  for (int c = 0; c < kHB; ++c) {
    ofs[((size_t)(t * kHB + c) << 14) + bin] = run;
    run += part[((size_t)((2 * t + 1) * kHB + c) << 14) + bin];
  }
}

__global__ __launch_bounds__(256) void fill_kernel(EdgePtrs ep,
                                                   const uint_t* __restrict__ ofs,
                                                   ushort_t* __restrict__ csr_all) {
  __shared__ uint_t cursor[16384];
  int t = blockIdx.x >> 4, chunk = blockIdx.x & (kHB - 1);
  const uint_t* o = ofs + ((size_t)(t * kHB + chunk) << 14);
  for (int i = threadIdx.x; i < 16384; i += 256) cursor[i] = o[i];
  __syncthreads();
  const int* srcp = ep.p[2 * t];
  const int* dstp = ep.p[2 * t + 1];
  int base = chunk * (kE / kHB);
  ushort_t* csr = csr_all + (size_t)t * kE;
  for (int i = threadIdx.x; i < kE / kHB; i += 256) {
    int e = base + i;
    int d = dstp[e];
    uint_t pos = atomicAdd(&cursor[d], 1u);
    csr[pos] = (ushort_t)srcp[e];
  }
}

// ===== generic bf16 MFMA GEMM, 128x128 tile, BK=64, 2-buffer (R8) ==========
__global__ __launch_bounds__(256) void gemm_bf16_kernel(
    const ushort_t* __restrict__ A, const ushort_t* __restrict__ Bt,
    const float* __restrict__ Cin, void* __restrict__ out, int outBf16,
    int M, int N, int K, int ldb,
    const float* __restrict__ bias, int act,
    int kChunk, float* __restrict__ partOut) {
  __shared__ ushort_t As[2][8192];   // 2 x 16 KB
  __shared__ ushort_t Bs[2][8192];
  int tid = threadIdx.x;
  int wave = tid >> 6, lane = tid & 63;
  int bx = blockIdx.x, by = blockIdx.y;
  xcd_swizzle(bx, by);
  int brow = by * 128, bcol = bx * 128;
  int kStart = partOut ? blockIdx.z * kChunk : 0;
  int kLen = partOut ? kChunk : K;
  int nsteps = kLen >> 6;              // BK = 64

  int rowBase = tid >> 3;              // 0..31
  int u = (tid & 7) ^ (rowBase & 7);
  const ushort_t* gA = A + (size_t)(brow + rowBase) * K + kStart + u * 8;
  const ushort_t* gB = Bt + (size_t)(bcol + rowBase) * ldb + kStart + u * 8;

  int fr = lane & 15, fq = lane >> 4;
  f32x4 acc[2][8] = {};

#define STAGE_G(buf, koff)                                              \
  do {                                                                  \
    _Pragma("unroll")                                                   \
    for (int j = 0; j < 4; ++j) {                                       \
      gload16(gA + (size_t)j * 32 * K + (koff), &As[buf][j * 2048 + tid * 8]);   \
      gload16(gB + (size_t)j * 32 * ldb + (koff), &Bs[buf][j * 2048 + tid * 8]); \
    }                                                                   \
  } while (0)

  STAGE_G(0, 0);
  int cur = 0;
  for (int i = 0; i < nsteps; ++i) {
    __syncthreads();
    if (i + 1 < nsteps) STAGE_G(cur ^ 1, (i + 1) * 64);
#pragma unroll
    for (int kk = 0; kk < 2; ++kk) {
      short8v af[2], bfr[8];
#pragma unroll
      for (int mi = 0; mi < 2; ++mi) {
        int row = wave * 32 + mi * 16 + fr;
        af[mi] = *(const short8v*)(&As[cur][row * 64 + (((kk * 4 + fq) ^ (row & 7)) * 8)]);
      }
#pragma unroll
      for (int ni = 0; ni < 8; ++ni) {
        int row = ni * 16 + fr;
        bfr[ni] = *(const short8v*)(&Bs[cur][row * 64 + (((kk * 4 + fq) ^ (row & 7)) * 8)]);
      }
#pragma unroll
      for (int mi = 0; mi < 2; ++mi)
#pragma unroll
        for (int ni = 0; ni < 8; ++ni)
          acc[mi][ni] = __builtin_amdgcn_mfma_f32_16x16x32_bf16(af[mi], bfr[ni], acc[mi][ni], 0, 0, 0);
    }
    cur ^= 1;
  }
#undef STAGE_G

  if (partOut) {
    float* o = partOut + (size_t)blockIdx.z * M * N;
#pragma unroll
    for (int mi = 0; mi < 2; ++mi)
#pragma unroll
      for (int ni = 0; ni < 8; ++ni)
#pragma unroll
        for (int r = 0; r < 4; ++r) {
          int row = brow + wave * 32 + mi * 16 + fq * 4 + r;
          int col = bcol + ni * 16 + fr;
          o[(size_t)row * N + col] = acc[mi][ni][r];
        }
    return;
  }
#pragma unroll
  for (int mi = 0; mi < 2; ++mi)
#pragma unroll
    for (int ni = 0; ni < 8; ++ni)
#pragma unroll
      for (int r = 0; r < 4; ++r) {
        int row = brow + wave * 32 + mi * 16 + fq * 4 + r;
        int col = bcol + ni * 16 + fr;
        float v = acc[mi][ni][r];
        if (Cin) v += Cin[(size_t)row * N + col];
        if (bias) v += bias[col];
        if (act == 1) v = fmaxf(v, 0.0f);
        else if (act == 2) v = 1.0f / (1.0f + expf(-v));
        if (outBf16) ((ushort_t*)out)[(size_t)row * N + col] = f2bf(v);
        else ((float*)out)[(size_t)row * N + col] = v;
      }
}

// ===== m201-schedule GEMM for f4: BM=256 BN=128 BK=64, 512 thr, 3-buf ======
__global__ __launch_bounds__(512) void gemm256_kernel(
    const ushort_t* __restrict__ A, const ushort_t* __restrict__ Bt,
    float* __restrict__ out, int M, int N, int K,
    const float* __restrict__ bias) {
  __shared__ ushort_t As[3][16384];   // 3 x 32 KB
  __shared__ ushort_t Bs[3][8192];    // 3 x 16 KB
  int tid = threadIdx.x;
  int wave = tid >> 6, lane = tid & 63;
  int bx = blockIdx.x, by = blockIdx.y;
  xcd_swizzle(bx, by);
  int fr = lane & 15, fq = lane >> 4;
  int wm = wave >> 2, wn = wave & 3;

  int rquot = tid >> 3;                // 0..63
  int uslot = (tid & 7) ^ (rquot & 7); // pre-swizzled global slot
  const ushort_t* gA = A + (size_t)(by * 256 + rquot) * K + uslot * 8;
  const ushort_t* gB = Bt + (size_t)(bx * 128 + rquot) * K + uslot * 8;

  f32x4 acc[8][2] = {};
  int nsteps = K >> 6;

#define SG_A(b_, t_, j_) gload16(gA + (size_t)(j_) * 64 * K + (size_t)(t_) * 64, &As[b_][(j_) * 4096 + tid * 8])
#define SG_B(b_, t_, j_) gload16(gB + (size_t)(j_) * 64 * K + (size_t)(t_) * 64, &Bs[b_][(j_) * 4096 + tid * 8])

  SG_A(0, 0, 0); SG_A(0, 0, 1); SG_A(0, 0, 2); SG_A(0, 0, 3); SG_B(0, 0, 0); SG_B(0, 0, 1);
  SG_A(1, 1, 0); SG_A(1, 1, 1); SG_A(1, 1, 2); SG_A(1, 1, 3); SG_B(1, 1, 0); SG_B(1, 1, 1);
  asm volatile("s_waitcnt vmcnt(6)" ::: "memory");
  __builtin_amdgcn_s_barrier();

  short8v bf[2][2];

#define PHASE(p_)                                                            \
  {                                                                          \
    short8v af[4][2];                                                        \
    _Pragma("unroll")                                                        \
    for (int q = 0; q < 4; ++q) {                                            \
      int row = wm * 128 + (4 * (p_) + q) * 16 + fr;                         \
      int base = row * 64;                                                   \
      af[q][0] = *(const short8v*)(&As[b][base + ((fq ^ (row & 7)) * 8)]);   \
      af[q][1] = *(const short8v*)(&As[b][base + (((4 + fq) ^ (row & 7)) * 8)]); \
    }                                                                        \
    if ((p_) == 0) {                                                         \
      _Pragma("unroll")                                                      \
      for (int q = 0; q < 2; ++q) {                                          \
        int row = wn * 32 + q * 16 + fr;                                     \
        int base = row * 64;                                                 \
        bf[q][0] = *(const short8v*)(&Bs[b][base + ((fq ^ (row & 7)) * 8)]); \
        bf[q][1] = *(const short8v*)(&Bs[b][base + (((4 + fq) ^ (row & 7)) * 8)]); \
      }                                                                      \
      if (doStage) { SG_A(sb, t + 2, 0); SG_A(sb, t + 2, 1); SG_A(sb, t + 2, 2); SG_A(sb, t + 2, 3); } \
    } else {                                                                 \
      if (doStage) { SG_B(sb, t + 2, 0); SG_B(sb, t + 2, 1); }               \
      if (t + 2 < nsteps)      asm volatile("s_waitcnt vmcnt(6)" ::: "memory"); \
      else if (t + 1 < nsteps) asm volatile("s_waitcnt vmcnt(0)" ::: "memory"); \
    }                                                                        \
    __builtin_amdgcn_s_barrier();                                            \
    asm volatile("s_waitcnt lgkmcnt(0)" ::: "memory");                       \
    __builtin_amdgcn_s_setprio(1);                                           \
    _Pragma("unroll")                                                        \
    for (int kk = 0; kk < 2; ++kk)                                           \
      _Pragma("unroll")                                                      \
      for (int q = 0; q < 4; ++q)                                            \
        _Pragma("unroll")                                                    \
        for (int ni = 0; ni < 2; ++ni)                                       \
          acc[4 * (p_) + q][ni] = __builtin_amdgcn_mfma_f32_16x16x32_bf16(af[q][kk], bf[ni][kk], acc[4 * (p_) + q][ni], 0, 0, 0); \
    __builtin_amdgcn_s_setprio(0);                                           \
    __builtin_amdgcn_s_barrier();                                            \
  }

  for (int t = 0; t < nsteps; ++t) {
    int b = t % 3, sb = (t + 2) % 3;
    bool doStage = (t + 2 < nsteps);
    PHASE(0);
    PHASE(1);
  }
#undef PHASE
#undef SG_A
#undef SG_B

#pragma unroll
  for (int mi = 0; mi < 8; ++mi)
#pragma unroll
    for (int ni = 0; ni < 2; ++ni)
#pragma unroll
      for (int r = 0; r < 4; ++r) {
        int row = by * 256 + wm * 128 + mi * 16 + fq * 4 + r;
        int col = bx * 128 + wn * 32 + ni * 16 + fr;
        float v = acc[mi][ni][r] + bias[col];
        out[(size_t)row * N + col] = 1.0f / (1.0f + expf(-v));
      }
}

// ===== batched z GEMM (R16-proven): N=128, BK=64, 2-buffer LDS =============
struct ZDesc { const ushort_t* A; const ushort_t* Bt; ushort_t* out;
               const float* rs0; const float* rs1; int M; int K; };
struct ZDescs { ZDesc d[3]; };

__global__ __launch_bounds__(256) void zgemm_batched_kernel(ZDescs ds) {
  __shared__ ushort_t As[2][8192];
  __shared__ ushort_t Bs[2][8192];
  ZDesc de = ds.d[blockIdx.z];
  int gy = gridDim.y;
  int yq = gy >> 3;
  int ys = (blockIdx.y & 7) * yq + (blockIdx.y >> 3);
  int brow = ys * 128;
  if (brow >= de.M) return;
  int K = de.K;
  int nsteps = K >> 6;
  if (nsteps == 0) nsteps = 1;
  int kkMax = (K >= 64) ? 2 : 1;
  int tid = threadIdx.x;
  int wave = tid >> 6, lane = tid & 63;

  int rowBase = tid >> 3;
  int u = (tid & 7) ^ (rowBase & 7);
  const ushort_t* gA = de.A + (size_t)(brow + rowBase) * K + u * 8;
  const ushort_t* gB = de.Bt + (size_t)rowBase * K + u * 8;

  int fr = lane & 15, fq = lane >> 4;
  f32x4 acc[2][8] = {};

#define STAGE_Z(buf, koff)                                              \
  do {                                                                  \
    _Pragma("unroll")                                                   \
    for (int j = 0; j < 4; ++j) {                                       \
      gload16(gA + (size_t)j * 32 * K + (koff), &As[buf][j * 2048 + tid * 8]); \
      gload16(gB + (size_t)j * 32 * K + (koff), &Bs[buf][j * 2048 + tid * 8]); \
    }                                                                   \
  } while (0)

  STAGE_Z(0, 0);
  int cur = 0;
  for (int i = 0; i < nsteps; ++i) {
    __syncthreads();
    if (i + 1 < nsteps) STAGE_Z(cur ^ 1, (i + 1) * 64);
#pragma unroll
    for (int kk = 0; kk < 2; ++kk) {
      if (kk >= kkMax) break;
      short8v af[2], bfr[8];
#pragma unroll
      for (int mi = 0; mi < 2; ++mi) {
        int row = wave * 32 + mi * 16 + fr;
        af[mi] = *(const short8v*)(&As[cur][row * 64 + (((kk * 4 + fq) ^ (row & 7)) * 8)]);
      }
#pragma unroll
      for (int ni = 0; ni < 8; ++ni) {
        int row = ni * 16 + fr;
        bfr[ni] = *(const short8v*)(&Bs[cur][row * 64 + (((kk * 4 + fq) ^ (row & 7)) * 8)]);
      }
#pragma unroll
      for (int mi = 0; mi < 2; ++mi)
#pragma unroll
        for (int ni = 0; ni < 8; ++ni)
          acc[mi][ni] = __builtin_amdgcn_mfma_f32_16x16x32_bf16(af[mi], bfr[ni], acc[mi][ni], 0, 0, 0);
    }
    cur ^= 1;
  }
#undef STAGE_Z

#pragma unroll
  for (int mi = 0; mi < 2; ++mi)
#pragma unroll
    for (int ni = 0; ni < 8; ++ni) {
      const float* rs = (ni < 4) ? de.rs0 : de.rs1;
#pragma unroll
      for (int r = 0; r < 4; ++r) {
        int row = brow + wave * 32 + mi * 16 + fq * 4 + r;
        int col = ni * 16 + fr;
        de.out[(size_t)row * 128 + col] = f2bf(acc[mi][ni][r] * rs[row]);
      }
    }
}

// ===== batched CSR gather: dwordx4 per edge-slot (u16 indices) =============
// lane = (h, c): h = edge slot, c = col group of 8 cols -> one 16B load/edge.
struct GDesc { const ushort_t* z0; const uint_t* rp0; const ushort_t* cs0; const float* s0;
               const ushort_t* z1; const uint_t* rp1; const ushort_t* cs1; const float* s1;
               const float* b0; const float* b1; ushort_t* out; int nd; };
struct GDescs { GDesc d[3]; };

__device__ __forceinline__ void acc8(float* __restrict__ a, uint4v v) {
  a[0] += bf2f_lo(v[0]); a[1] += bf2f_hi(v[0]);
  a[2] += bf2f_lo(v[1]); a[3] += bf2f_hi(v[1]);
  a[4] += bf2f_lo(v[2]); a[5] += bf2f_hi(v[2]);
  a[6] += bf2f_lo(v[3]); a[7] += bf2f_hi(v[3]);
}

// width-64 z (stride kZS): 8 edge slots (h=lane>>3), col group c=lane&7
__device__ __forceinline__ void gsum64(const ushort_t* __restrict__ z,
                                       const ushort_t* __restrict__ cs,
                                       uint_t e, uint_t ee, int h, int off,
                                       float* __restrict__ a) {
  for (; e + 16 <= ee; e += 16) {
    uint_t sA = cs[e + h], sB = cs[e + 8 + h];
    uint4v vA = *(const uint4v*)(z + (size_t)sA * kZS + off);
    uint4v vB = *(const uint4v*)(z + (size_t)sB * kZS + off);
    acc8(a, vA); acc8(a, vB);
  }
  for (; e + 8 <= ee; e += 8) {
    uint4v v = *(const uint4v*)(z + (size_t)cs[e + h] * kZS + off);
    acc8(a, v);
  }
  if ((uint_t)h < ee - e) {
    uint4v v = *(const uint4v*)(z + (size_t)cs[e + h] * kZS + off);
    acc8(a, v);
  }
}

__global__ __launch_bounds__(256) void gather_batched_kernel(GDescs ds) {
  GDesc de = ds.d[blockIdx.z];
  int d = blockIdx.x * 4 + (threadIdx.x >> 6);
  if (d >= de.nd) return;
  int lane = threadIdx.x & 63;
  int h = lane >> 3, c = lane & 7;
  int off = 8 * c;
  float a0[8] = {}, a1[8] = {};
  gsum64(de.z0, de.cs0, de.rp0[d], de.rp0[d + 1], h, off, a0);
  gsum64(de.z1, de.cs1, de.rp1[d], de.rp1[d + 1], h, off, a1);
  float s0 = de.s0[d], s1 = de.s1[d];
  float v[8];
#pragma unroll
  for (int j = 0; j < 8; ++j) {
    v[j] = a0[j] * s0 + a1[j] * s1;
    v[j] += __shfl_xor(v[j], 8);
    v[j] += __shfl_xor(v[j], 16);
    v[j] += __shfl_xor(v[j], 32);
  }
  if (h == 0) {
    int c0 = off;
    uint4v pack;
#pragma unroll
    for (int j = 0; j < 4; ++j) {
      float x = v[2 * j] + de.b0[c0 + 2 * j] + de.b1[c0 + 2 * j];
      float y = v[2 * j + 1] + de.b0[c0 + 2 * j + 1] + de.b1[c0 + 2 * j + 1];
      pack[j] = (uint_t)f2bf(x) | ((uint_t)f2bf(y) << 16);
    }
    *(uint4v*)(de.out + (size_t)d * 64 + c0) = pack;
  }
}

// width-128 z (stride 128): 4 edge slots (h=lane>>4), col group c=lane&15
__device__ __forceinline__ void gsum128(const ushort_t* __restrict__ z,
                                        const ushort_t* __restrict__ cs,
                                        uint_t e, uint_t ee, int h, int off,
                                        float* __restrict__ a) {
  for (; e + 8 <= ee; e += 8) {
    uint_t sA = cs[e + h], sB = cs[e + 4 + h];
    uint4v vA = *(const uint4v*)(z + (size_t)sA * 128 + off);
    uint4v vB = *(const uint4v*)(z + (size_t)sB * 128 + off);
    acc8(a, vA); acc8(a, vB);
  }
  for (; e + 4 <= ee; e += 4) {
    uint4v v = *(const uint4v*)(z + (size_t)cs[e + h] * 128 + off);
    acc8(a, v);
  }
  if ((uint_t)h < ee - e) {
    uint4v v = *(const uint4v*)(z + (size_t)cs[e + h] * 128 + off);
    acc8(a, v);
  }
}

__global__ __launch_bounds__(256) void gather128_l1_kernel(
    const ushort_t* __restrict__ zD, const uint_t* __restrict__ rpD, const ushort_t* __restrict__ csD,
    const float* __restrict__ sInD,
    const ushort_t* __restrict__ zM, const uint_t* __restrict__ rpM, const ushort_t* __restrict__ csM,
    const float* __restrict__ sInM,
    const float* __restrict__ bD, const float* __restrict__ bM,
    float* __restrict__ emb, ushort_t* __restrict__ embb, int embStride) {
  int d = blockIdx.x * 4 + (threadIdx.x >> 6);
  int lane = threadIdx.x & 63;
  int h = lane >> 4, c = lane & 15;
  int off = 8 * c;                   // cols [8c, 8c+8)
  float aD[8] = {}, aM[8] = {};
  gsum128(zD, csD, rpD[d], rpD[d + 1], h, off, aD);
  gsum128(zM, csM, rpM[d], rpM[d + 1], h, off, aM);
  float sD = sInD[d], sM = sInM[d];
  float v[8];
#pragma unroll
  for (int j = 0; j < 8; ++j) {
    v[j] = aD[j] * sD + aM[j] * sM + bD[off + j] + bM[off + j];
    v[j] += __shfl_xor(v[j], 16);
    v[j] += __shfl_xor(v[j], 32);
  }
  float a = 0;
#pragma unroll
  for (int j = 0; j < 8; ++j) a += fabsf(v[j]);
#pragma unroll
  for (int o = 8; o > 0; o >>= 1) a += __shfl_xor(a, o);
  float l1 = fmaxf(a, 1e-12f);
  if (h == 0) {
    float e0[8];
#pragma unroll
    for (int j = 0; j < 8; ++j) e0[j] = v[j] / l1;
    float* ep_ = emb + (size_t)d * kOUTF + off;
    *(f32x4*)ep_ = {e0[0], e0[1], e0[2], e0[3]};
    *(f32x4*)(ep_ + 4) = {e0[4], e0[5], e0[6], e0[7]};
    uint4v pack;
#pragma unroll
    for (int j = 0; j < 4; ++j)
      pack[j] = (uint_t)f2bf(e0[2 * j]) | ((uint_t)f2bf(e0[2 * j + 1]) << 16);
    *(uint4v*)(embb + (size_t)d * embStride + off) = pack;
  }
}

// ===== split-K reduce with fused bias/act/bf16-out =========================
__global__ void reducek_kernel(const float* __restrict__ P, void* __restrict__ out,
                               int outBf16, int n4, int S, int N,
                               const float* __restrict__ bias, int act) {
  int idx = blockIdx.x * 256 + threadIdx.x;
  if (idx >= n4) return;
  float4 a = ((const float4*)P)[idx];
  for (int s = 1; s < S; ++s) {
    float4 b = ((const float4*)P)[(size_t)s * n4 + idx];
    a.x += b.x; a.y += b.y; a.z += b.z; a.w += b.w;
  }
  float v[4] = {a.x, a.y, a.z, a.w};
  int c0 = (idx * 4) % N;
#pragma unroll
  for (int j = 0; j < 4; ++j) {
    if (bias) v[j] += bias[c0 + j];
    if (act == 1) v[j] = fmaxf(v[j], 0.0f);
    else if (act == 2) v[j] = 1.0f / (1.0f + expf(-v[j]));
  }
  if (outBf16) {
    ushort_t* o = (ushort_t*)out + (size_t)idx * 4;
    o[0] = f2bf(v[0]); o[1] = f2bf(v[1]); o[2] = f2bf(v[2]); o[3] = f2bf(v[3]);
  } else {
    float4 r = {v[0], v[1], v[2], v[3]};
    ((float4*)out)[idx] = r;
  }
}

extern "C" void kernel_launch(void* const* d_in, const int* in_sizes, int n_in,
                              void* d_out, int out_size, void* d_ws, size_t ws_size,
                              hipStream_t stream) {
  const float* h_L = (const float*)d_in[0];
  const float* h_D = (const float*)d_in[1];
  const float* h_M = (const float*)d_in[2];
  const float* Adj = (const float*)d_in[3];
  EdgePtrs ep;
  for (int i = 0; i < 12; ++i) ep.p[i] = (const int*)d_in[4 + i];
  const float* W[3]  = {(const float*)d_in[16], (const float*)d_in[18], (const float*)d_in[20]};
  const float* Bb[3] = {(const float*)d_in[17], (const float*)d_in[19], (const float*)d_in[21]};
  const float* f1_w = (const float*)d_in[22];
  const float* f1_b = (const float*)d_in[23];
  const float* f2_w = (const float*)d_in[24];
  const float* f2_b = (const float*)d_in[25];
  const float* f3_w = (const float*)d_in[26];
  const float* f3_b = (const float*)d_in[27];
  const float* f4_w = (const float*)d_in[28];
  const float* f4_b = (const float*)d_in[29];

  // ---- workspace layout ----
  float* ws = (float*)d_ws;
  size_t off = 0;
  auto allocF = [&](size_t n) { float* p = ws + off; off += (n + 3) & ~(size_t)3; return p; };
  auto allocU = [&](size_t n) { return (uint_t*)allocF(n); };
  auto allocB = [&](size_t n) { return (ushort_t*)allocF((n + 1) / 2); };

  uint_t* part   = allocU((size_t)12 * kHB * 16384);   // 12.6 MB, reused as z bufs
  uint_t* cnts   = allocU((size_t)12 * 16384);
  float*  degscale = allocF((size_t)12 * 16384);
  uint_t* rp_all = allocU(45062 + 2);
  uint_t* ofs    = allocU((size_t)6 * kHB * 16384);
  ushort_t* csr  = allocB((size_t)6 * kE);            // u16 CSR (src ids < 16384)
  ushort_t* hLb  = allocB((size_t)kNL * kFEAT);
  ushort_t* hDb  = allocB((size_t)kND * kFEAT);
  ushort_t* hMb  = allocB((size_t)kNM * kFEAT);
  ushort_t* xin  = allocB((size_t)kSIZE * kXIN);   // [Adj | emb] bf16, stride 4224
  ushort_t* aLb  = allocB((size_t)kNL * kHID);
  ushort_t* aDb  = allocB((size_t)kND * kHID);
  ushort_t* aMb  = allocB((size_t)kNM * kHID);
  ushort_t* WLt  = allocB((size_t)128 * kFEAT);
  ushort_t* WDt  = allocB((size_t)128 * kFEAT);
  ushort_t* WMt  = allocB((size_t)128 * kFEAT);
  ushort_t* WL2t = allocB((size_t)128 * kHID);
  ushort_t* WD2t = allocB((size_t)128 * kHID);
  ushort_t* WM2t = allocB((size_t)128 * kHID);
  ushort_t* W3t1 = allocB((size_t)kOUTF * kHID);
  ushort_t* W3t3 = allocB((size_t)kOUTF * kHID);
  ushort_t* f1t  = allocB((size_t)256 * kXIN);
  ushort_t* f2t  = allocB((size_t)512 * 256);
  ushort_t* f3t  = allocB((size_t)1024 * 512);
  ushort_t* f4t  = allocB((size_t)kITEMS * 1024);
  ushort_t* x1b  = allocB((size_t)kSIZE * 256);
  ushort_t* x2b  = allocB((size_t)kSIZE * 512);
  ushort_t* x3b  = allocB((size_t)kSIZE * 1024);

  // shared split-K partials (f1 S=6: 3.15M, f2 S=4: 4.19M, f3 S=2: 4.19M floats)
  int S1 = 1, S2 = 1, S3 = 1;
  float* partK = nullptr;
  size_t avail = (ws_size / 4 > off) ? ws_size / 4 - off - 64 : 0;
  if (avail >= (size_t)4 * kSIZE * 512 + 16) {
    partK = allocF((size_t)4 * kSIZE * 512);
    S1 = 6; S2 = 4; S3 = 2;
  }

  // z buffers alias `part` (dead after chunkofs/fill)
  ushort_t* zL  = (ushort_t*)part;                       // 16384 x 128
  ushort_t* zD  = zL + (size_t)kNL * kZS;                // 4096 x 128
  ushort_t* zM  = zD + (size_t)kND * kZS;                // 2048 x 128
  ushort_t* zD3 = zM + (size_t)kNM * kZS;                // 4096 x 128
  ushort_t* zM3 = zD3 + (size_t)kND * kZS;               // 2048 x 128

  I6 ndI; const int ndst_[6] = {kND, kNL, kNM, kNL, kNM, kND};
  for (int t = 0; t < 6; ++t) ndI.v[t] = ndst_[t];
  I6 rpo; { int r = 0; for (int t = 0; t < 6; ++t) { rpo.v[t] = r; r += ndst_[t] + 1; } }
  auto dsc = [&](int k) { return degscale + ((size_t)k << 14); };

  // ---- 1) hist (64KB LDS) then prep (4.2KB LDS, high occupancy) ----
  hist_kernel<<<12 * kHB, 256, 0, stream>>>(ep, part);

  PJobs pj; int nj = 0; int totblk = 0;
  auto addCvt = [&](const float* in, ushort_t* out, size_t n) {
    int n4 = (int)(n / 4);
    pj.j[nj] = {in, out, n4, 0, 0, 0, (n4 + 255) / 256}; totblk += pj.j[nj].nblk; ++nj;
  };
  auto addStrided = [&](const float* in, ushort_t* out, size_t n, int rowLen, int stride) {
    int n4 = (int)(n / 4);
    pj.j[nj] = {in, out, n4, rowLen / 4, stride, 2, (n4 + 255) / 256}; totblk += pj.j[nj].nblk; ++nj;
  };
  auto addT = [&](const float* in, ushort_t* out, int K, int N) {
    pj.j[nj] = {in, out, K, N, 0, 1, (N / 32) * (K / 32)}; totblk += pj.j[nj].nblk; ++nj;
  };
  addCvt(h_L, hLb, (size_t)kNL * kFEAT);
  addCvt(h_D, hDb, (size_t)kND * kFEAT);
  addCvt(h_M, hMb, (size_t)kNM * kFEAT);
  addStrided(Adj, xin, (size_t)kSIZE * kITEMS, kITEMS, kXIN);
  addT(W[0] + (size_t)0 * kFEAT * kHID, WLt + (size_t)0 * kFEAT, kFEAT, kHID);
  addT(W[0] + (size_t)2 * kFEAT * kHID, WLt + (size_t)64 * kFEAT, kFEAT, kHID);
  addT(W[0] + (size_t)1 * kFEAT * kHID, WDt + (size_t)0 * kFEAT, kFEAT, kHID);
  addT(W[0] + (size_t)4 * kFEAT * kHID, WDt + (size_t)64 * kFEAT, kFEAT, kHID);
  addT(W[0] + (size_t)3 * kFEAT * kHID, WMt + (size_t)0 * kFEAT, kFEAT, kHID);
  addT(W[0] + (size_t)5 * kFEAT * kHID, WMt + (size_t)64 * kFEAT, kFEAT, kHID);
  addT(W[1] + (size_t)0 * kHID * kHID, WL2t + (size_t)0 * kHID, kHID, kHID);
  addT(W[1] + (size_t)2 * kHID * kHID, WL2t + (size_t)64 * kHID, kHID, kHID);
  addT(W[1] + (size_t)1 * kHID * kHID, WD2t + (size_t)0 * kHID, kHID, kHID);
  addT(W[1] + (size_t)4 * kHID * kHID, WD2t + (size_t)64 * kHID, kHID, kHID);
  addT(W[1] + (size_t)3 * kHID * kHID, WM2t + (size_t)0 * kHID, kHID, kHID);
  addT(W[1] + (size_t)5 * kHID * kHID, WM2t + (size_t)64 * kHID, kHID, kHID);
  addT(W[2] + (size_t)1 * kHID * kOUTF, W3t1, kHID, kOUTF);
  addT(W[2] + (size_t)3 * kHID * kOUTF, W3t3, kHID, kOUTF);
  addT(f1_w, f1t, kXIN, 256);
  addT(f2_w, f2t, 256, 512);
  addT(f3_w, f3t, 512, 1024);
  addT(f4_w, f4t, 1024, kITEMS);
  pj.n = nj;
  prep_kernel<<<totblk, 256, 0, stream>>>(pj);

  // ---- 2) CSR metadata chain + fill ----
  reduce_finalize_kernel<<<12 * 16384 / 256, 256, 0, stream>>>(part, cnts, degscale);
  scan_kernel<<<6, 1024, 0, stream>>>(cnts, rp_all, rpo, ndI);
  chunkofs_kernel<<<6 * 16384 / 256, 256, 0, stream>>>(part, rp_all, rpo, ndI, ofs);
  fill_kernel<<<6 * kHB, 256, 0, stream>>>(ep, ofs, csr);

  // ---- 3) GNN layers 1 & 2 ----
  const ushort_t* curb[3] = {hLb, hDb, hMb};
  for (int layer = 0; layer < 2; ++layer) {
    int K = (layer == 0) ? kFEAT : kHID;
    const ushort_t* WtL = (layer == 0) ? WLt : WL2t;
    const ushort_t* WtD = (layer == 0) ? WDt : WD2t;
    const ushort_t* WtM = (layer == 0) ? WMt : WM2t;
    const float* bl = Bb[layer];
    ZDescs zd;
    zd.d[0] = {curb[0], WtL, zL, dsc(0), dsc(4),  kNL, K};
    zd.d[1] = {curb[1], WtD, zD, dsc(2), dsc(8),  kND, K};
    zd.d[2] = {curb[2], WtM, zM, dsc(6), dsc(10), kNM, K};
    zgemm_batched_kernel<<<dim3(1, kNL / 128, 3), 256, 0, stream>>>(zd);
    if (layer == 0) {
      GDescs gd;
      gd.d[0] = {zD, rp_all + rpo.v[1], csr + (size_t)1 * kE, dsc(3),
                 zM, rp_all + rpo.v[3], csr + (size_t)3 * kE, dsc(7),
                 bl + 1 * kHID, bl + 3 * kHID, aLb, kNL};
      gd.d[1] = {zL, rp_all + rpo.v[0], csr + (size_t)0 * kE, dsc(1),
                 zM + 64, rp_all + rpo.v[5], csr + (size_t)5 * kE, dsc(11),
                 bl + 0 * kHID, bl + 5 * kHID, aDb, kND};
      gd.d[2] = {zL + 64, rp_all + rpo.v[2], csr + (size_t)2 * kE, dsc(5),
                 zD + 64, rp_all + rpo.v[4], csr + (size_t)4 * kE, dsc(9),
                 bl + 2 * kHID, bl + 4 * kHID, aMb, kNM};
      gather_batched_kernel<<<dim3(kNL / 4, 1, 3), 256, 0, stream>>>(gd);
    } else {
      // layer-3 consumes only aDb/aMb -> skip dead aLb gather (70% of work)
      GDescs gd;
      gd.d[0] = {zL, rp_all + rpo.v[0], csr + (size_t)0 * kE, dsc(1),
                 zM + 64, rp_all + rpo.v[5], csr + (size_t)5 * kE, dsc(11),
                 bl + 0 * kHID, bl + 5 * kHID, aDb, kND};
      gd.d[1] = {zL + 64, rp_all + rpo.v[2], csr + (size_t)2 * kE, dsc(5),
                 zD + 64, rp_all + rpo.v[4], csr + (size_t)4 * kE, dsc(9),
                 bl + 2 * kHID, bl + 4 * kHID, aMb, kNM};
      gd.d[2] = gd.d[1];
      gather_batched_kernel<<<dim3(kND / 4, 1, 2), 256, 0, stream>>>(gd);
    }
    curb[0] = aLb; curb[1] = aDb; curb[2] = aMb;
  }

  // ---- 4) layer 3 (types 1: D->L, 3: M->L; rows < 2048) + L1 norm ----
  float* emb  = (float*)d_out;
  float* outx = (float*)d_out + (size_t)kSIZE * kOUTF;
  {
    ZDescs zd;
    zd.d[0] = {curb[1], W3t1, zD3, dsc(2), dsc(2), kND, kHID};
    zd.d[1] = {curb[2], W3t3, zM3, dsc(6), dsc(6), kNM, kHID};
    zd.d[2] = zd.d[1];
    zgemm_batched_kernel<<<dim3(1, kND / 128, 2), 256, 0, stream>>>(zd);
    gather128_l1_kernel<<<kSIZE / 4, 256, 0, stream>>>(
        zD3, rp_all + rpo.v[1], csr + (size_t)1 * kE, dsc(3),
        zM3, rp_all + rpo.v[3], csr + (size_t)3 * kE, dsc(7),
        Bb[2] + 1 * kOUTF, Bb[2] + 3 * kOUTF, emb, xin + kITEMS, kXIN);
  }

  // ---- 5) MLP ----
  if (S1 > 1) {
    gemm_bf16_kernel<<<dim3(2, 16, S1), 256, 0, stream>>>(
        xin, f1t, nullptr, nullptr, 0, kSIZE, 256, kXIN, kXIN,
        nullptr, 0, kXIN / S1, partK);
    int n4 = kSIZE * 256 / 4;
    reducek_kernel<<<(n4 + 255) / 256, 256, 0, stream>>>(
        partK, x1b, 1, n4, S1, 256, f1_b, 1);
  } else {
    gemm_bf16_kernel<<<dim3(2, 16, 1), 256, 0, stream>>>(
        xin, f1t, nullptr, x1b, 1, kSIZE, 256, kXIN, kXIN, f1_b, 1, 0, nullptr);
  }
  if (S2 > 1) {
    gemm_bf16_kernel<<<dim3(4, 16, S2), 256, 0, stream>>>(
        x1b, f2t, nullptr, nullptr, 0, kSIZE, 512, 256, 256,
        nullptr, 0, 256 / S2, partK);
    int n4 = kSIZE * 512 / 4;
    reducek_kernel<<<(n4 + 255) / 256, 256, 0, stream>>>(
        partK, x2b, 1, n4, S2, 512, f2_b, 1);
  } else {
    gemm_bf16_kernel<<<dim3(4, 16, 1), 256, 0, stream>>>(
        x1b, f2t, nullptr, x2b, 1, kSIZE, 512, 256, 256, f2_b, 1, 0, nullptr);
  }
  if (S3 > 1) {
    gemm_bf16_kernel<<<dim3(8, 16, S3), 256, 0, stream>>>(
        x2b, f3t, nullptr, nullptr, 0, kSIZE, 1024, 512, 512,
        nullptr, 0, 512 / S3, partK);
    int n4 = kSIZE * 1024 / 4;
    reducek_kernel<<<(n4 + 255) / 256, 256, 0, stream>>>(
        partK, x3b, 1, n4, S3, 1024, f3_b, 1);
  } else {
    gemm_bf16_kernel<<<dim3(8, 16, 1), 256, 0, stream>>>(
        x2b, f3t, nullptr, x3b, 1, kSIZE, 1024, 512, 512, f3_b, 1, 0, nullptr);
  }
  // f4: m201-schedule 256x128 kernel, fused bias+sigmoid, fp32 out
  gemm256_kernel<<<dim3(kITEMS / 128, kSIZE / 256), 512, 0, stream>>>(
      x3b, f4t, outx, kSIZE, kITEMS, 1024, f4_b);
}

// Round 21
// 256.913 us; speedup vs baseline: 1.2558x; 1.1228x over previous
//
#include <hip/hip_runtime.h>

constexpr int kNL = 16384, kND = 4096, kNM = 2048;
constexpr int kE = 262144;              // 2^18
constexpr int kFEAT = 256, kHID = 64, kOUTF = 128;
constexpr int kITEMS = 4096, kSIZE = 2048;
constexpr int kHB = 16;                 // histogram chunks per index array
constexpr int kZS = 128;                // z row stride (merged 2-type layout)
constexpr int kXIN = kITEMS + kOUTF;    // 4224

typedef unsigned short ushort_t;
typedef unsigned int uint_t;
typedef __attribute__((ext_vector_type(8))) short short8v;
typedef __attribute__((ext_vector_type(4))) float f32x4;
typedef __attribute__((ext_vector_type(4))) uint_t uint4v;
typedef __attribute__((ext_vector_type(4))) int int4v;

struct EdgePtrs { const int* p[12]; };
struct I6 { int v[6]; };

__device__ inline ushort_t f2bf(float f) {
  unsigned u = __builtin_bit_cast(unsigned, f);
  unsigned r = u + 0x7fffu + ((u >> 16) & 1u);
  return (ushort_t)(r >> 16);
}
__device__ inline float bf2f(ushort_t b) {
  unsigned u = ((unsigned)b) << 16;
  return __builtin_bit_cast(float, u);
}
__device__ inline float bf2f_lo(uint_t v) { return __builtin_bit_cast(float, v << 16); }
__device__ inline float bf2f_hi(uint_t v) { return __builtin_bit_cast(float, v & 0xffff0000u); }

// async global->LDS, 16 B per lane (global_load_lds_dwordx4)
__device__ __forceinline__ void gload16(const ushort_t* g, ushort_t* l) {
  __builtin_amdgcn_global_load_lds(
      (const __attribute__((address_space(1))) void*)g,
      (__attribute__((address_space(3))) void*)l, 16, 0, 0);
}

// bijective XCD swizzle (m204)
__device__ __forceinline__ void xcd_swizzle(int& bx, int& by) {
  int gx = gridDim.x, gy = gridDim.y;
  int nwg = gx * gy;
  int orig = by * gx + bx;
  int q = nwg >> 3, r = nwg & 7;
  int xcd = orig & 7, loc = orig >> 3;
  int s = ((xcd < r) ? xcd * (q + 1) : r * (q + 1) + (xcd - r) * q) + loc;
  by = s % gy;
  bx = s / gy;
}

// ===== hist: standalone (64 KB LDS only here), int4 edge loads =============
__global__ __launch_bounds__(256) void hist_kernel(EdgePtrs ep, uint_t* __restrict__ part) {
  __shared__ uint_t bins[16384];
  int k = blockIdx.x >> 4, chunk = blockIdx.x & (kHB - 1);
  uint4v zero = {0, 0, 0, 0};
  for (int i = threadIdx.x; i < 4096; i += 256) ((uint4v*)bins)[i] = zero;
  __syncthreads();
  const int4v* arr = (const int4v*)(ep.p[k] + chunk * (kE / kHB));
  for (int i = threadIdx.x; i < kE / kHB / 4; i += 256) {
    int4v e4 = arr[i];
    atomicAdd(&bins[e4[0]], 1u);
    atomicAdd(&bins[e4[1]], 1u);
    atomicAdd(&bins[e4[2]], 1u);
    atomicAdd(&bins[e4[3]], 1u);
  }
  __syncthreads();
  uint4v* o = (uint4v*)(part + ((size_t)blockIdx.x << 14));
  for (int i = threadIdx.x; i < 4096; i += 256) o[i] = ((uint4v*)bins)[i];
}

// ===== prep: converts/transposes ONLY (4.2 KB LDS -> high occupancy) =======
struct PJob { const float* in; ushort_t* out; int A; int B; int C; int kind; int nblk; };
struct PJobs { PJob j[24]; int n; };

__global__ __launch_bounds__(256) void prep_kernel(PJobs jobs) {
  __shared__ float t[32][33];
  int b = blockIdx.x;
  int ji = 0;
  while (ji < jobs.n && b >= jobs.j[ji].nblk) { b -= jobs.j[ji].nblk; ++ji; }
  if (ji >= jobs.n) return;
  PJob jb = jobs.j[ji];
  if (jb.kind == 0) {                       // flat convert, A = n4
    int idx = b * 256 + threadIdx.x;
    if (idx >= jb.A) return;
    float4 v = ((const float4*)jb.in)[idx];
    ushort_t* o = jb.out + (size_t)idx * 4;
    o[0] = f2bf(v.x); o[1] = f2bf(v.y); o[2] = f2bf(v.z); o[3] = f2bf(v.w);
  } else if (jb.kind == 2) {                // strided convert: A=n4, B=rowLen4, C=outStride
    int idx = b * 256 + threadIdx.x;
    if (idx >= jb.A) return;
    float4 v = ((const float4*)jb.in)[idx];
    int row = idx / jb.B, col4 = idx - row * jb.B;
    ushort_t* o = jb.out + (size_t)row * jb.C + (size_t)col4 * 4;
    o[0] = f2bf(v.x); o[1] = f2bf(v.y); o[2] = f2bf(v.z); o[3] = f2bf(v.w);
  } else {                                  // transpose: in [K][N] -> out [N][K]; A=K, B=N
    int K = jb.A, N = jb.B;
    int tpr = N >> 5;
    int n0 = (b % tpr) * 32, k0 = (b / tpr) * 32;
    int tx = threadIdx.x & 31, ty = threadIdx.x >> 5;
#pragma unroll
    for (int i = 0; i < 32; i += 8)
      t[ty + i][tx] = jb.in[(size_t)(k0 + ty + i) * N + n0 + tx];
    __syncthreads();
#pragma unroll
    for (int i = 0; i < 32; i += 8)
      jb.out[(size_t)(n0 + ty + i) * K + k0 + tx] = f2bf(t[tx][ty + i]);
  }
}

// ===== CSR metadata chain (R12-proven: wide grids) =========================
__global__ void reduce_finalize_kernel(const uint_t* __restrict__ part,
                                       uint_t* __restrict__ cnts,
                                       float* __restrict__ degscale) {
  int idx = blockIdx.x * 256 + threadIdx.x;   // grid = 12*16384/256
  int k = idx >> 14, bin = idx & 16383;
  uint_t s = 0;
  for (int c = 0; c < kHB; ++c) s += part[((size_t)(k * kHB + c) << 14) + bin];
  cnts[idx] = s;
  degscale[idx] = rsqrtf((float)max(s, 1u));
}

__global__ __launch_bounds__(1024) void scan_kernel(const uint_t* __restrict__ cnts,
                                                    uint_t* __restrict__ rp_all,
                                                    I6 rpoff, I6 nd) {
  __shared__ uint_t sums[1024];
  int t = blockIdx.x;
  int n = nd.v[t];
  const uint_t* c = cnts + ((size_t)(2 * t + 1) << 14);
  uint_t* rp = rp_all + rpoff.v[t];
  int tid = threadIdx.x;
  int seg = n >> 10;
  uint_t s = 0;
  for (int j = 0; j < seg; ++j) s += c[tid * seg + j];
  sums[tid] = s;
  __syncthreads();
  for (int o = 1; o < 1024; o <<= 1) {
    uint_t v = (tid >= o) ? sums[tid - o] : 0u;
    __syncthreads();
    sums[tid] += v;
    __syncthreads();
  }
  uint_t run = sums[tid] - s;   // exclusive
  for (int j = 0; j < seg; ++j) { rp[tid * seg + j] = run; run += c[tid * seg + j]; }
  if (tid == 1023) rp[n] = run;
}

__global__ void chunkofs_kernel(const uint_t* __restrict__ part,
                                const uint_t* __restrict__ rp_all,
                                I6 rpoff, I6 nd, uint_t* __restrict__ ofs) {
  int idx = blockIdx.x * 256 + threadIdx.x;   // grid = 6*16384/256
  int t = idx >> 14, bin = idx & 16383;
  if (bin >= nd.v[t]) return;
  uint_t run = (rp_all + rpoff.v[t])[bin];
  for (int c = 0; c < kHB; ++c) {
    ofs[((size_t)(t * kHB + c) << 14) + bin] = run;
    run += part[((size_t)((2 * t + 1) * kHB + c) << 14) + bin];
  }
}

__global__ __launch_bounds__(256) void fill_kernel(EdgePtrs ep,
                                                   const uint_t* __restrict__ ofs,
                                                   ushort_t* __restrict__ csr_all) {
  __shared__ uint_t cursor[16384];
  int t = blockIdx.x >> 4, chunk = blockIdx.x & (kHB - 1);
  const uint_t* o = ofs + ((size_t)(t * kHB + chunk) << 14);
  for (int i = threadIdx.x; i < 16384; i += 256) cursor[i] = o[i];
  __syncthreads();
  int base = chunk * (kE / kHB);
  const int4v* srcp = (const int4v*)(ep.p[2 * t] + base);
  const int4v* dstp = (const int4v*)(ep.p[2 * t + 1] + base);
  ushort_t* csr = csr_all + (size_t)t * kE;
  for (int i = threadIdx.x; i < kE / kHB / 4; i += 256) {
    int4v d4 = dstp[i];
    int4v s4 = srcp[i];
#pragma unroll
    for (int j = 0; j < 4; ++j) {
      uint_t pos = atomicAdd(&cursor[d4[j]], 1u);
      csr[pos] = (ushort_t)s4[j];
    }
  }
}

// ===== generic bf16 MFMA GEMM, 128x128 tile, BK=64, 2-buffer (R8) ==========
__global__ __launch_bounds__(256) void gemm_bf16_kernel(
    const ushort_t* __restrict__ A, const ushort_t* __restrict__ Bt,
    const float* __restrict__ Cin, void* __restrict__ out, int outBf16,
    int M, int N, int K, int ldb,
    const float* __restrict__ bias, int act,
    int kChunk, float* __restrict__ partOut) {
  __shared__ ushort_t As[2][8192];   // 2 x 16 KB
  __shared__ ushort_t Bs[2][8192];
  int tid = threadIdx.x;
  int wave = tid >> 6, lane = tid & 63;
  int bx = blockIdx.x, by = blockIdx.y;
  xcd_swizzle(bx, by);
  int brow = by * 128, bcol = bx * 128;
  int kStart = partOut ? blockIdx.z * kChunk : 0;
  int kLen = partOut ? kChunk : K;
  int nsteps = kLen >> 6;              // BK = 64

  int rowBase = tid >> 3;              // 0..31
  int u = (tid & 7) ^ (rowBase & 7);
  const ushort_t* gA = A + (size_t)(brow + rowBase) * K + kStart + u * 8;
  const ushort_t* gB = Bt + (size_t)(bcol + rowBase) * ldb + kStart + u * 8;

  int fr = lane & 15, fq = lane >> 4;
  f32x4 acc[2][8] = {};

#define STAGE_G(buf, koff)                                              \
  do {                                                                  \
    _Pragma("unroll")                                                   \
    for (int j = 0; j < 4; ++j) {                                       \
      gload16(gA + (size_t)j * 32 * K + (koff), &As[buf][j * 2048 + tid * 8]);   \
      gload16(gB + (size_t)j * 32 * ldb + (koff), &Bs[buf][j * 2048 + tid * 8]); \
    }                                                                   \
  } while (0)

  STAGE_G(0, 0);
  int cur = 0;
  for (int i = 0; i < nsteps; ++i) {
    __syncthreads();
    if (i + 1 < nsteps) STAGE_G(cur ^ 1, (i + 1) * 64);
#pragma unroll
    for (int kk = 0; kk < 2; ++kk) {
      short8v af[2], bfr[8];
#pragma unroll
      for (int mi = 0; mi < 2; ++mi) {
        int row = wave * 32 + mi * 16 + fr;
        af[mi] = *(const short8v*)(&As[cur][row * 64 + (((kk * 4 + fq) ^ (row & 7)) * 8)]);
      }
#pragma unroll
      for (int ni = 0; ni < 8; ++ni) {
        int row = ni * 16 + fr;
        bfr[ni] = *(const short8v*)(&Bs[cur][row * 64 + (((kk * 4 + fq) ^ (row & 7)) * 8)]);
      }
#pragma unroll
      for (int mi = 0; mi < 2; ++mi)
#pragma unroll
        for (int ni = 0; ni < 8; ++ni)
          acc[mi][ni] = __builtin_amdgcn_mfma_f32_16x16x32_bf16(af[mi], bfr[ni], acc[mi][ni], 0, 0, 0);
    }
    cur ^= 1;
  }
#undef STAGE_G

  if (partOut) {
    float* o = partOut + (size_t)blockIdx.z * M * N;
#pragma unroll
    for (int mi = 0; mi < 2; ++mi)
#pragma unroll
      for (int ni = 0; ni < 8; ++ni)
#pragma unroll
        for (int r = 0; r < 4; ++r) {
          int row = brow + wave * 32 + mi * 16 + fq * 4 + r;
          int col = bcol + ni * 16 + fr;
          o[(size_t)row * N + col] = acc[mi][ni][r];
        }
    return;
  }
#pragma unroll
  for (int mi = 0; mi < 2; ++mi)
#pragma unroll
    for (int ni = 0; ni < 8; ++ni)
#pragma unroll
      for (int r = 0; r < 4; ++r) {
        int row = brow + wave * 32 + mi * 16 + fq * 4 + r;
        int col = bcol + ni * 16 + fr;
        float v = acc[mi][ni][r];
        if (Cin) v += Cin[(size_t)row * N + col];
        if (bias) v += bias[col];
        if (act == 1) v = fmaxf(v, 0.0f);
        else if (act == 2) v = 1.0f / (1.0f + expf(-v));
        if (outBf16) ((ushort_t*)out)[(size_t)row * N + col] = f2bf(v);
        else ((float*)out)[(size_t)row * N + col] = v;
      }
}

// ===== m201-schedule GEMM for f4: BM=256 BN=128 BK=64, 512 thr, 3-buf ======
__global__ __launch_bounds__(512) void gemm256_kernel(
    const ushort_t* __restrict__ A, const ushort_t* __restrict__ Bt,
    float* __restrict__ out, int M, int N, int K,
    const float* __restrict__ bias) {
  __shared__ ushort_t As[3][16384];   // 3 x 32 KB
  __shared__ ushort_t Bs[3][8192];    // 3 x 16 KB
  int tid = threadIdx.x;
  int wave = tid >> 6, lane = tid & 63;
  int bx = blockIdx.x, by = blockIdx.y;
  xcd_swizzle(bx, by);
  int fr = lane & 15, fq = lane >> 4;
  int wm = wave >> 2, wn = wave & 3;

  int rquot = tid >> 3;                // 0..63
  int uslot = (tid & 7) ^ (rquot & 7); // pre-swizzled global slot
  const ushort_t* gA = A + (size_t)(by * 256 + rquot) * K + uslot * 8;
  const ushort_t* gB = Bt + (size_t)(bx * 128 + rquot) * K + uslot * 8;

  f32x4 acc[8][2] = {};
  int nsteps = K >> 6;

#define SG_A(b_, t_, j_) gload16(gA + (size_t)(j_) * 64 * K + (size_t)(t_) * 64, &As[b_][(j_) * 4096 + tid * 8])
#define SG_B(b_, t_, j_) gload16(gB + (size_t)(j_) * 64 * K + (size_t)(t_) * 64, &Bs[b_][(j_) * 4096 + tid * 8])

  SG_A(0, 0, 0); SG_A(0, 0, 1); SG_A(0, 0, 2); SG_A(0, 0, 3); SG_B(0, 0, 0); SG_B(0, 0, 1);
  SG_A(1, 1, 0); SG_A(1, 1, 1); SG_A(1, 1, 2); SG_A(1, 1, 3); SG_B(1, 1, 0); SG_B(1, 1, 1);
  asm volatile("s_waitcnt vmcnt(6)" ::: "memory");
  __builtin_amdgcn_s_barrier();

  short8v bf[2][2];

#define PHASE(p_)                                                            \
  {                                                                          \
    short8v af[4][2];                                                        \
    _Pragma("unroll")                                                        \
    for (int q = 0; q < 4; ++q) {                                            \
      int row = wm * 128 + (4 * (p_) + q) * 16 + fr;                         \
      int base = row * 64;                                                   \
      af[q][0] = *(const short8v*)(&As[b][base + ((fq ^ (row & 7)) * 8)]);   \
      af[q][1] = *(const short8v*)(&As[b][base + (((4 + fq) ^ (row & 7)) * 8)]); \
    }                                                                        \
    if ((p_) == 0) {                                                         \
      _Pragma("unroll")                                                      \
      for (int q = 0; q < 2; ++q) {                                          \
        int row = wn * 32 + q * 16 + fr;                                     \
        int base = row * 64;                                                 \
        bf[q][0] = *(const short8v*)(&Bs[b][base + ((fq ^ (row & 7)) * 8)]); \
        bf[q][1] = *(const short8v*)(&Bs[b][base + (((4 + fq) ^ (row & 7)) * 8)]); \
      }                                                                      \
      if (doStage) { SG_A(sb, t + 2, 0); SG_A(sb, t + 2, 1); SG_A(sb, t + 2, 2); SG_A(sb, t + 2, 3); } \
    } else {                                                                 \
      if (doStage) { SG_B(sb, t + 2, 0); SG_B(sb, t + 2, 1); }               \
      if (t + 2 < nsteps)      asm volatile("s_waitcnt vmcnt(6)" ::: "memory"); \
      else if (t + 1 < nsteps) asm volatile("s_waitcnt vmcnt(0)" ::: "memory"); \
    }                                                                        \
    __builtin_amdgcn_s_barrier();                                            \
    asm volatile("s_waitcnt lgkmcnt(0)" ::: "memory");                       \
    __builtin_amdgcn_s_setprio(1);                                           \
    _Pragma("unroll")                                                        \
    for (int kk = 0; kk < 2; ++kk)                                           \
      _Pragma("unroll")                                                      \
      for (int q = 0; q < 4; ++q)                                            \
        _Pragma("unroll")                                                    \
        for (int ni = 0; ni < 2; ++ni)                                       \
          acc[4 * (p_) + q][ni] = __builtin_amdgcn_mfma_f32_16x16x32_bf16(af[q][kk], bf[ni][kk], acc[4 * (p_) + q][ni], 0, 0, 0); \
    __builtin_amdgcn_s_setprio(0);                                           \
    __builtin_amdgcn_s_barrier();                                            \
  }

  for (int t = 0; t < nsteps; ++t) {
    int b = t % 3, sb = (t + 2) % 3;
    bool doStage = (t + 2 < nsteps);
    PHASE(0);
    PHASE(1);
  }
#undef PHASE
#undef SG_A
#undef SG_B

#pragma unroll
  for (int mi = 0; mi < 8; ++mi)
#pragma unroll
    for (int ni = 0; ni < 2; ++ni)
#pragma unroll
      for (int r = 0; r < 4; ++r) {
        int row = by * 256 + wm * 128 + mi * 16 + fq * 4 + r;
        int col = bx * 128 + wn * 32 + ni * 16 + fr;
        float v = acc[mi][ni][r] + bias[col];
        out[(size_t)row * N + col] = 1.0f / (1.0f + expf(-v));
      }
}

// ===== batched z GEMM (R16-proven): N=128, BK=64, 2-buffer LDS =============
struct ZDesc { const ushort_t* A; const ushort_t* Bt; ushort_t* out;
               const float* rs0; const float* rs1; int M; int K; };
struct ZDescs { ZDesc d[3]; };

__global__ __launch_bounds__(256) void zgemm_batched_kernel(ZDescs ds) {
  __shared__ ushort_t As[2][8192];
  __shared__ ushort_t Bs[2][8192];
  ZDesc de = ds.d[blockIdx.z];
  int gy = gridDim.y;
  int yq = gy >> 3;
  int ys = (blockIdx.y & 7) * yq + (blockIdx.y >> 3);
  int brow = ys * 128;
  if (brow >= de.M) return;
  int K = de.K;
  int nsteps = K >> 6;
  if (nsteps == 0) nsteps = 1;
  int kkMax = (K >= 64) ? 2 : 1;
  int tid = threadIdx.x;
  int wave = tid >> 6, lane = tid & 63;

  int rowBase = tid >> 3;
  int u = (tid & 7) ^ (rowBase & 7);
  const ushort_t* gA = de.A + (size_t)(brow + rowBase) * K + u * 8;
  const ushort_t* gB = de.Bt + (size_t)rowBase * K + u * 8;

  int fr = lane & 15, fq = lane >> 4;
  f32x4 acc[2][8] = {};

#define STAGE_Z(buf, koff)                                              \
  do {                                                                  \
    _Pragma("unroll")                                                   \
    for (int j = 0; j < 4; ++j) {                                       \
      gload16(gA + (size_t)j * 32 * K + (koff), &As[buf][j * 2048 + tid * 8]); \
      gload16(gB + (size_t)j * 32 * K + (koff), &Bs[buf][j * 2048 + tid * 8]); \
    }                                                                   \
  } while (0)

  STAGE_Z(0, 0);
  int cur = 0;
  for (int i = 0; i < nsteps; ++i) {
    __syncthreads();
    if (i + 1 < nsteps) STAGE_Z(cur ^ 1, (i + 1) * 64);
#pragma unroll
    for (int kk = 0; kk < 2; ++kk) {
      if (kk >= kkMax) break;
      short8v af[2], bfr[8];
#pragma unroll
      for (int mi = 0; mi < 2; ++mi) {
        int row = wave * 32 + mi * 16 + fr;
        af[mi] = *(const short8v*)(&As[cur][row * 64 + (((kk * 4 + fq) ^ (row & 7)) * 8)]);
      }
#pragma unroll
      for (int ni = 0; ni < 8; ++ni) {
        int row = ni * 16 + fr;
        bfr[ni] = *(const short8v*)(&Bs[cur][row * 64 + (((kk * 4 + fq) ^ (row & 7)) * 8)]);
      }
#pragma unroll
      for (int mi = 0; mi < 2; ++mi)
#pragma unroll
        for (int ni = 0; ni < 8; ++ni)
          acc[mi][ni] = __builtin_amdgcn_mfma_f32_16x16x32_bf16(af[mi], bfr[ni], acc[mi][ni], 0, 0, 0);
    }
    cur ^= 1;
  }
#undef STAGE_Z

#pragma unroll
  for (int mi = 0; mi < 2; ++mi)
#pragma unroll
    for (int ni = 0; ni < 8; ++ni) {
      const float* rs = (ni < 4) ? de.rs0 : de.rs1;
#pragma unroll
      for (int r = 0; r < 4; ++r) {
        int row = brow + wave * 32 + mi * 16 + fq * 4 + r;
        int col = ni * 16 + fr;
        de.out[(size_t)row * 128 + col] = f2bf(acc[mi][ni][r] * rs[row]);
      }
    }
}

// ===== batched CSR gather: dwordx4 per edge-slot (u16 indices) =============
struct GDesc { const ushort_t* z0; const uint_t* rp0; const ushort_t* cs0; const float* s0;
               const ushort_t* z1; const uint_t* rp1; const ushort_t* cs1; const float* s1;
               const float* b0; const float* b1; ushort_t* out; int nd; };
struct GDescs { GDesc d[3]; };

__device__ __forceinline__ void acc8(float* __restrict__ a, uint4v v) {
  a[0] += bf2f_lo(v[0]); a[1] += bf2f_hi(v[0]);
  a[2] += bf2f_lo(v[1]); a[3] += bf2f_hi(v[1]);
  a[4] += bf2f_lo(v[2]); a[5] += bf2f_hi(v[2]);
  a[6] += bf2f_lo(v[3]); a[7] += bf2f_hi(v[3]);
}

// width-64 z (stride kZS): 8 edge slots (h=lane>>3), col group c=lane&7
__device__ __forceinline__ void gsum64(const ushort_t* __restrict__ z,
                                       const ushort_t* __restrict__ cs,
                                       uint_t e, uint_t ee, int h, int off,
                                       float* __restrict__ a) {
  for (; e + 16 <= ee; e += 16) {
    uint_t sA = cs[e + h], sB = cs[e + 8 + h];
    uint4v vA = *(const uint4v*)(z + (size_t)sA * kZS + off);
    uint4v vB = *(const uint4v*)(z + (size_t)sB * kZS + off);
    acc8(a, vA); acc8(a, vB);
  }
  for (; e + 8 <= ee; e += 8) {
    uint4v v = *(const uint4v*)(z + (size_t)cs[e + h] * kZS + off);
    acc8(a, v);
  }
  if ((uint_t)h < ee - e) {
    uint4v v = *(const uint4v*)(z + (size_t)cs[e + h] * kZS + off);
    acc8(a, v);
  }
}

__global__ __launch_bounds__(256) void gather_batched_kernel(GDescs ds) {
  GDesc de = ds.d[blockIdx.z];
  int d = blockIdx.x * 4 + (threadIdx.x >> 6);
  if (d >= de.nd) return;
  int lane = threadIdx.x & 63;
  int h = lane >> 3, c = lane & 7;
  int off = 8 * c;
  float a0[8] = {}, a1[8] = {};
  gsum64(de.z0, de.cs0, de.rp0[d], de.rp0[d + 1], h, off, a0);
  gsum64(de.z1, de.cs1, de.rp1[d], de.rp1[d + 1], h, off, a1);
  float s0 = de.s0[d], s1 = de.s1[d];
  float v[8];
#pragma unroll
  for (int j = 0; j < 8; ++j) {
    v[j] = a0[j] * s0 + a1[j] * s1;
    v[j] += __shfl_xor(v[j], 8);
    v[j] += __shfl_xor(v[j], 16);
    v[j] += __shfl_xor(v[j], 32);
  }
  if (h == 0) {
    int c0 = off;
    uint4v pack;
#pragma unroll
    for (int j = 0; j < 4; ++j) {
      float x = v[2 * j] + de.b0[c0 + 2 * j] + de.b1[c0 + 2 * j];
      float y = v[2 * j + 1] + de.b0[c0 + 2 * j + 1] + de.b1[c0 + 2 * j + 1];
      pack[j] = (uint_t)f2bf(x) | ((uint_t)f2bf(y) << 16);
    }
    *(uint4v*)(de.out + (size_t)d * 64 + c0) = pack;
  }
}

// width-128 z (stride 128): 4 edge slots (h=lane>>4), col group c=lane&15
__device__ __forceinline__ void gsum128(const ushort_t* __restrict__ z,
                                        const ushort_t* __restrict__ cs,
                                        uint_t e, uint_t ee, int h, int off,
                                        float* __restrict__ a) {
  for (; e + 8 <= ee; e += 8) {
    uint_t sA = cs[e + h], sB = cs[e + 4 + h];
    uint4v vA = *(const uint4v*)(z + (size_t)sA * 128 + off);
    uint4v vB = *(const uint4v*)(z + (size_t)sB * 128 + off);
    acc8(a, vA); acc8(a, vB);
  }
  for (; e + 4 <= ee; e += 4) {
    uint4v v = *(const uint4v*)(z + (size_t)cs[e + h] * 128 + off);
    acc8(a, v);
  }
  if ((uint_t)h < ee - e) {
    uint4v v = *(const uint4v*)(z + (size_t)cs[e + h] * 128 + off);
    acc8(a, v);
  }
}

__global__ __launch_bounds__(256) void gather128_l1_kernel(
    const ushort_t* __restrict__ zD, const uint_t* __restrict__ rpD, const ushort_t* __restrict__ csD,
    const float* __restrict__ sInD,
    const ushort_t* __restrict__ zM, const uint_t* __restrict__ rpM, const ushort_t* __restrict__ csM,
    const float* __restrict__ sInM,
    const float* __restrict__ bD, const float* __restrict__ bM,
    float* __restrict__ emb, ushort_t* __restrict__ embb, int embStride) {
  int d = blockIdx.x * 4 + (threadIdx.x >> 6);
  int lane = threadIdx.x & 63;
  int h = lane >> 4, c = lane & 15;
  int off = 8 * c;                   // cols [8c, 8c+8)
  float aD[8] = {}, aM[8] = {};
  gsum128(zD, csD, rpD[d], rpD[d + 1], h, off, aD);
  gsum128(zM, csM, rpM[d], rpM[d + 1], h, off, aM);
  float sD = sInD[d], sM = sInM[d];
  float v[8];
#pragma unroll
  for (int j = 0; j < 8; ++j) {
    v[j] = aD[j] * sD + aM[j] * sM + bD[off + j] + bM[off + j];
    v[j] += __shfl_xor(v[j], 16);
    v[j] += __shfl_xor(v[j], 32);
  }
  float a = 0;
#pragma unroll
  for (int j = 0; j < 8; ++j) a += fabsf(v[j]);
#pragma unroll
  for (int o = 8; o > 0; o >>= 1) a += __shfl_xor(a, o);
  float l1 = fmaxf(a, 1e-12f);
  if (h == 0) {
    float e0[8];
#pragma unroll
    for (int j = 0; j < 8; ++j) e0[j] = v[j] / l1;
    float* ep_ = emb + (size_t)d * kOUTF + off;
    *(f32x4*)ep_ = {e0[0], e0[1], e0[2], e0[3]};
    *(f32x4*)(ep_ + 4) = {e0[4], e0[5], e0[6], e0[7]};
    uint4v pack;
#pragma unroll
    for (int j = 0; j < 4; ++j)
      pack[j] = (uint_t)f2bf(e0[2 * j]) | ((uint_t)f2bf(e0[2 * j + 1]) << 16);
    *(uint4v*)(embb + (size_t)d * embStride + off) = pack;
  }
}

// ===== split-K reduce with fused bias/act/bf16-out =========================
__global__ void reducek_kernel(const float* __restrict__ P, void* __restrict__ out,
                               int outBf16, int n4, int S, int N,
                               const float* __restrict__ bias, int act) {
  int idx = blockIdx.x * 256 + threadIdx.x;
  if (idx >= n4) return;
  float4 a = ((const float4*)P)[idx];
  for (int s = 1; s < S; ++s) {
    float4 b = ((const float4*)P)[(size_t)s * n4 + idx];
    a.x += b.x; a.y += b.y; a.z += b.z; a.w += b.w;
  }
  float v[4] = {a.x, a.y, a.z, a.w};
  int c0 = (idx * 4) % N;
#pragma unroll
  for (int j = 0; j < 4; ++j) {
    if (bias) v[j] += bias[c0 + j];
    if (act == 1) v[j] = fmaxf(v[j], 0.0f);
    else if (act == 2) v[j] = 1.0f / (1.0f + expf(-v[j]));
  }
  if (outBf16) {
    ushort_t* o = (ushort_t*)out + (size_t)idx * 4;
    o[0] = f2bf(v[0]); o[1] = f2bf(v[1]); o[2] = f2bf(v[2]); o[3] = f2bf(v[3]);
  } else {
    float4 r = {v[0], v[1], v[2], v[3]};
    ((float4*)out)[idx] = r;
  }
}

extern "C" void kernel_launch(void* const* d_in, const int* in_sizes, int n_in,
                              void* d_out, int out_size, void* d_ws, size_t ws_size,
                              hipStream_t stream) {
  const float* h_L = (const float*)d_in[0];
  const float* h_D = (const float*)d_in[1];
  const float* h_M = (const float*)d_in[2];
  const float* Adj = (const float*)d_in[3];
  EdgePtrs ep;
  for (int i = 0; i < 12; ++i) ep.p[i] = (const int*)d_in[4 + i];
  const float* W[3]  = {(const float*)d_in[16], (const float*)d_in[18], (const float*)d_in[20]};
  const float* Bb[3] = {(const float*)d_in[17], (const float*)d_in[19], (const float*)d_in[21]};
  const float* f1_w = (const float*)d_in[22];
  const float* f1_b = (const float*)d_in[23];
  const float* f2_w = (const float*)d_in[24];
  const float* f2_b = (const float*)d_in[25];
  const float* f3_w = (const float*)d_in[26];
  const float* f3_b = (const float*)d_in[27];
  const float* f4_w = (const float*)d_in[28];
  const float* f4_b = (const float*)d_in[29];

  // ---- workspace layout ----
  float* ws = (float*)d_ws;
  size_t off = 0;
  auto allocF = [&](size_t n) { float* p = ws + off; off += (n + 3) & ~(size_t)3; return p; };
  auto allocU = [&](size_t n) { return (uint_t*)allocF(n); };
  auto allocB = [&](size_t n) { return (ushort_t*)allocF((n + 1) / 2); };

  uint_t* part   = allocU((size_t)12 * kHB * 16384);   // 12.6 MB, reused as z bufs
  uint_t* cnts   = allocU((size_t)12 * 16384);
  float*  degscale = allocF((size_t)12 * 16384);
  uint_t* rp_all = allocU(45062 + 2);
  uint_t* ofs    = allocU((size_t)6 * kHB * 16384);
  ushort_t* csr  = allocB((size_t)6 * kE);            // u16 CSR (src ids < 16384)
  ushort_t* hLb  = allocB((size_t)kNL * kFEAT);
  ushort_t* hDb  = allocB((size_t)kND * kFEAT);
  ushort_t* hMb  = allocB((size_t)kNM * kFEAT);
  ushort_t* xin  = allocB((size_t)kSIZE * kXIN);   // [Adj | emb] bf16, stride 4224
  ushort_t* aLb  = allocB((size_t)kNL * kHID);
  ushort_t* aDb  = allocB((size_t)kND * kHID);
  ushort_t* aMb  = allocB((size_t)kNM * kHID);
  ushort_t* WLt  = allocB((size_t)128 * kFEAT);
  ushort_t* WDt  = allocB((size_t)128 * kFEAT);
  ushort_t* WMt  = allocB((size_t)128 * kFEAT);
  ushort_t* WL2t = allocB((size_t)128 * kHID);
  ushort_t* WD2t = allocB((size_t)128 * kHID);
  ushort_t* WM2t = allocB((size_t)128 * kHID);
  ushort_t* W3t1 = allocB((size_t)kOUTF * kHID);
  ushort_t* W3t3 = allocB((size_t)kOUTF * kHID);
  ushort_t* f1t  = allocB((size_t)256 * kXIN);
  ushort_t* f2t  = allocB((size_t)512 * 256);
  ushort_t* f3t  = allocB((size_t)1024 * 512);
  ushort_t* f4t  = allocB((size_t)kITEMS * 1024);
  ushort_t* x1b  = allocB((size_t)kSIZE * 256);
  ushort_t* x2b  = allocB((size_t)kSIZE * 512);
  ushort_t* x3b  = allocB((size_t)kSIZE * 1024);

  // shared split-K partials (f1 S=6: 3.15M, f2 S=4: 4.19M, f3 S=2: 4.19M floats)
  int S1 = 1, S2 = 1, S3 = 1;
  float* partK = nullptr;
  size_t avail = (ws_size / 4 > off) ? ws_size / 4 - off - 64 : 0;
  if (avail >= (size_t)4 * kSIZE * 512 + 16) {
    partK = allocF((size_t)4 * kSIZE * 512);
    S1 = 6; S2 = 4; S3 = 2;
  }

  // z buffers alias `part` (dead after chunkofs/fill)
  ushort_t* zL  = (ushort_t*)part;                       // 16384 x 128
  ushort_t* zD  = zL + (size_t)kNL * kZS;                // 4096 x 128
  ushort_t* zM  = zD + (size_t)kND * kZS;                // 2048 x 128
  ushort_t* zD3 = zM + (size_t)kNM * kZS;                // 4096 x 128
  ushort_t* zM3 = zD3 + (size_t)kND * kZS;               // 2048 x 128

  I6 ndI; const int ndst_[6] = {kND, kNL, kNM, kNL, kNM, kND};
  for (int t = 0; t < 6; ++t) ndI.v[t] = ndst_[t];
  I6 rpo; { int r = 0; for (int t = 0; t < 6; ++t) { rpo.v[t] = r; r += ndst_[t] + 1; } }
  auto dsc = [&](int k) { return degscale + ((size_t)k << 14); };

  // ---- 1) hist (64KB LDS) then prep (4.2KB LDS, high occupancy) ----
  hist_kernel<<<12 * kHB, 256, 0, stream>>>(ep, part);

  PJobs pj; int nj = 0; int totblk = 0;
  auto addCvt = [&](const float* in, ushort_t* out, size_t n) {
    int n4 = (int)(n / 4);
    pj.j[nj] = {in, out, n4, 0, 0, 0, (n4 + 255) / 256}; totblk += pj.j[nj].nblk; ++nj;
  };
  auto addStrided = [&](const float* in, ushort_t* out, size_t n, int rowLen, int stride) {
    int n4 = (int)(n / 4);
    pj.j[nj] = {in, out, n4, rowLen / 4, stride, 2, (n4 + 255) / 256}; totblk += pj.j[nj].nblk; ++nj;
  };
  auto addT = [&](const float* in, ushort_t* out, int K, int N) {
    pj.j[nj] = {in, out, K, N, 0, 1, (N / 32) * (K / 32)}; totblk += pj.j[nj].nblk; ++nj;
  };
  addCvt(h_L, hLb, (size_t)kNL * kFEAT);
  addCvt(h_D, hDb, (size_t)kND * kFEAT);
  addCvt(h_M, hMb, (size_t)kNM * kFEAT);
  addStrided(Adj, xin, (size_t)kSIZE * kITEMS, kITEMS, kXIN);
  addT(W[0] + (size_t)0 * kFEAT * kHID, WLt + (size_t)0 * kFEAT, kFEAT, kHID);
  addT(W[0] + (size_t)2 * kFEAT * kHID, WLt + (size_t)64 * kFEAT, kFEAT, kHID);
  addT(W[0] + (size_t)1 * kFEAT * kHID, WDt + (size_t)0 * kFEAT, kFEAT, kHID);
  addT(W[0] + (size_t)4 * kFEAT * kHID, WDt + (size_t)64 * kFEAT, kFEAT, kHID);
  addT(W[0] + (size_t)3 * kFEAT * kHID, WMt + (size_t)0 * kFEAT, kFEAT, kHID);
  addT(W[0] + (size_t)5 * kFEAT * kHID, WMt + (size_t)64 * kFEAT, kFEAT, kHID);
  addT(W[1] + (size_t)0 * kHID * kHID, WL2t + (size_t)0 * kHID, kHID, kHID);
  addT(W[1] + (size_t)2 * kHID * kHID, WL2t + (size_t)64 * kHID, kHID, kHID);
  addT(W[1] + (size_t)1 * kHID * kHID, WD2t + (size_t)0 * kHID, kHID, kHID);
  addT(W[1] + (size_t)4 * kHID * kHID, WD2t + (size_t)64 * kHID, kHID, kHID);
  addT(W[1] + (size_t)3 * kHID * kHID, WM2t + (size_t)0 * kHID, kHID, kHID);
  addT(W[1] + (size_t)5 * kHID * kHID, WM2t + (size_t)64 * kHID, kHID, kHID);
  addT(W[2] + (size_t)1 * kHID * kOUTF, W3t1, kHID, kOUTF);
  addT(W[2] + (size_t)3 * kHID * kOUTF, W3t3, kHID, kOUTF);
  addT(f1_w, f1t, kXIN, 256);
  addT(f2_w, f2t, 256, 512);
  addT(f3_w, f3t, 512, 1024);
  addT(f4_w, f4t, 1024, kITEMS);
  pj.n = nj;
  prep_kernel<<<totblk, 256, 0, stream>>>(pj);

  // ---- 2) CSR metadata chain + fill ----
  reduce_finalize_kernel<<<12 * 16384 / 256, 256, 0, stream>>>(part, cnts, degscale);
  scan_kernel<<<6, 1024, 0, stream>>>(cnts, rp_all, rpo, ndI);
  chunkofs_kernel<<<6 * 16384 / 256, 256, 0, stream>>>(part, rp_all, rpo, ndI, ofs);
  fill_kernel<<<6 * kHB, 256, 0, stream>>>(ep, ofs, csr);

  // ---- 3) GNN layers 1 & 2 ----
  const ushort_t* curb[3] = {hLb, hDb, hMb};
  for (int layer = 0; layer < 2; ++layer) {
    int K = (layer == 0) ? kFEAT : kHID;
    const ushort_t* WtL = (layer == 0) ? WLt : WL2t;
    const ushort_t* WtD = (layer == 0) ? WDt : WD2t;
    const ushort_t* WtM = (layer == 0) ? WMt : WM2t;
    const float* bl = Bb[layer];
    ZDescs zd;
    zd.d[0] = {curb[0], WtL, zL, dsc(0), dsc(4),  kNL, K};
    zd.d[1] = {curb[1], WtD, zD, dsc(2), dsc(8),  kND, K};
    zd.d[2] = {curb[2], WtM, zM, dsc(6), dsc(10), kNM, K};
    zgemm_batched_kernel<<<dim3(1, kNL / 128, 3), 256, 0, stream>>>(zd);
    if (layer == 0) {
      GDescs gd;
      gd.d[0] = {zD, rp_all + rpo.v[1], csr + (size_t)1 * kE, dsc(3),
                 zM, rp_all + rpo.v[3], csr + (size_t)3 * kE, dsc(7),
                 bl + 1 * kHID, bl + 3 * kHID, aLb, kNL};
      gd.d[1] = {zL, rp_all + rpo.v[0], csr + (size_t)0 * kE, dsc(1),
                 zM + 64, rp_all + rpo.v[5], csr + (size_t)5 * kE, dsc(11),
                 bl + 0 * kHID, bl + 5 * kHID, aDb, kND};
      gd.d[2] = {zL + 64, rp_all + rpo.v[2], csr + (size_t)2 * kE, dsc(5),
                 zD + 64, rp_all + rpo.v[4], csr + (size_t)4 * kE, dsc(9),
                 bl + 2 * kHID, bl + 4 * kHID, aMb, kNM};
      gather_batched_kernel<<<dim3(kNL / 4, 1, 3), 256, 0, stream>>>(gd);
    } else {
      // layer-3 consumes only aDb/aMb -> skip dead aLb gather (70% of work)
      GDescs gd;
      gd.d[0] = {zL, rp_all + rpo.v[0], csr + (size_t)0 * kE, dsc(1),
                 zM + 64, rp_all + rpo.v[5], csr + (size_t)5 * kE, dsc(11),
                 bl + 0 * kHID, bl + 5 * kHID, aDb, kND};
      gd.d[1] = {zL + 64, rp_all + rpo.v[2], csr + (size_t)2 * kE, dsc(5),
                 zD + 64, rp_all + rpo.v[4], csr + (size_t)4 * kE, dsc(9),
                 bl + 2 * kHID, bl + 4 * kHID, aMb, kNM};
      gd.d[2] = gd.d[1];
      gather_batched_kernel<<<dim3(kND / 4, 1, 2), 256, 0, stream>>>(gd);
    }
    curb[0] = aLb; curb[1] = aDb; curb[2] = aMb;
  }

  // ---- 4) layer 3 (types 1: D->L, 3: M->L; rows < 2048) + L1 norm ----
  float* emb  = (float*)d_out;
  float* outx = (float*)d_out + (size_t)kSIZE * kOUTF;
  {
    ZDescs zd;
    zd.d[0] = {curb[1], W3t1, zD3, dsc(2), dsc(2), kND, kHID};
    zd.d[1] = {curb[2], W3t3, zM3, dsc(6), dsc(6), kNM, kHID};
    zd.d[2] = zd.d[1];
    zgemm_batched_kernel<<<dim3(1, kND / 128, 2), 256, 0, stream>>>(zd);
    gather128_l1_kernel<<<kSIZE / 4, 256, 0, stream>>>(
        zD3, rp_all + rpo.v[1], csr + (size_t)1 * kE, dsc(3),
        zM3, rp_all + rpo.v[3], csr + (size_t)3 * kE, dsc(7),
        Bb[2] + 1 * kOUTF, Bb[2] + 3 * kOUTF, emb, xin + kITEMS, kXIN);
  }

  // ---- 5) MLP ----
  if (S1 > 1) {
    gemm_bf16_kernel<<<dim3(2, 16, S1), 256, 0, stream>>>(
        xin, f1t, nullptr, nullptr, 0, kSIZE, 256, kXIN, kXIN,
        nullptr, 0, kXIN / S1, partK);
    int n4 = kSIZE * 256 / 4;
    reducek_kernel<<<(n4 + 255) / 256, 256, 0, stream>>>(
        partK, x1b, 1, n4, S1, 256, f1_b, 1);
  } else {
    gemm_bf16_kernel<<<dim3(2, 16, 1), 256, 0, stream>>>(
        xin, f1t, nullptr, x1b, 1, kSIZE, 256, kXIN, kXIN, f1_b, 1, 0, nullptr);
  }
  if (S2 > 1) {
    gemm_bf16_kernel<<<dim3(4, 16, S2), 256, 0, stream>>>(
        x1b, f2t, nullptr, nullptr, 0, kSIZE, 512, 256, 256,
        nullptr, 0, 256 / S2, partK);
    int n4 = kSIZE * 512 / 4;
    reducek_kernel<<<(n4 + 255) / 256, 256, 0, stream>>>(
        partK, x2b, 1, n4, S2, 512, f2_b, 1);
  } else {
    gemm_bf16_kernel<<<dim3(4, 16, 1), 256, 0, stream>>>(
        x1b, f2t, nullptr, x2b, 1, kSIZE, 512, 256, 256, f2_b, 1, 0, nullptr);
  }
  if (S3 > 1) {
    gemm_bf16_kernel<<<dim3(8, 16, S3), 256, 0, stream>>>(
        x2b, f3t, nullptr, nullptr, 0, kSIZE, 1024, 512, 512,
        nullptr, 0, 512 / S3, partK);
    int n4 = kSIZE * 1024 / 4;
    reducek_kernel<<<(n4 + 255) / 256, 256, 0, stream>>>(
        partK, x3b, 1, n4, S3, 1024, f3_b, 1);
  } else {
    gemm_bf16_kernel<<<dim3(8, 16, 1), 256, 0, stream>>>(
        x2b, f3t, nullptr, x3b, 1, kSIZE, 1024, 512, 512, f3_b, 1, 0, nullptr);
  }
  // f4: m201-schedule 256x128 kernel, fused bias+sigmoid, fp32 out
  gemm256_kernel<<<dim3(kITEMS / 128, kSIZE / 256), 512, 0, stream>>>(
      x3b, f4t, outx, kSIZE, kITEMS, 1024, f4_b);
}

// Round 22
// 256.605 us; speedup vs baseline: 1.2573x; 1.0012x over previous
//
#include <hip/hip_runtime.h>

constexpr int kNL = 16384, kND = 4096, kNM = 2048;
constexpr int kE = 262144;              // 2^18
constexpr int kFEAT = 256, kHID = 64, kOUTF = 128;
constexpr int kITEMS = 4096, kSIZE = 2048;
constexpr int kHB = 16;                 // histogram chunks per index array
constexpr int kZS = 128;                // z row stride (merged 2-type layout)
constexpr int kXIN = kITEMS + kOUTF;    // 4224

typedef unsigned short ushort_t;
typedef unsigned int uint_t;
typedef __attribute__((ext_vector_type(8))) short short8v;
typedef __attribute__((ext_vector_type(4))) float f32x4;
typedef __attribute__((ext_vector_type(4))) uint_t uint4v;
typedef __attribute__((ext_vector_type(4))) int int4v;

struct EdgePtrs { const int* p[12]; };
struct I6 { int v[6]; };

__device__ inline ushort_t f2bf(float f) {
  unsigned u = __builtin_bit_cast(unsigned, f);
  unsigned r = u + 0x7fffu + ((u >> 16) & 1u);
  return (ushort_t)(r >> 16);
}
__device__ inline float bf2f(ushort_t b) {
  unsigned u = ((unsigned)b) << 16;
  return __builtin_bit_cast(float, u);
}
__device__ inline float bf2f_lo(uint_t v) { return __builtin_bit_cast(float, v << 16); }
__device__ inline float bf2f_hi(uint_t v) { return __builtin_bit_cast(float, v & 0xffff0000u); }

// async global->LDS, 16 B per lane (global_load_lds_dwordx4)
__device__ __forceinline__ void gload16(const ushort_t* g, ushort_t* l) {
  __builtin_amdgcn_global_load_lds(
      (const __attribute__((address_space(1))) void*)g,
      (__attribute__((address_space(3))) void*)l, 16, 0, 0);
}

// bijective XCD swizzle (m204)
__device__ __forceinline__ void xcd_swizzle(int& bx, int& by) {
  int gx = gridDim.x, gy = gridDim.y;
  int nwg = gx * gy;
  int orig = by * gx + bx;
  int q = nwg >> 3, r = nwg & 7;
  int xcd = orig & 7, loc = orig >> 3;
  int s = ((xcd < r) ? xcd * (q + 1) : r * (q + 1) + (xcd - r) * q) + loc;
  by = s % gy;
  bx = s / gy;
}

// ===== hist: standalone (64 KB LDS only here), int4 edge loads =============
__global__ __launch_bounds__(256) void hist_kernel(EdgePtrs ep, uint_t* __restrict__ part) {
  __shared__ uint_t bins[16384];
  int k = blockIdx.x >> 4, chunk = blockIdx.x & (kHB - 1);
  uint4v zero = {0, 0, 0, 0};
  for (int i = threadIdx.x; i < 4096; i += 256) ((uint4v*)bins)[i] = zero;
  __syncthreads();
  const int4v* arr = (const int4v*)(ep.p[k] + chunk * (kE / kHB));
  for (int i = threadIdx.x; i < kE / kHB / 4; i += 256) {
    int4v e4 = arr[i];
    atomicAdd(&bins[e4[0]], 1u);
    atomicAdd(&bins[e4[1]], 1u);
    atomicAdd(&bins[e4[2]], 1u);
    atomicAdd(&bins[e4[3]], 1u);
  }
  __syncthreads();
  uint4v* o = (uint4v*)(part + ((size_t)blockIdx.x << 14));
  for (int i = threadIdx.x; i < 4096; i += 256) o[i] = ((uint4v*)bins)[i];
}

// ===== prep: converts/transposes ONLY (4.2 KB LDS -> high occupancy) =======
// kind 2: strided convert with POWER-OF-2 row length; B = log2(rowLen4)
struct PJob { const float* in; ushort_t* out; int A; int B; int C; int kind; int nblk; };
struct PJobs { PJob j[24]; int n; };

__global__ __launch_bounds__(256) void prep_kernel(PJobs jobs) {
  __shared__ float t[32][33];
  int b = blockIdx.x;
  int ji = 0;
  while (ji < jobs.n && b >= jobs.j[ji].nblk) { b -= jobs.j[ji].nblk; ++ji; }
  if (ji >= jobs.n) return;
  PJob jb = jobs.j[ji];
  if (jb.kind == 0) {                       // flat convert, A = n4
    int idx = b * 256 + threadIdx.x;
    if (idx >= jb.A) return;
    float4 v = ((const float4*)jb.in)[idx];
    ushort_t* o = jb.out + (size_t)idx * 4;
    o[0] = f2bf(v.x); o[1] = f2bf(v.y); o[2] = f2bf(v.z); o[3] = f2bf(v.w);
  } else if (jb.kind == 2) {                // strided convert: A=n4, B=log2(rowLen4), C=outStride
    int idx = b * 256 + threadIdx.x;
    if (idx >= jb.A) return;
    float4 v = ((const float4*)jb.in)[idx];
    int row = idx >> jb.B, col4 = idx & ((1 << jb.B) - 1);
    ushort_t* o = jb.out + (size_t)row * jb.C + (size_t)col4 * 4;
    o[0] = f2bf(v.x); o[1] = f2bf(v.y); o[2] = f2bf(v.z); o[3] = f2bf(v.w);
  } else {                                  // transpose: in [K][N] -> out [N][K]; A=K, B=N
    int K = jb.A, N = jb.B;
    int tpr = N >> 5;
    int n0 = (b % tpr) * 32, k0 = (b / tpr) * 32;
    int tx = threadIdx.x & 31, ty = threadIdx.x >> 5;
#pragma unroll
    for (int i = 0; i < 32; i += 8)
      t[ty + i][tx] = jb.in[(size_t)(k0 + ty + i) * N + n0 + tx];
    __syncthreads();
#pragma unroll
    for (int i = 0; i < 32; i += 8)
      jb.out[(size_t)(n0 + ty + i) * K + k0 + tx] = f2bf(t[tx][ty + i]);
  }
}

// ===== CSR metadata chain (R12-proven: wide grids) =========================
__global__ void reduce_finalize_kernel(const uint_t* __restrict__ part,
                                       uint_t* __restrict__ cnts,
                                       float* __restrict__ degscale) {
  int idx = blockIdx.x * 256 + threadIdx.x;   // grid = 12*16384/256
  int k = idx >> 14, bin = idx & 16383;
  uint_t s = 0;
  for (int c = 0; c < kHB; ++c) s += part[((size_t)(k * kHB + c) << 14) + bin];
  cnts[idx] = s;
  degscale[idx] = rsqrtf((float)max(s, 1u));
}

__global__ __launch_bounds__(1024) void scan_kernel(const uint_t* __restrict__ cnts,
                                                    uint_t* __restrict__ rp_all,
                                                    I6 rpoff, I6 nd) {
  __shared__ uint_t sums[1024];
  int t = blockIdx.x;
  int n = nd.v[t];
  const uint_t* c = cnts + ((size_t)(2 * t + 1) << 14);
  uint_t* rp = rp_all + rpoff.v[t];
  int tid = threadIdx.x;
  int seg = n >> 10;
  uint_t s = 0;
  for (int j = 0; j < seg; ++j) s += c[tid * seg + j];
  sums[tid] = s;
  __syncthreads();
  for (int o = 1; o < 1024; o <<= 1) {
    uint_t v = (tid >= o) ? sums[tid - o] : 0u;
    __syncthreads();
    sums[tid] += v;
    __syncthreads();
  }
  uint_t run = sums[tid] - s;   // exclusive
  for (int j = 0; j < seg; ++j) { rp[tid * seg + j] = run; run += c[tid * seg + j]; }
  if (tid == 1023) rp[n] = run;
}

__global__ void chunkofs_kernel(const uint_t* __restrict__ part,
                                const uint_t* __restrict__ rp_all,
                                I6 rpoff, I6 nd, uint_t* __restrict__ ofs) {
  int idx = blockIdx.x * 256 + threadIdx.x;   // grid = 6*16384/256
  int t = idx >> 14, bin = idx & 16383;
  if (bin >= nd.v[t]) return;
  uint_t run = (rp_all + rpoff.v[t])[bin];
  for (int c = 0; c < kHB; ++c) {
    ofs[((size_t)(t * kHB + c) << 14) + bin] = run;
    run += part[((size_t)((2 * t + 1) * kHB + c) << 14) + bin];
  }
}

__global__ __launch_bounds__(256) void fill_kernel(EdgePtrs ep,
                                                   const uint_t* __restrict__ ofs,
                                                   ushort_t* __restrict__ csr_all) {
  __shared__ uint_t cursor[16384];
  int t = blockIdx.x >> 4, chunk = blockIdx.x & (kHB - 1);
  const uint_t* o = ofs + ((size_t)(t * kHB + chunk) << 14);
  for (int i = threadIdx.x; i < 16384; i += 256) cursor[i] = o[i];
  __syncthreads();
  int base = chunk * (kE / kHB);
  const int4v* srcp = (const int4v*)(ep.p[2 * t] + base);
  const int4v* dstp = (const int4v*)(ep.p[2 * t + 1] + base);
  ushort_t* csr = csr_all + (size_t)t * kE;
  for (int i = threadIdx.x; i < kE / kHB / 4; i += 256) {
    int4v d4 = dstp[i];
    int4v s4 = srcp[i];
#pragma unroll
    for (int j = 0; j < 4; ++j) {
      uint_t pos = atomicAdd(&cursor[d4[j]], 1u);
      csr[pos] = (ushort_t)s4[j];
    }
  }
}

// ===== generic bf16 MFMA GEMM, 128x128 tile, BK=64, 2-buffer (R8) ==========
__global__ __launch_bounds__(256) void gemm_bf16_kernel(
    const ushort_t* __restrict__ A, const ushort_t* __restrict__ Bt,
    const float* __restrict__ Cin, void* __restrict__ out, int outBf16,
    int M, int N, int K, int ldb,
    const float* __restrict__ bias, int act,
    int kChunk, float* __restrict__ partOut) {
  __shared__ ushort_t As[2][8192];   // 2 x 16 KB
  __shared__ ushort_t Bs[2][8192];
  int tid = threadIdx.x;
  int wave = tid >> 6, lane = tid & 63;
  int bx = blockIdx.x, by = blockIdx.y;
  xcd_swizzle(bx, by);
  int brow = by * 128, bcol = bx * 128;
  int kStart = partOut ? blockIdx.z * kChunk : 0;
  int kLen = partOut ? kChunk : K;
  int nsteps = kLen >> 6;              // BK = 64

  int rowBase = tid >> 3;              // 0..31
  int u = (tid & 7) ^ (rowBase & 7);
  const ushort_t* gA = A + (size_t)(brow + rowBase) * K + kStart + u * 8;
  const ushort_t* gB = Bt + (size_t)(bcol + rowBase) * ldb + kStart + u * 8;

  int fr = lane & 15, fq = lane >> 4;
  f32x4 acc[2][8] = {};

#define STAGE_G(buf, koff)                                              \
  do {                                                                  \
    _Pragma("unroll")                                                   \
    for (int j = 0; j < 4; ++j) {                                       \
      gload16(gA + (size_t)j * 32 * K + (koff), &As[buf][j * 2048 + tid * 8]);   \
      gload16(gB + (size_t)j * 32 * ldb + (koff), &Bs[buf][j * 2048 + tid * 8]); \
    }                                                                   \
  } while (0)

  STAGE_G(0, 0);
  int cur = 0;
  for (int i = 0; i < nsteps; ++i) {
    __syncthreads();
    if (i + 1 < nsteps) STAGE_G(cur ^ 1, (i + 1) * 64);
#pragma unroll
    for (int kk = 0; kk < 2; ++kk) {
      short8v af[2], bfr[8];
#pragma unroll
      for (int mi = 0; mi < 2; ++mi) {
        int row = wave * 32 + mi * 16 + fr;
        af[mi] = *(const short8v*)(&As[cur][row * 64 + (((kk * 4 + fq) ^ (row & 7)) * 8)]);
      }
#pragma unroll
      for (int ni = 0; ni < 8; ++ni) {
        int row = ni * 16 + fr;
        bfr[ni] = *(const short8v*)(&Bs[cur][row * 64 + (((kk * 4 + fq) ^ (row & 7)) * 8)]);
      }
#pragma unroll
      for (int mi = 0; mi < 2; ++mi)
#pragma unroll
        for (int ni = 0; ni < 8; ++ni)
          acc[mi][ni] = __builtin_amdgcn_mfma_f32_16x16x32_bf16(af[mi], bfr[ni], acc[mi][ni], 0, 0, 0);
    }
    cur ^= 1;
  }
#undef STAGE_G

  if (partOut) {
    float* o = partOut + (size_t)blockIdx.z * M * N;
#pragma unroll
    for (int mi = 0; mi < 2; ++mi)
#pragma unroll
      for (int ni = 0; ni < 8; ++ni)
#pragma unroll
        for (int r = 0; r < 4; ++r) {
          int row = brow + wave * 32 + mi * 16 + fq * 4 + r;
          int col = bcol + ni * 16 + fr;
          o[(size_t)row * N + col] = acc[mi][ni][r];
        }
    return;
  }
#pragma unroll
  for (int mi = 0; mi < 2; ++mi)
#pragma unroll
    for (int ni = 0; ni < 8; ++ni)
#pragma unroll
      for (int r = 0; r < 4; ++r) {
        int row = brow + wave * 32 + mi * 16 + fq * 4 + r;
        int col = bcol + ni * 16 + fr;
        float v = acc[mi][ni][r];
        if (Cin) v += Cin[(size_t)row * N + col];
        if (bias) v += bias[col];
        if (act == 1) v = fmaxf(v, 0.0f);
        else if (act == 2) v = 1.0f / (1.0f + expf(-v));
        if (outBf16) ((ushort_t*)out)[(size_t)row * N + col] = f2bf(v);
        else ((float*)out)[(size_t)row * N + col] = v;
      }
}

// ===== m201-schedule GEMM for f4: BM=256 BN=128 BK=64, 512 thr, 3-buf ======
__global__ __launch_bounds__(512) void gemm256_kernel(
    const ushort_t* __restrict__ A, const ushort_t* __restrict__ Bt,
    float* __restrict__ out, int M, int N, int K,
    const float* __restrict__ bias) {
  __shared__ ushort_t As[3][16384];   // 3 x 32 KB
  __shared__ ushort_t Bs[3][8192];    // 3 x 16 KB
  int tid = threadIdx.x;
  int wave = tid >> 6, lane = tid & 63;
  int bx = blockIdx.x, by = blockIdx.y;
  xcd_swizzle(bx, by);
  int fr = lane & 15, fq = lane >> 4;
  int wm = wave >> 2, wn = wave & 3;

  int rquot = tid >> 3;                // 0..63
  int uslot = (tid & 7) ^ (rquot & 7); // pre-swizzled global slot
  const ushort_t* gA = A + (size_t)(by * 256 + rquot) * K + uslot * 8;
  const ushort_t* gB = Bt + (size_t)(bx * 128 + rquot) * K + uslot * 8;

  f32x4 acc[8][2] = {};
  int nsteps = K >> 6;

#define SG_A(b_, t_, j_) gload16(gA + (size_t)(j_) * 64 * K + (size_t)(t_) * 64, &As[b_][(j_) * 4096 + tid * 8])
#define SG_B(b_, t_, j_) gload16(gB + (size_t)(j_) * 64 * K + (size_t)(t_) * 64, &Bs[b_][(j_) * 4096 + tid * 8])

  SG_A(0, 0, 0); SG_A(0, 0, 1); SG_A(0, 0, 2); SG_A(0, 0, 3); SG_B(0, 0, 0); SG_B(0, 0, 1);
  SG_A(1, 1, 0); SG_A(1, 1, 1); SG_A(1, 1, 2); SG_A(1, 1, 3); SG_B(1, 1, 0); SG_B(1, 1, 1);
  asm volatile("s_waitcnt vmcnt(6)" ::: "memory");
  __builtin_amdgcn_s_barrier();

  short8v bf[2][2];

#define PHASE(p_)                                                            \
  {                                                                          \
    short8v af[4][2];                                                        \
    _Pragma("unroll")                                                        \
    for (int q = 0; q < 4; ++q) {                                            \
      int row = wm * 128 + (4 * (p_) + q) * 16 + fr;                         \
      int base = row * 64;                                                   \
      af[q][0] = *(const short8v*)(&As[b][base + ((fq ^ (row & 7)) * 8)]);   \
      af[q][1] = *(const short8v*)(&As[b][base + (((4 + fq) ^ (row & 7)) * 8)]); \
    }                                                                        \
    if ((p_) == 0) {                                                         \
      _Pragma("unroll")                                                      \
      for (int q = 0; q < 2; ++q) {                                          \
        int row = wn * 32 + q * 16 + fr;                                     \
        int base = row * 64;                                                 \
        bf[q][0] = *(const short8v*)(&Bs[b][base + ((fq ^ (row & 7)) * 8)]); \
        bf[q][1] = *(const short8v*)(&Bs[b][base + (((4 + fq) ^ (row & 7)) * 8)]); \
      }                                                                      \
      if (doStage) { SG_A(sb, t + 2, 0); SG_A(sb, t + 2, 1); SG_A(sb, t + 2, 2); SG_A(sb, t + 2, 3); } \
    } else {                                                                 \
      if (doStage) { SG_B(sb, t + 2, 0); SG_B(sb, t + 2, 1); }               \
      if (t + 2 < nsteps)      asm volatile("s_waitcnt vmcnt(6)" ::: "memory"); \
      else if (t + 1 < nsteps) asm volatile("s_waitcnt vmcnt(0)" ::: "memory"); \
    }                                                                        \
    __builtin_amdgcn_s_barrier();                                            \
    asm volatile("s_waitcnt lgkmcnt(0)" ::: "memory");                       \
    __builtin_amdgcn_s_setprio(1);                                           \
    _Pragma("unroll")                                                        \
    for (int kk = 0; kk < 2; ++kk)                                           \
      _Pragma("unroll")                                                      \
      for (int q = 0; q < 4; ++q)                                            \
        _Pragma("unroll")                                                    \
        for (int ni = 0; ni < 2; ++ni)                                       \
          acc[4 * (p_) + q][ni] = __builtin_amdgcn_mfma_f32_16x16x32_bf16(af[q][kk], bf[ni][kk], acc[4 * (p_) + q][ni], 0, 0, 0); \
    __builtin_amdgcn_s_setprio(0);                                           \
    __builtin_amdgcn_s_barrier();                                            \
  }

  for (int t = 0; t < nsteps; ++t) {
    int b = t % 3, sb = (t + 2) % 3;
    bool doStage = (t + 2 < nsteps);
    PHASE(0);
    PHASE(1);
  }
#undef PHASE
#undef SG_A
#undef SG_B

#pragma unroll
  for (int mi = 0; mi < 8; ++mi)
#pragma unroll
    for (int ni = 0; ni < 2; ++ni)
#pragma unroll
      for (int r = 0; r < 4; ++r) {
        int row = by * 256 + wm * 128 + mi * 16 + fq * 4 + r;
        int col = bx * 128 + wn * 32 + ni * 16 + fr;
        float v = acc[mi][ni][r] + bias[col];
        out[(size_t)row * N + col] = 1.0f / (1.0f + expf(-v));
      }
}

// ===== batched z GEMM (R16-proven): N=128, BK=64, 2-buffer LDS =============
struct ZDesc { const ushort_t* A; const ushort_t* Bt; ushort_t* out;
               const float* rs0; const float* rs1; int M; int K; };
struct ZDescs { ZDesc d[3]; };

__global__ __launch_bounds__(256) void zgemm_batched_kernel(ZDescs ds) {
  __shared__ ushort_t As[2][8192];
  __shared__ ushort_t Bs[2][8192];
  ZDesc de = ds.d[blockIdx.z];
  int gy = gridDim.y;
  int yq = gy >> 3;
  int ys = (blockIdx.y & 7) * yq + (blockIdx.y >> 3);
  int brow = ys * 128;
  if (brow >= de.M) return;
  int K = de.K;
  int nsteps = K >> 6;
  if (nsteps == 0) nsteps = 1;
  int kkMax = (K >= 64) ? 2 : 1;
  int tid = threadIdx.x;
  int wave = tid >> 6, lane = tid & 63;

  int rowBase = tid >> 3;
  int u = (tid & 7) ^ (rowBase & 7);
  const ushort_t* gA = de.A + (size_t)(brow + rowBase) * K + u * 8;
  const ushort_t* gB = de.Bt + (size_t)rowBase * K + u * 8;

  int fr = lane & 15, fq = lane >> 4;
  f32x4 acc[2][8] = {};

#define STAGE_Z(buf, koff)                                              \
  do {                                                                  \
    _Pragma("unroll")                                                   \
    for (int j = 0; j < 4; ++j) {                                       \
      gload16(gA + (size_t)j * 32 * K + (koff), &As[buf][j * 2048 + tid * 8]); \
      gload16(gB + (size_t)j * 32 * K + (koff), &Bs[buf][j * 2048 + tid * 8]); \
    }                                                                   \
  } while (0)

  STAGE_Z(0, 0);
  int cur = 0;
  for (int i = 0; i < nsteps; ++i) {
    __syncthreads();
    if (i + 1 < nsteps) STAGE_Z(cur ^ 1, (i + 1) * 64);
#pragma unroll
    for (int kk = 0; kk < 2; ++kk) {
      if (kk >= kkMax) break;
      short8v af[2], bfr[8];
#pragma unroll
      for (int mi = 0; mi < 2; ++mi) {
        int row = wave * 32 + mi * 16 + fr;
        af[mi] = *(const short8v*)(&As[cur][row * 64 + (((kk * 4 + fq) ^ (row & 7)) * 8)]);
      }
#pragma unroll
      for (int ni = 0; ni < 8; ++ni) {
        int row = ni * 16 + fr;
        bfr[ni] = *(const short8v*)(&Bs[cur][row * 64 + (((kk * 4 + fq) ^ (row & 7)) * 8)]);
      }
#pragma unroll
      for (int mi = 0; mi < 2; ++mi)
#pragma unroll
        for (int ni = 0; ni < 8; ++ni)
          acc[mi][ni] = __builtin_amdgcn_mfma_f32_16x16x32_bf16(af[mi], bfr[ni], acc[mi][ni], 0, 0, 0);
    }
    cur ^= 1;
  }
#undef STAGE_Z

#pragma unroll
  for (int mi = 0; mi < 2; ++mi)
#pragma unroll
    for (int ni = 0; ni < 8; ++ni) {
      const float* rs = (ni < 4) ? de.rs0 : de.rs1;
#pragma unroll
      for (int r = 0; r < 4; ++r) {
        int row = brow + wave * 32 + mi * 16 + fq * 4 + r;
        int col = ni * 16 + fr;
        de.out[(size_t)row * 128 + col] = f2bf(acc[mi][ni][r] * rs[row]);
      }
    }
}

// ===== batched CSR gather: dwordx4 per edge-slot (u16 indices) =============
struct GDesc { const ushort_t* z0; const uint_t* rp0; const ushort_t* cs0; const float* s0;
               const ushort_t* z1; const uint_t* rp1; const ushort_t* cs1; const float* s1;
               const float* b0; const float* b1; ushort_t* out; int nd; };
struct GDescs { GDesc d[3]; };

__device__ __forceinline__ void acc8(float* __restrict__ a, uint4v v) {
  a[0] += bf2f_lo(v[0]); a[1] += bf2f_hi(v[0]);
  a[2] += bf2f_lo(v[1]); a[3] += bf2f_hi(v[1]);
  a[4] += bf2f_lo(v[2]); a[5] += bf2f_hi(v[2]);
  a[6] += bf2f_lo(v[3]); a[7] += bf2f_hi(v[3]);
}

// width-64 z (stride kZS): 8 edge slots (h=lane>>3), col group c=lane&7
__device__ __forceinline__ void gsum64(const ushort_t* __restrict__ z,
                                       const ushort_t* __restrict__ cs,
                                       uint_t e, uint_t ee, int h, int off,
                                       float* __restrict__ a) {
  for (; e + 16 <= ee; e += 16) {
    uint_t sA = cs[e + h], sB = cs[e + 8 + h];
    uint4v vA = *(const uint4v*)(z + (size_t)sA * kZS + off);
    uint4v vB = *(const uint4v*)(z + (size_t)sB * kZS + off);
    acc8(a, vA); acc8(a, vB);
  }
  for (; e + 8 <= ee; e += 8) {
    uint4v v = *(const uint4v*)(z + (size_t)cs[e + h] * kZS + off);
    acc8(a, v);
  }
  if ((uint_t)h < ee - e) {
    uint4v v = *(const uint4v*)(z + (size_t)cs[e + h] * kZS + off);
    acc8(a, v);
  }
}

__global__ __launch_bounds__(256) void gather_batched_kernel(GDescs ds) {
  GDesc de = ds.d[blockIdx.z];
  int d = blockIdx.x * 4 + (threadIdx.x >> 6);
  if (d >= de.nd) return;
  int lane = threadIdx.x & 63;
  int h = lane >> 3, c = lane & 7;
  int off = 8 * c;
  float a0[8] = {}, a1[8] = {};
  gsum64(de.z0, de.cs0, de.rp0[d], de.rp0[d + 1], h, off, a0);
  gsum64(de.z1, de.cs1, de.rp1[d], de.rp1[d + 1], h, off, a1);
  float s0 = de.s0[d], s1 = de.s1[d];
  float v[8];
#pragma unroll
  for (int j = 0; j < 8; ++j) {
    v[j] = a0[j] * s0 + a1[j] * s1;
    v[j] += __shfl_xor(v[j], 8);
    v[j] += __shfl_xor(v[j], 16);
    v[j] += __shfl_xor(v[j], 32);
  }
  if (h == 0) {
    int c0 = off;
    uint4v pack;
#pragma unroll
    for (int j = 0; j < 4; ++j) {
      float x = v[2 * j] + de.b0[c0 + 2 * j] + de.b1[c0 + 2 * j];
      float y = v[2 * j + 1] + de.b0[c0 + 2 * j + 1] + de.b1[c0 + 2 * j + 1];
      pack[j] = (uint_t)f2bf(x) | ((uint_t)f2bf(y) << 16);
    }
    *(uint4v*)(de.out + (size_t)d * 64 + c0) = pack;
  }
}

// width-128 z (stride 128): 4 edge slots (h=lane>>4), col group c=lane&15
__device__ __forceinline__ void gsum128(const ushort_t* __restrict__ z,
                                        const ushort_t* __restrict__ cs,
                                        uint_t e, uint_t ee, int h, int off,
                                        float* __restrict__ a) {
  for (; e + 8 <= ee; e += 8) {
    uint_t sA = cs[e + h], sB = cs[e + 4 + h];
    uint4v vA = *(const uint4v*)(z + (size_t)sA * 128 + off);
    uint4v vB = *(const uint4v*)(z + (size_t)sB * 128 + off);
    acc8(a, vA); acc8(a, vB);
  }
  for (; e + 4 <= ee; e += 4) {
    uint4v v = *(const uint4v*)(z + (size_t)cs[e + h] * 128 + off);
    acc8(a, v);
  }
  if ((uint_t)h < ee - e) {
    uint4v v = *(const uint4v*)(z + (size_t)cs[e + h] * 128 + off);
    acc8(a, v);
  }
}

__global__ __launch_bounds__(256) void gather128_l1_kernel(
    const ushort_t* __restrict__ zD, const uint_t* __restrict__ rpD, const ushort_t* __restrict__ csD,
    const float* __restrict__ sInD,
    const ushort_t* __restrict__ zM, const uint_t* __restrict__ rpM, const ushort_t* __restrict__ csM,
    const float* __restrict__ sInM,
    const float* __restrict__ bD, const float* __restrict__ bM,
    float* __restrict__ emb, ushort_t* __restrict__ embb, int embStride) {
  int d = blockIdx.x * 4 + (threadIdx.x >> 6);
  int lane = threadIdx.x & 63;
  int h = lane >> 4, c = lane & 15;
  int off = 8 * c;                   // cols [8c, 8c+8)
  float aD[8] = {}, aM[8] = {};
  gsum128(zD, csD, rpD[d], rpD[d + 1], h, off, aD);
  gsum128(zM, csM, rpM[d], rpM[d + 1], h, off, aM);
  float sD = sInD[d], sM = sInM[d];
  float v[8];
#pragma unroll
  for (int j = 0; j < 8; ++j) {
    v[j] = aD[j] * sD + aM[j] * sM + bD[off + j] + bM[off + j];
    v[j] += __shfl_xor(v[j], 16);
    v[j] += __shfl_xor(v[j], 32);
  }
  float a = 0;
#pragma unroll
  for (int j = 0; j < 8; ++j) a += fabsf(v[j]);
#pragma unroll
  for (int o = 8; o > 0; o >>= 1) a += __shfl_xor(a, o);
  float l1 = fmaxf(a, 1e-12f);
  if (h == 0) {
    float e0[8];
#pragma unroll
    for (int j = 0; j < 8; ++j) e0[j] = v[j] / l1;
    float* ep_ = emb + (size_t)d * kOUTF + off;
    *(f32x4*)ep_ = {e0[0], e0[1], e0[2], e0[3]};
    *(f32x4*)(ep_ + 4) = {e0[4], e0[5], e0[6], e0[7]};
    uint4v pack;
#pragma unroll
    for (int j = 0; j < 4; ++j)
      pack[j] = (uint_t)f2bf(e0[2 * j]) | ((uint_t)f2bf(e0[2 * j + 1]) << 16);
    *(uint4v*)(embb + (size_t)d * embStride + off) = pack;
  }
}

// ===== split-K reduce with fused bias/act/bf16-out =========================
__global__ void reducek_kernel(const float* __restrict__ P, void* __restrict__ out,
                               int outBf16, int n4, int S, int N,
                               const float* __restrict__ bias, int act) {
  int idx = blockIdx.x * 256 + threadIdx.x;
  if (idx >= n4) return;
  float4 a = ((const float4*)P)[idx];
  for (int s = 1; s < S; ++s) {
    float4 b = ((const float4*)P)[(size_t)s * n4 + idx];
    a.x += b.x; a.y += b.y; a.z += b.z; a.w += b.w;
  }
  float v[4] = {a.x, a.y, a.z, a.w};
  int c0 = (idx * 4) % N;
#pragma unroll
  for (int j = 0; j < 4; ++j) {
    if (bias) v[j] += bias[c0 + j];
    if (act == 1) v[j] = fmaxf(v[j], 0.0f);
    else if (act == 2) v[j] = 1.0f / (1.0f + expf(-v[j]));
  }
  if (outBf16) {
    ushort_t* o = (ushort_t*)out + (size_t)idx * 4;
    o[0] = f2bf(v[0]); o[1] = f2bf(v[1]); o[2] = f2bf(v[2]); o[3] = f2bf(v[3]);
  } else {
    float4 r = {v[0], v[1], v[2], v[3]};
    ((float4*)out)[idx] = r;
  }
}

extern "C" void kernel_launch(void* const* d_in, const int* in_sizes, int n_in,
                              void* d_out, int out_size, void* d_ws, size_t ws_size,
                              hipStream_t stream) {
  const float* h_L = (const float*)d_in[0];
  const float* h_D = (const float*)d_in[1];
  const float* h_M = (const float*)d_in[2];
  const float* Adj = (const float*)d_in[3];
  EdgePtrs ep;
  for (int i = 0; i < 12; ++i) ep.p[i] = (const int*)d_in[4 + i];
  const float* W[3]  = {(const float*)d_in[16], (const float*)d_in[18], (const float*)d_in[20]};
  const float* Bb[3] = {(const float*)d_in[17], (const float*)d_in[19], (const float*)d_in[21]};
  const float* f1_w = (const float*)d_in[22];
  const float* f1_b = (const float*)d_in[23];
  const float* f2_w = (const float*)d_in[24];
  const float* f2_b = (const float*)d_in[25];
  const float* f3_w = (const float*)d_in[26];
  const float* f3_b = (const float*)d_in[27];
  const float* f4_w = (const float*)d_in[28];
  const float* f4_b = (const float*)d_in[29];

  // ---- workspace layout ----
  float* ws = (float*)d_ws;
  size_t off = 0;
  auto allocF = [&](size_t n) { float* p = ws + off; off += (n + 3) & ~(size_t)3; return p; };
  auto allocU = [&](size_t n) { return (uint_t*)allocF(n); };
  auto allocB = [&](size_t n) { return (ushort_t*)allocF((n + 1) / 2); };

  uint_t* part   = allocU((size_t)12 * kHB * 16384);   // 12.6 MB, reused as z bufs
  uint_t* cnts   = allocU((size_t)12 * 16384);
  float*  degscale = allocF((size_t)12 * 16384);
  uint_t* rp_all = allocU(45062 + 2);
  uint_t* ofs    = allocU((size_t)6 * kHB * 16384);
  ushort_t* csr  = allocB((size_t)6 * kE);            // u16 CSR (src ids < 16384)
  ushort_t* hLb  = allocB((size_t)kNL * kFEAT);
  ushort_t* hDb  = allocB((size_t)kND * kFEAT);
  ushort_t* hMb  = allocB((size_t)kNM * kFEAT);
  ushort_t* xin  = allocB((size_t)kSIZE * kXIN);   // [Adj | emb] bf16, stride 4224
  ushort_t* aLb  = allocB((size_t)kNL * kHID);
  ushort_t* aDb  = allocB((size_t)kND * kHID);
  ushort_t* aMb  = allocB((size_t)kNM * kHID);
  ushort_t* WLt  = allocB((size_t)128 * kFEAT);
  ushort_t* WDt  = allocB((size_t)128 * kFEAT);
  ushort_t* WMt  = allocB((size_t)128 * kFEAT);
  ushort_t* WL2t = allocB((size_t)128 * kHID);
  ushort_t* WD2t = allocB((size_t)128 * kHID);
  ushort_t* WM2t = allocB((size_t)128 * kHID);
  ushort_t* W3t1 = allocB((size_t)kOUTF * kHID);
  ushort_t* W3t3 = allocB((size_t)kOUTF * kHID);
  ushort_t* f1t  = allocB((size_t)256 * kXIN);
  ushort_t* f2t  = allocB((size_t)512 * 256);
  ushort_t* f3t  = allocB((size_t)1024 * 512);
  ushort_t* f4t  = allocB((size_t)kITEMS * 1024);
  ushort_t* x1b  = allocB((size_t)kSIZE * 256);
  ushort_t* x2b  = allocB((size_t)kSIZE * 512);
  ushort_t* x3b  = allocB((size_t)kSIZE * 1024);

  // shared split-K partials: f1 S=11 (5.77M), f2 S=4 (4.19M), f3 S=2 (4.19M)
  int S1 = 1, S2 = 1, S3 = 1;
  float* partK = nullptr;
  size_t avail = (ws_size / 4 > off) ? ws_size / 4 - off - 64 : 0;
  size_t needBig = (size_t)11 * kSIZE * 256;           // 5.77M floats
  size_t needStd = (size_t)4 * kSIZE * 512;            // 4.19M floats
  if (avail >= needBig + 16) {
    partK = allocF(needBig);
    S1 = 11; S2 = 4; S3 = 2;
  } else if (avail >= needStd + 16) {
    partK = allocF(needStd);
    S1 = 6; S2 = 4; S3 = 2;
  }

  // z buffers alias `part` (dead after chunkofs/fill)
  ushort_t* zL  = (ushort_t*)part;                       // 16384 x 128
  ushort_t* zD  = zL + (size_t)kNL * kZS;                // 4096 x 128
  ushort_t* zM  = zD + (size_t)kND * kZS;                // 2048 x 128
  ushort_t* zD3 = zM + (size_t)kNM * kZS;                // 4096 x 128
  ushort_t* zM3 = zD3 + (size_t)kND * kZS;               // 2048 x 128

  I6 ndI; const int ndst_[6] = {kND, kNL, kNM, kNL, kNM, kND};
  for (int t = 0; t < 6; ++t) ndI.v[t] = ndst_[t];
  I6 rpo; { int r = 0; for (int t = 0; t < 6; ++t) { rpo.v[t] = r; r += ndst_[t] + 1; } }
  auto dsc = [&](int k) { return degscale + ((size_t)k << 14); };

  // ---- 1) hist (64KB LDS) then prep (4.2KB LDS, high occupancy) ----
  hist_kernel<<<12 * kHB, 256, 0, stream>>>(ep, part);

  PJobs pj; int nj = 0; int totblk = 0;
  auto addCvt = [&](const float* in, ushort_t* out, size_t n) {
    int n4 = (int)(n / 4);
    pj.j[nj] = {in, out, n4, 0, 0, 0, (n4 + 255) / 256}; totblk += pj.j[nj].nblk; ++nj;
  };
  auto addStrided = [&](const float* in, ushort_t* out, size_t n, int log2RowLen4, int stride) {
    int n4 = (int)(n / 4);
    pj.j[nj] = {in, out, n4, log2RowLen4, stride, 2, (n4 + 255) / 256}; totblk += pj.j[nj].nblk; ++nj;
  };
  auto addT = [&](const float* in, ushort_t* out, int K, int N) {
    pj.j[nj] = {in, out, K, N, 0, 1, (N / 32) * (K / 32)}; totblk += pj.j[nj].nblk; ++nj;
  };
  addCvt(h_L, hLb, (size_t)kNL * kFEAT);
  addCvt(h_D, hDb, (size_t)kND * kFEAT);
  addCvt(h_M, hMb, (size_t)kNM * kFEAT);
  addStrided(Adj, xin, (size_t)kSIZE * kITEMS, 10, kXIN);   // rowLen4 = 1024 = 2^10
  addT(W[0] + (size_t)0 * kFEAT * kHID, WLt + (size_t)0 * kFEAT, kFEAT, kHID);
  addT(W[0] + (size_t)2 * kFEAT * kHID, WLt + (size_t)64 * kFEAT, kFEAT, kHID);
  addT(W[0] + (size_t)1 * kFEAT * kHID, WDt + (size_t)0 * kFEAT, kFEAT, kHID);
  addT(W[0] + (size_t)4 * kFEAT * kHID, WDt + (size_t)64 * kFEAT, kFEAT, kHID);
  addT(W[0] + (size_t)3 * kFEAT * kHID, WMt + (size_t)0 * kFEAT, kFEAT, kHID);
  addT(W[0] + (size_t)5 * kFEAT * kHID, WMt + (size_t)64 * kFEAT, kFEAT, kHID);
  addT(W[1] + (size_t)0 * kHID * kHID, WL2t + (size_t)0 * kHID, kHID, kHID);
  addT(W[1] + (size_t)2 * kHID * kHID, WL2t + (size_t)64 * kHID, kHID, kHID);
  addT(W[1] + (size_t)1 * kHID * kHID, WD2t + (size_t)0 * kHID, kHID, kHID);
  addT(W[1] + (size_t)4 * kHID * kHID, WD2t + (size_t)64 * kHID, kHID, kHID);
  addT(W[1] + (size_t)3 * kHID * kHID, WM2t + (size_t)0 * kHID, kHID, kHID);
  addT(W[1] + (size_t)5 * kHID * kHID, WM2t + (size_t)64 * kHID, kHID, kHID);
  addT(W[2] + (size_t)1 * kHID * kOUTF, W3t1, kHID, kOUTF);
  addT(W[2] + (size_t)3 * kHID * kOUTF, W3t3, kHID, kOUTF);
  addT(f1_w, f1t, kXIN, 256);
  addT(f2_w, f2t, 256, 512);
  addT(f3_w, f3t, 512, 1024);
  addT(f4_w, f4t, 1024, kITEMS);
  pj.n = nj;
  prep_kernel<<<totblk, 256, 0, stream>>>(pj);

  // ---- 2) CSR metadata chain + fill ----
  reduce_finalize_kernel<<<12 * 16384 / 256, 256, 0, stream>>>(part, cnts, degscale);
  scan_kernel<<<6, 1024, 0, stream>>>(cnts, rp_all, rpo, ndI);
  chunkofs_kernel<<<6 * 16384 / 256, 256, 0, stream>>>(part, rp_all, rpo, ndI, ofs);
  fill_kernel<<<6 * kHB, 256, 0, stream>>>(ep, ofs, csr);

  // ---- 3) GNN layers 1 & 2 ----
  const ushort_t* curb[3] = {hLb, hDb, hMb};
  for (int layer = 0; layer < 2; ++layer) {
    int K = (layer == 0) ? kFEAT : kHID;
    const ushort_t* WtL = (layer == 0) ? WLt : WL2t;
    const ushort_t* WtD = (layer == 0) ? WDt : WD2t;
    const ushort_t* WtM = (layer == 0) ? WMt : WM2t;
    const float* bl = Bb[layer];
    ZDescs zd;
    zd.d[0] = {curb[0], WtL, zL, dsc(0), dsc(4),  kNL, K};
    zd.d[1] = {curb[1], WtD, zD, dsc(2), dsc(8),  kND, K};
    zd.d[2] = {curb[2], WtM, zM, dsc(6), dsc(10), kNM, K};
    zgemm_batched_kernel<<<dim3(1, kNL / 128, 3), 256, 0, stream>>>(zd);
    if (layer == 0) {
      GDescs gd;
      gd.d[0] = {zD, rp_all + rpo.v[1], csr + (size_t)1 * kE, dsc(3),
                 zM, rp_all + rpo.v[3], csr + (size_t)3 * kE, dsc(7),
                 bl + 1 * kHID, bl + 3 * kHID, aLb, kNL};
      gd.d[1] = {zL, rp_all + rpo.v[0], csr + (size_t)0 * kE, dsc(1),
                 zM + 64, rp_all + rpo.v[5], csr + (size_t)5 * kE, dsc(11),
                 bl + 0 * kHID, bl + 5 * kHID, aDb, kND};
      gd.d[2] = {zL + 64, rp_all + rpo.v[2], csr + (size_t)2 * kE, dsc(5),
                 zD + 64, rp_all + rpo.v[4], csr + (size_t)4 * kE, dsc(9),
                 bl + 2 * kHID, bl + 4 * kHID, aMb, kNM};
      gather_batched_kernel<<<dim3(kNL / 4, 1, 3), 256, 0, stream>>>(gd);
    } else {
      // layer-3 consumes only aDb/aMb -> skip dead aLb gather (70% of work)
      GDescs gd;
      gd.d[0] = {zL, rp_all + rpo.v[0], csr + (size_t)0 * kE, dsc(1),
                 zM + 64, rp_all + rpo.v[5], csr + (size_t)5 * kE, dsc(11),
                 bl + 0 * kHID, bl + 5 * kHID, aDb, kND};
      gd.d[1] = {zL + 64, rp_all + rpo.v[2], csr + (size_t)2 * kE, dsc(5),
                 zD + 64, rp_all + rpo.v[4], csr + (size_t)4 * kE, dsc(9),
                 bl + 2 * kHID, bl + 4 * kHID, aMb, kNM};
      gd.d[2] = gd.d[1];
      gather_batched_kernel<<<dim3(kND / 4, 1, 2), 256, 0, stream>>>(gd);
    }
    curb[0] = aLb; curb[1] = aDb; curb[2] = aMb;
  }

  // ---- 4) layer 3 (types 1: D->L, 3: M->L; rows < 2048) + L1 norm ----
  float* emb  = (float*)d_out;
  float* outx = (float*)d_out + (size_t)kSIZE * kOUTF;
  {
    ZDescs zd;
    zd.d[0] = {curb[1], W3t1, zD3, dsc(2), dsc(2), kND, kHID};
    zd.d[1] = {curb[2], W3t3, zM3, dsc(6), dsc(6), kNM, kHID};
    zd.d[2] = zd.d[1];
    zgemm_batched_kernel<<<dim3(1, kND / 128, 2), 256, 0, stream>>>(zd);
    gather128_l1_kernel<<<kSIZE / 4, 256, 0, stream>>>(
        zD3, rp_all + rpo.v[1], csr + (size_t)1 * kE, dsc(3),
        zM3, rp_all + rpo.v[3], csr + (size_t)3 * kE, dsc(7),
        Bb[2] + 1 * kOUTF, Bb[2] + 3 * kOUTF, emb, xin + kITEMS, kXIN);
  }

  // ---- 5) MLP ----
  if (S1 > 1) {
    gemm_bf16_kernel<<<dim3(2, 16, S1), 256, 0, stream>>>(
        xin, f1t, nullptr, nullptr, 0, kSIZE, 256, kXIN, kXIN,
        nullptr, 0, kXIN / S1, partK);
    int n4 = kSIZE * 256 / 4;
    reducek_kernel<<<(n4 + 255) / 256, 256, 0, stream>>>(
        partK, x1b, 1, n4, S1, 256, f1_b, 1);
  } else {
    gemm_bf16_kernel<<<dim3(2, 16, 1), 256, 0, stream>>>(
        xin, f1t, nullptr, x1b, 1, kSIZE, 256, kXIN, kXIN, f1_b, 1, 0, nullptr);
  }
  if (S2 > 1) {
    gemm_bf16_kernel<<<dim3(4, 16, S2), 256, 0, stream>>>(
        x1b, f2t, nullptr, nullptr, 0, kSIZE, 512, 256, 256,
        nullptr, 0, 256 / S2, partK);
    int n4 = kSIZE * 512 / 4;
    reducek_kernel<<<(n4 + 255) / 256, 256, 0, stream>>>(
        partK, x2b, 1, n4, S2, 512, f2_b, 1);
  } else {
    gemm_bf16_kernel<<<dim3(4, 16, 1), 256, 0, stream>>>(
        x1b, f2t, nullptr, x2b, 1, kSIZE, 512, 256, 256, f2_b, 1, 0, nullptr);
  }
  if (S3 > 1) {
    gemm_bf16_kernel<<<dim3(8, 16, S3), 256, 0, stream>>>(
        x2b, f3t, nullptr, nullptr, 0, kSIZE, 1024, 512, 512,
        nullptr, 0, 512 / S3, partK);
    int n4 = kSIZE * 1024 / 4;
    reducek_kernel<<<(n4 + 255) / 256, 256, 0, stream>>>(
        partK, x3b, 1, n4, S3, 1024, f3_b, 1);
  } else {
    gemm_bf16_kernel<<<dim3(8, 16, 1), 256, 0, stream>>>(
        x2b, f3t, nullptr, x3b, 1, kSIZE, 1024, 512, 512, f3_b, 1, 0, nullptr);
  }
  // f4: m201-schedule 256x128 kernel, fused bias+sigmoid, fp32 out
  gemm256_kernel<<<dim3(kITEMS / 128, kSIZE / 256), 512, 0, stream>>>(
      x3b, f4t, outx, kSIZE, kITEMS, 1024, f4_b);
}

// Round 23
// 251.194 us; speedup vs baseline: 1.2844x; 1.0215x over previous
//
#include <hip/hip_runtime.h>

constexpr int kNL = 16384, kND = 4096, kNM = 2048;
constexpr int kE = 262144;              // 2^18
constexpr int kFEAT = 256, kHID = 64, kOUTF = 128;
constexpr int kITEMS = 4096, kSIZE = 2048;
constexpr int kHB = 16;                 // histogram chunks per index array
constexpr int kZS = 128;                // z row stride (merged 2-type layout)
constexpr int kXIN = kITEMS + kOUTF;    // 4224

typedef unsigned short ushort_t;
typedef unsigned int uint_t;
typedef __attribute__((ext_vector_type(8))) short short8v;
typedef __attribute__((ext_vector_type(4))) float f32x4;
typedef __attribute__((ext_vector_type(4))) uint_t uint4v;
typedef __attribute__((ext_vector_type(2))) uint_t uint2v;
typedef __attribute__((ext_vector_type(4))) int int4v;

struct EdgePtrs { const int* p[12]; };
struct I6 { int v[6]; };

__device__ inline ushort_t f2bf(float f) {
  unsigned u = __builtin_bit_cast(unsigned, f);
  unsigned r = u + 0x7fffu + ((u >> 16) & 1u);
  return (ushort_t)(r >> 16);
}
__device__ inline float bf2f(ushort_t b) {
  unsigned u = ((unsigned)b) << 16;
  return __builtin_bit_cast(float, u);
}
__device__ inline float bf2f_lo(uint_t v) { return __builtin_bit_cast(float, v << 16); }
__device__ inline float bf2f_hi(uint_t v) { return __builtin_bit_cast(float, v & 0xffff0000u); }

// async global->LDS, 16 B per lane (global_load_lds_dwordx4)
__device__ __forceinline__ void gload16(const ushort_t* g, ushort_t* l) {
  __builtin_amdgcn_global_load_lds(
      (const __attribute__((address_space(1))) void*)g,
      (__attribute__((address_space(3))) void*)l, 16, 0, 0);
}

// bijective XCD swizzle (m204)
__device__ __forceinline__ void xcd_swizzle(int& bx, int& by) {
  int gx = gridDim.x, gy = gridDim.y;
  int nwg = gx * gy;
  int orig = by * gx + bx;
  int q = nwg >> 3, r = nwg & 7;
  int xcd = orig & 7, loc = orig >> 3;
  int s = ((xcd < r) ? xcd * (q + 1) : r * (q + 1) + (xcd - r) * q) + loc;
  by = s % gy;
  bx = s / gy;
}

// ===== hist: standalone (64 KB LDS only here), int4 edge loads =============
__global__ __launch_bounds__(256) void hist_kernel(EdgePtrs ep, uint_t* __restrict__ part) {
  __shared__ uint_t bins[16384];
  int k = blockIdx.x >> 4, chunk = blockIdx.x & (kHB - 1);
  uint4v zero = {0, 0, 0, 0};
  for (int i = threadIdx.x; i < 4096; i += 256) ((uint4v*)bins)[i] = zero;
  __syncthreads();
  const int4v* arr = (const int4v*)(ep.p[k] + chunk * (kE / kHB));
  for (int i = threadIdx.x; i < kE / kHB / 4; i += 256) {
    int4v e4 = arr[i];
    atomicAdd(&bins[e4[0]], 1u);
    atomicAdd(&bins[e4[1]], 1u);
    atomicAdd(&bins[e4[2]], 1u);
    atomicAdd(&bins[e4[3]], 1u);
  }
  __syncthreads();
  uint4v* o = (uint4v*)(part + ((size_t)blockIdx.x << 14));
  for (int i = threadIdx.x; i < 4096; i += 256) o[i] = ((uint4v*)bins)[i];
}

// ===== prep: converts/transposes ONLY =====================================
// kind 0: flat convert (A=n4). kind 2: strided convert, B=log2(rowLen4).
// kind 1: 64x64 transpose tile, float4 loads, ushort4 (8B) stores.
struct PJob { const float* in; ushort_t* out; int A; int B; int C; int kind; int nblk; };
struct PJobs { PJob j[24]; int n; };

__global__ __launch_bounds__(256) void prep_kernel(PJobs jobs) {
  __shared__ float t64[64][65];
  int b = blockIdx.x;
  int ji = 0;
  while (ji < jobs.n && b >= jobs.j[ji].nblk) { b -= jobs.j[ji].nblk; ++ji; }
  if (ji >= jobs.n) return;
  PJob jb = jobs.j[ji];
  if (jb.kind == 0) {                       // flat convert, A = n4
    int idx = b * 256 + threadIdx.x;
    if (idx >= jb.A) return;
    float4 v = ((const float4*)jb.in)[idx];
    uint2v pk;
    pk[0] = (uint_t)f2bf(v.x) | ((uint_t)f2bf(v.y) << 16);
    pk[1] = (uint_t)f2bf(v.z) | ((uint_t)f2bf(v.w) << 16);
    *(uint2v*)(jb.out + (size_t)idx * 4) = pk;
  } else if (jb.kind == 2) {                // strided convert: A=n4, B=log2(rowLen4), C=outStride
    int idx = b * 256 + threadIdx.x;
    if (idx >= jb.A) return;
    float4 v = ((const float4*)jb.in)[idx];
    int row = idx >> jb.B, col4 = idx & ((1 << jb.B) - 1);
    uint2v pk;
    pk[0] = (uint_t)f2bf(v.x) | ((uint_t)f2bf(v.y) << 16);
    pk[1] = (uint_t)f2bf(v.z) | ((uint_t)f2bf(v.w) << 16);
    *(uint2v*)(jb.out + (size_t)row * jb.C + (size_t)col4 * 4) = pk;
  } else {                                  // transpose: in [K][N] -> out [N][K]; A=K, B=N (both %64==0)
    int K = jb.A, N = jb.B;
    int tpr = N >> 6;
    int n0 = (b % tpr) * 64, k0 = (b / tpr) * 64;
    int tx = threadIdx.x & 15, ty = threadIdx.x >> 4;   // tx: float4 col group, ty: row
#pragma unroll
    for (int i = 0; i < 64; i += 16) {
      float4 v = *(const float4*)(&jb.in[(size_t)(k0 + ty + i) * N + n0 + 4 * tx]);
      t64[ty + i][4 * tx + 0] = v.x;
      t64[ty + i][4 * tx + 1] = v.y;
      t64[ty + i][4 * tx + 2] = v.z;
      t64[ty + i][4 * tx + 3] = v.w;
    }
    __syncthreads();
#pragma unroll
    for (int i = 0; i < 64; i += 16) {
      int n = n0 + ty + i;
      float a0 = t64[4 * tx + 0][ty + i];
      float a1 = t64[4 * tx + 1][ty + i];
      float a2 = t64[4 * tx + 2][ty + i];
      float a3 = t64[4 * tx + 3][ty + i];
      uint2v pk;
      pk[0] = (uint_t)f2bf(a0) | ((uint_t)f2bf(a1) << 16);
      pk[1] = (uint_t)f2bf(a2) | ((uint_t)f2bf(a3) << 16);
      *(uint2v*)(&jb.out[(size_t)n * K + k0 + 4 * tx]) = pk;
    }
  }
}

// ===== CSR metadata chain (R12-proven: wide grids) =========================
__global__ void reduce_finalize_kernel(const uint_t* __restrict__ part,
                                       uint_t* __restrict__ cnts,
                                       float* __restrict__ degscale) {
  int idx = blockIdx.x * 256 + threadIdx.x;   // grid = 12*16384/256
  int k = idx >> 14, bin = idx & 16383;
  uint_t s = 0;
  for (int c = 0; c < kHB; ++c) s += part[((size_t)(k * kHB + c) << 14) + bin];
  cnts[idx] = s;
  degscale[idx] = rsqrtf((float)max(s, 1u));
}

__global__ __launch_bounds__(1024) void scan_kernel(const uint_t* __restrict__ cnts,
                                                    uint_t* __restrict__ rp_all,
                                                    I6 rpoff, I6 nd) {
  __shared__ uint_t sums[1024];
  int t = blockIdx.x;
  int n = nd.v[t];
  const uint_t* c = cnts + ((size_t)(2 * t + 1) << 14);
  uint_t* rp = rp_all + rpoff.v[t];
  int tid = threadIdx.x;
  int seg = n >> 10;
  uint_t s = 0;
  for (int j = 0; j < seg; ++j) s += c[tid * seg + j];
  sums[tid] = s;
  __syncthreads();
  for (int o = 1; o < 1024; o <<= 1) {
    uint_t v = (tid >= o) ? sums[tid - o] : 0u;
    __syncthreads();
    sums[tid] += v;
    __syncthreads();
  }
  uint_t run = sums[tid] - s;   // exclusive
  for (int j = 0; j < seg; ++j) { rp[tid * seg + j] = run; run += c[tid * seg + j]; }
  if (tid == 1023) rp[n] = run;
}

__global__ void chunkofs_kernel(const uint_t* __restrict__ part,
                                const uint_t* __restrict__ rp_all,
                                I6 rpoff, I6 nd, uint_t* __restrict__ ofs) {
  int idx = blockIdx.x * 256 + threadIdx.x;   // grid = 6*16384/256
  int t = idx >> 14, bin = idx & 16383;
  if (bin >= nd.v[t]) return;
  uint_t run = (rp_all + rpoff.v[t])[bin];
  for (int c = 0; c < kHB; ++c) {
    ofs[((size_t)(t * kHB + c) << 14) + bin] = run;
    run += part[((size_t)((2 * t + 1) * kHB + c) << 14) + bin];
  }
}

__global__ __launch_bounds__(256) void fill_kernel(EdgePtrs ep,
                                                   const uint_t* __restrict__ ofs,
                                                   ushort_t* __restrict__ csr_all) {
  __shared__ uint_t cursor[16384];
  int t = blockIdx.x >> 4, chunk = blockIdx.x & (kHB - 1);
  const uint_t* o = ofs + ((size_t)(t * kHB + chunk) << 14);
  for (int i = threadIdx.x; i < 16384; i += 256) cursor[i] = o[i];
  __syncthreads();
  int base = chunk * (kE / kHB);
  const int4v* srcp = (const int4v*)(ep.p[2 * t] + base);
  const int4v* dstp = (const int4v*)(ep.p[2 * t + 1] + base);
  ushort_t* csr = csr_all + (size_t)t * kE;
  for (int i = threadIdx.x; i < kE / kHB / 4; i += 256) {
    int4v d4 = dstp[i];
    int4v s4 = srcp[i];
#pragma unroll
    for (int j = 0; j < 4; ++j) {
      uint_t pos = atomicAdd(&cursor[d4[j]], 1u);
      csr[pos] = (ushort_t)s4[j];
    }
  }
}

// ===== generic bf16 MFMA GEMM, 128x128 tile, BK=64, 2-buffer (R8) ==========
__global__ __launch_bounds__(256) void gemm_bf16_kernel(
    const ushort_t* __restrict__ A, const ushort_t* __restrict__ Bt,
    const float* __restrict__ Cin, void* __restrict__ out, int outBf16,
    int M, int N, int K, int ldb,
    const float* __restrict__ bias, int act,
    int kChunk, float* __restrict__ partOut) {
  __shared__ ushort_t As[2][8192];   // 2 x 16 KB
  __shared__ ushort_t Bs[2][8192];
  int tid = threadIdx.x;
  int wave = tid >> 6, lane = tid & 63;
  int bx = blockIdx.x, by = blockIdx.y;
  xcd_swizzle(bx, by);
  int brow = by * 128, bcol = bx * 128;
  int kStart = partOut ? blockIdx.z * kChunk : 0;
  int kLen = partOut ? kChunk : K;
  int nsteps = kLen >> 6;              // BK = 64

  int rowBase = tid >> 3;              // 0..31
  int u = (tid & 7) ^ (rowBase & 7);
  const ushort_t* gA = A + (size_t)(brow + rowBase) * K + kStart + u * 8;
  const ushort_t* gB = Bt + (size_t)(bcol + rowBase) * ldb + kStart + u * 8;

  int fr = lane & 15, fq = lane >> 4;
  f32x4 acc[2][8] = {};

#define STAGE_G(buf, koff)                                              \
  do {                                                                  \
    _Pragma("unroll")                                                   \
    for (int j = 0; j < 4; ++j) {                                       \
      gload16(gA + (size_t)j * 32 * K + (koff), &As[buf][j * 2048 + tid * 8]);   \
      gload16(gB + (size_t)j * 32 * ldb + (koff), &Bs[buf][j * 2048 + tid * 8]); \
    }                                                                   \
  } while (0)

  STAGE_G(0, 0);
  int cur = 0;
  for (int i = 0; i < nsteps; ++i) {
    __syncthreads();
    if (i + 1 < nsteps) STAGE_G(cur ^ 1, (i + 1) * 64);
#pragma unroll
    for (int kk = 0; kk < 2; ++kk) {
      short8v af[2], bfr[8];
#pragma unroll
      for (int mi = 0; mi < 2; ++mi) {
        int row = wave * 32 + mi * 16 + fr;
        af[mi] = *(const short8v*)(&As[cur][row * 64 + (((kk * 4 + fq) ^ (row & 7)) * 8)]);
      }
#pragma unroll
      for (int ni = 0; ni < 8; ++ni) {
        int row = ni * 16 + fr;
        bfr[ni] = *(const short8v*)(&Bs[cur][row * 64 + (((kk * 4 + fq) ^ (row & 7)) * 8)]);
      }
#pragma unroll
      for (int mi = 0; mi < 2; ++mi)
#pragma unroll
        for (int ni = 0; ni < 8; ++ni)
          acc[mi][ni] = __builtin_amdgcn_mfma_f32_16x16x32_bf16(af[mi], bfr[ni], acc[mi][ni], 0, 0, 0);
    }
    cur ^= 1;
  }
#undef STAGE_G

  if (partOut) {
    float* o = partOut + (size_t)blockIdx.z * M * N;
#pragma unroll
    for (int mi = 0; mi < 2; ++mi)
#pragma unroll
      for (int ni = 0; ni < 8; ++ni)
#pragma unroll
        for (int r = 0; r < 4; ++r) {
          int row = brow + wave * 32 + mi * 16 + fq * 4 + r;
          int col = bcol + ni * 16 + fr;
          o[(size_t)row * N + col] = acc[mi][ni][r];
        }
    return;
  }
#pragma unroll
  for (int mi = 0; mi < 2; ++mi)
#pragma unroll
    for (int ni = 0; ni < 8; ++ni)
#pragma unroll
      for (int r = 0; r < 4; ++r) {
        int row = brow + wave * 32 + mi * 16 + fq * 4 + r;
        int col = bcol + ni * 16 + fr;
        float v = acc[mi][ni][r];
        if (Cin) v += Cin[(size_t)row * N + col];
        if (bias) v += bias[col];
        if (act == 1) v = fmaxf(v, 0.0f);
        else if (act == 2) v = 1.0f / (1.0f + expf(-v));
        if (outBf16) ((ushort_t*)out)[(size_t)row * N + col] = f2bf(v);
        else ((float*)out)[(size_t)row * N + col] = v;
      }
}

// ===== m201-schedule GEMM for f4: BM=256 BN=128 BK=64, 512 thr, 3-buf ======
__global__ __launch_bounds__(512) void gemm256_kernel(
    const ushort_t* __restrict__ A, const ushort_t* __restrict__ Bt,
    float* __restrict__ out, int M, int N, int K,
    const float* __restrict__ bias) {
  __shared__ ushort_t As[3][16384];   // 3 x 32 KB
  __shared__ ushort_t Bs[3][8192];    // 3 x 16 KB
  int tid = threadIdx.x;
  int wave = tid >> 6, lane = tid & 63;
  int bx = blockIdx.x, by = blockIdx.y;
  xcd_swizzle(bx, by);
  int fr = lane & 15, fq = lane >> 4;
  int wm = wave >> 2, wn = wave & 3;

  int rquot = tid >> 3;                // 0..63
  int uslot = (tid & 7) ^ (rquot & 7); // pre-swizzled global slot
  const ushort_t* gA = A + (size_t)(by * 256 + rquot) * K + uslot * 8;
  const ushort_t* gB = Bt + (size_t)(bx * 128 + rquot) * K + uslot * 8;

  f32x4 acc[8][2] = {};
  int nsteps = K >> 6;

#define SG_A(b_, t_, j_) gload16(gA + (size_t)(j_) * 64 * K + (size_t)(t_) * 64, &As[b_][(j_) * 4096 + tid * 8])
#define SG_B(b_, t_, j_) gload16(gB + (size_t)(j_) * 64 * K + (size_t)(t_) * 64, &Bs[b_][(j_) * 4096 + tid * 8])

  SG_A(0, 0, 0); SG_A(0, 0, 1); SG_A(0, 0, 2); SG_A(0, 0, 3); SG_B(0, 0, 0); SG_B(0, 0, 1);
  SG_A(1, 1, 0); SG_A(1, 1, 1); SG_A(1, 1, 2); SG_A(1, 1, 3); SG_B(1, 1, 0); SG_B(1, 1, 1);
  asm volatile("s_waitcnt vmcnt(6)" ::: "memory");
  __builtin_amdgcn_s_barrier();

  short8v bf[2][2];

#define PHASE(p_)                                                            \
  {                                                                          \
    short8v af[4][2];                                                        \
    _Pragma("unroll")                                                        \
    for (int q = 0; q < 4; ++q) {                                            \
      int row = wm * 128 + (4 * (p_) + q) * 16 + fr;                         \
      int base = row * 64;                                                   \
      af[q][0] = *(const short8v*)(&As[b][base + ((fq ^ (row & 7)) * 8)]);   \
      af[q][1] = *(const short8v*)(&As[b][base + (((4 + fq) ^ (row & 7)) * 8)]); \
    }                                                                        \
    if ((p_) == 0) {                                                         \
      _Pragma("unroll")                                                      \
      for (int q = 0; q < 2; ++q) {                                          \
        int row = wn * 32 + q * 16 + fr;                                     \
        int base = row * 64;                                                 \
        bf[q][0] = *(const short8v*)(&Bs[b][base + ((fq ^ (row & 7)) * 8)]); \
        bf[q][1] = *(const short8v*)(&Bs[b][base + (((4 + fq) ^ (row & 7)) * 8)]); \
      }                                                                      \
      if (doStage) { SG_A(sb, t + 2, 0); SG_A(sb, t + 2, 1); SG_A(sb, t + 2, 2); SG_A(sb, t + 2, 3); } \
    } else {                                                                 \
      if (doStage) { SG_B(sb, t + 2, 0); SG_B(sb, t + 2, 1); }               \
      if (t + 2 < nsteps)      asm volatile("s_waitcnt vmcnt(6)" ::: "memory"); \
      else if (t + 1 < nsteps) asm volatile("s_waitcnt vmcnt(0)" ::: "memory"); \
    }                                                                        \
    __builtin_amdgcn_s_barrier();                                            \
    asm volatile("s_waitcnt lgkmcnt(0)" ::: "memory");                       \
    __builtin_amdgcn_s_setprio(1);                                           \
    _Pragma("unroll")                                                        \
    for (int kk = 0; kk < 2; ++kk)                                           \
      _Pragma("unroll")                                                      \
      for (int q = 0; q < 4; ++q)                                            \
        _Pragma("unroll")                                                    \
        for (int ni = 0; ni < 2; ++ni)                                       \
          acc[4 * (p_) + q][ni] = __builtin_amdgcn_mfma_f32_16x16x32_bf16(af[q][kk], bf[ni][kk], acc[4 * (p_) + q][ni], 0, 0, 0); \
    __builtin_amdgcn_s_setprio(0);                                           \
    __builtin_amdgcn_s_barrier();                                            \
  }

  for (int t = 0; t < nsteps; ++t) {
    int b = t % 3, sb = (t + 2) % 3;
    bool doStage = (t + 2 < nsteps);
    PHASE(0);
    PHASE(1);
  }
#undef PHASE
#undef SG_A
#undef SG_B

#pragma unroll
  for (int mi = 0; mi < 8; ++mi)
#pragma unroll
    for (int ni = 0; ni < 2; ++ni)
#pragma unroll
      for (int r = 0; r < 4; ++r) {
        int row = by * 256 + wm * 128 + mi * 16 + fq * 4 + r;
        int col = bx * 128 + wn * 32 + ni * 16 + fr;
        float v = acc[mi][ni][r] + bias[col];
        out[(size_t)row * N + col] = 1.0f / (1.0f + expf(-v));
      }
}

// ===== batched z GEMM (R16-proven): N=128, BK=64, 2-buffer LDS =============
struct ZDesc { const ushort_t* A; const ushort_t* Bt; ushort_t* out;
               const float* rs0; const float* rs1; int M; int K; };
struct ZDescs { ZDesc d[3]; };

__global__ __launch_bounds__(256) void zgemm_batched_kernel(ZDescs ds) {
  __shared__ ushort_t As[2][8192];
  __shared__ ushort_t Bs[2][8192];
  ZDesc de = ds.d[blockIdx.z];
  int gy = gridDim.y;
  int yq = gy >> 3;
  int ys = (blockIdx.y & 7) * yq + (blockIdx.y >> 3);
  int brow = ys * 128;
  if (brow >= de.M) return;
  int K = de.K;
  int nsteps = K >> 6;
  if (nsteps == 0) nsteps = 1;
  int kkMax = (K >= 64) ? 2 : 1;
  int tid = threadIdx.x;
  int wave = tid >> 6, lane = tid & 63;

  int rowBase = tid >> 3;
  int u = (tid & 7) ^ (rowBase & 7);
  const ushort_t* gA = de.A + (size_t)(brow + rowBase) * K + u * 8;
  const ushort_t* gB = de.Bt + (size_t)rowBase * K + u * 8;

  int fr = lane & 15, fq = lane >> 4;
  f32x4 acc[2][8] = {};

#define STAGE_Z(buf, koff)                                              \
  do {                                                                  \
    _Pragma("unroll")                                                   \
    for (int j = 0; j < 4; ++j) {                                       \
      gload16(gA + (size_t)j * 32 * K + (koff), &As[buf][j * 2048 + tid * 8]); \
      gload16(gB + (size_t)j * 32 * K + (koff), &Bs[buf][j * 2048 + tid * 8]); \
    }                                                                   \
  } while (0)

  STAGE_Z(0, 0);
  int cur = 0;
  for (int i = 0; i < nsteps; ++i) {
    __syncthreads();
    if (i + 1 < nsteps) STAGE_Z(cur ^ 1, (i + 1) * 64);
#pragma unroll
    for (int kk = 0; kk < 2; ++kk) {
      if (kk >= kkMax) break;
      short8v af[2], bfr[8];
#pragma unroll
      for (int mi = 0; mi < 2; ++mi) {
        int row = wave * 32 + mi * 16 + fr;
        af[mi] = *(const short8v*)(&As[cur][row * 64 + (((kk * 4 + fq) ^ (row & 7)) * 8)]);
      }
#pragma unroll
      for (int ni = 0; ni < 8; ++ni) {
        int row = ni * 16 + fr;
        bfr[ni] = *(const short8v*)(&Bs[cur][row * 64 + (((kk * 4 + fq) ^ (row & 7)) * 8)]);
      }
#pragma unroll
      for (int mi = 0; mi < 2; ++mi)
#pragma unroll
        for (int ni = 0; ni < 8; ++ni)
          acc[mi][ni] = __builtin_amdgcn_mfma_f32_16x16x32_bf16(af[mi], bfr[ni], acc[mi][ni], 0, 0, 0);
    }
    cur ^= 1;
  }
#undef STAGE_Z

#pragma unroll
  for (int mi = 0; mi < 2; ++mi)
#pragma unroll
    for (int ni = 0; ni < 8; ++ni) {
      const float* rs = (ni < 4) ? de.rs0 : de.rs1;
#pragma unroll
      for (int r = 0; r < 4; ++r) {
        int row = brow + wave * 32 + mi * 16 + fq * 4 + r;
        int col = ni * 16 + fr;
        de.out[(size_t)row * 128 + col] = f2bf(acc[mi][ni][r] * rs[row]);
      }
    }
}

// ===== batched CSR gather: dwordx4 per edge-slot (u16 indices) =============
struct GDesc { const ushort_t* z0; const uint_t* rp0; const ushort_t* cs0; const float* s0;
               const ushort_t* z1; const uint_t* rp1; const ushort_t* cs1; const float* s1;
               const float* b0; const float* b1; ushort_t* out; int nd; };
struct GDescs { GDesc d[3]; };

__device__ __forceinline__ void acc8(float* __restrict__ a, uint4v v) {
  a[0] += bf2f_lo(v[0]); a[1] += bf2f_hi(v[0]);
  a[2] += bf2f_lo(v[1]); a[3] += bf2f_hi(v[1]);
  a[4] += bf2f_lo(v[2]); a[5] += bf2f_hi(v[2]);
  a[6] += bf2f_lo(v[3]); a[7] += bf2f_hi(v[3]);
}

// width-64 z (stride kZS): 8 edge slots (h=lane>>3), col group c=lane&7
__device__ __forceinline__ void gsum64(const ushort_t* __restrict__ z,
                                       const ushort_t* __restrict__ cs,
                                       uint_t e, uint_t ee, int h, int off,
                                       float* __restrict__ a) {
  for (; e + 16 <= ee; e += 16) {
    uint_t sA = cs[e + h], sB = cs[e + 8 + h];
    uint4v vA = *(const uint4v*)(z + (size_t)sA * kZS + off);
    uint4v vB = *(const uint4v*)(z + (size_t)sB * kZS + off);
    acc8(a, vA); acc8(a, vB);
  }
  for (; e + 8 <= ee; e += 8) {
    uint4v v = *(const uint4v*)(z + (size_t)cs[e + h] * kZS + off);
    acc8(a, v);
  }
  if ((uint_t)h < ee - e) {
    uint4v v = *(const uint4v*)(z + (size_t)cs[e + h] * kZS + off);
    acc8(a, v);
  }
}

__global__ __launch_bounds__(256) void gather_batched_kernel(GDescs ds) {
  GDesc de = ds.d[blockIdx.z];
  int d = blockIdx.x * 4 + (threadIdx.x >> 6);
  if (d >= de.nd) return;
  int lane = threadIdx.x & 63;
  int h = lane >> 3, c = lane & 7;
  int off = 8 * c;
  float a0[8] = {}, a1[8] = {};
  gsum64(de.z0, de.cs0, de.rp0[d], de.rp0[d + 1], h, off, a0);
  gsum64(de.z1, de.cs1, de.rp1[d], de.rp1[d + 1], h, off, a1);
  float s0 = de.s0[d], s1 = de.s1[d];
  float v[8];
#pragma unroll
  for (int j = 0; j < 8; ++j) {
    v[j] = a0[j] * s0 + a1[j] * s1;
    v[j] += __shfl_xor(v[j], 8);
    v[j] += __shfl_xor(v[j], 16);
    v[j] += __shfl_xor(v[j], 32);
  }
  if (h == 0) {
    int c0 = off;
    uint4v pack;
#pragma unroll
    for (int j = 0; j < 4; ++j) {
      float x = v[2 * j] + de.b0[c0 + 2 * j] + de.b1[c0 + 2 * j];
      float y = v[2 * j + 1] + de.b0[c0 + 2 * j + 1] + de.b1[c0 + 2 * j + 1];
      pack[j] = (uint_t)f2bf(x) | ((uint_t)f2bf(y) << 16);
    }
    *(uint4v*)(de.out + (size_t)d * 64 + c0) = pack;
  }
}

// width-128 z (stride 128): 4 edge slots (h=lane>>4), col group c=lane&15
__device__ __forceinline__ void gsum128(const ushort_t* __restrict__ z,
                                        const ushort_t* __restrict__ cs,
                                        uint_t e, uint_t ee, int h, int off,
                                        float* __restrict__ a) {
  for (; e + 8 <= ee; e += 8) {
    uint_t sA = cs[e + h], sB = cs[e + 4 + h];
    uint4v vA = *(const uint4v*)(z + (size_t)sA * 128 + off);
    uint4v vB = *(const uint4v*)(z + (size_t)sB * 128 + off);
    acc8(a, vA); acc8(a, vB);
  }
  for (; e + 4 <= ee; e += 4) {
    uint4v v = *(const uint4v*)(z + (size_t)cs[e + h] * 128 + off);
    acc8(a, v);
  }
  if ((uint_t)h < ee - e) {
    uint4v v = *(const uint4v*)(z + (size_t)cs[e + h] * 128 + off);
    acc8(a, v);
  }
}

__global__ __launch_bounds__(256) void gather128_l1_kernel(
    const ushort_t* __restrict__ zD, const uint_t* __restrict__ rpD, const ushort_t* __restrict__ csD,
    const float* __restrict__ sInD,
    const ushort_t* __restrict__ zM, const uint_t* __restrict__ rpM, const ushort_t* __restrict__ csM,
    const float* __restrict__ sInM,
    const float* __restrict__ bD, const float* __restrict__ bM,
    float* __restrict__ emb, ushort_t* __restrict__ embb, int embStride) {
  int d = blockIdx.x * 4 + (threadIdx.x >> 6);
  int lane = threadIdx.x & 63;
  int h = lane >> 4, c = lane & 15;
  int off = 8 * c;                   // cols [8c, 8c+8)
  float aD[8] = {}, aM[8] = {};
  gsum128(zD, csD, rpD[d], rpD[d + 1], h, off, aD);
  gsum128(zM, csM, rpM[d], rpM[d + 1], h, off, aM);
  float sD = sInD[d], sM = sInM[d];
  float v[8];
#pragma unroll
  for (int j = 0; j < 8; ++j) {
    v[j] = aD[j] * sD + aM[j] * sM + bD[off + j] + bM[off + j];
    v[j] += __shfl_xor(v[j], 16);
    v[j] += __shfl_xor(v[j], 32);
  }
  float a = 0;
#pragma unroll
  for (int j = 0; j < 8; ++j) a += fabsf(v[j]);
#pragma unroll
  for (int o = 8; o > 0; o >>= 1) a += __shfl_xor(a, o);
  float l1 = fmaxf(a, 1e-12f);
  if (h == 0) {
    float e0[8];
#pragma unroll
    for (int j = 0; j < 8; ++j) e0[j] = v[j] / l1;
    float* ep_ = emb + (size_t)d * kOUTF + off;
    *(f32x4*)ep_ = {e0[0], e0[1], e0[2], e0[3]};
    *(f32x4*)(ep_ + 4) = {e0[4], e0[5], e0[6], e0[7]};
    uint4v pack;
#pragma unroll
    for (int j = 0; j < 4; ++j)
      pack[j] = (uint_t)f2bf(e0[2 * j]) | ((uint_t)f2bf(e0[2 * j + 1]) << 16);
    *(uint4v*)(embb + (size_t)d * embStride + off) = pack;
  }
}

// ===== split-K reduce with fused bias/act/bf16-out =========================
__global__ void reducek_kernel(const float* __restrict__ P, void* __restrict__ out,
                               int outBf16, int n4, int S, int N,
                               const float* __restrict__ bias, int act) {
  int idx = blockIdx.x * 256 + threadIdx.x;
  if (idx >= n4) return;
  float4 a = ((const float4*)P)[idx];
  for (int s = 1; s < S; ++s) {
    float4 b = ((const float4*)P)[(size_t)s * n4 + idx];
    a.x += b.x; a.y += b.y; a.z += b.z; a.w += b.w;
  }
  float v[4] = {a.x, a.y, a.z, a.w};
  int c0 = (idx * 4) % N;
#pragma unroll
  for (int j = 0; j < 4; ++j) {
    if (bias) v[j] += bias[c0 + j];
    if (act == 1) v[j] = fmaxf(v[j], 0.0f);
    else if (act == 2) v[j] = 1.0f / (1.0f + expf(-v[j]));
  }
  if (outBf16) {
    ushort_t* o = (ushort_t*)out + (size_t)idx * 4;
    o[0] = f2bf(v[0]); o[1] = f2bf(v[1]); o[2] = f2bf(v[2]); o[3] = f2bf(v[3]);
  } else {
    float4 r = {v[0], v[1], v[2], v[3]};
    ((float4*)out)[idx] = r;
  }
}

extern "C" void kernel_launch(void* const* d_in, const int* in_sizes, int n_in,
                              void* d_out, int out_size, void* d_ws, size_t ws_size,
                              hipStream_t stream) {
  const float* h_L = (const float*)d_in[0];
  const float* h_D = (const float*)d_in[1];
  const float* h_M = (const float*)d_in[2];
  const float* Adj = (const float*)d_in[3];
  EdgePtrs ep;
  for (int i = 0; i < 12; ++i) ep.p[i] = (const int*)d_in[4 + i];
  const float* W[3]  = {(const float*)d_in[16], (const float*)d_in[18], (const float*)d_in[20]};
  const float* Bb[3] = {(const float*)d_in[17], (const float*)d_in[19], (const float*)d_in[21]};
  const float* f1_w = (const float*)d_in[22];
  const float* f1_b = (const float*)d_in[23];
  const float* f2_w = (const float*)d_in[24];
  const float* f2_b = (const float*)d_in[25];
  const float* f3_w = (const float*)d_in[26];
  const float* f3_b = (const float*)d_in[27];
  const float* f4_w = (const float*)d_in[28];
  const float* f4_b = (const float*)d_in[29];

  // ---- workspace layout ----
  float* ws = (float*)d_ws;
  size_t off = 0;
  auto allocF = [&](size_t n) { float* p = ws + off; off += (n + 3) & ~(size_t)3; return p; };
  auto allocU = [&](size_t n) { return (uint_t*)allocF(n); };
  auto allocB = [&](size_t n) { return (ushort_t*)allocF((n + 1) / 2); };

  uint_t* part   = allocU((size_t)12 * kHB * 16384);   // 12.6 MB, reused as z bufs
  uint_t* cnts   = allocU((size_t)12 * 16384);
  float*  degscale = allocF((size_t)12 * 16384);
  uint_t* rp_all = allocU(45062 + 2);
  uint_t* ofs    = allocU((size_t)6 * kHB * 16384);
  ushort_t* csr  = allocB((size_t)6 * kE);            // u16 CSR (src ids < 16384)
  ushort_t* hLb  = allocB((size_t)kNL * kFEAT);
  ushort_t* hDb  = allocB((size_t)kND * kFEAT);
  ushort_t* hMb  = allocB((size_t)kNM * kFEAT);
  ushort_t* xin  = allocB((size_t)kSIZE * kXIN);   // [Adj | emb] bf16, stride 4224
  ushort_t* aLb  = allocB((size_t)kNL * kHID);
  ushort_t* aDb  = allocB((size_t)kND * kHID);
  ushort_t* aMb  = allocB((size_t)kNM * kHID);
  ushort_t* WLt  = allocB((size_t)128 * kFEAT);
  ushort_t* WDt  = allocB((size_t)128 * kFEAT);
  ushort_t* WMt  = allocB((size_t)128 * kFEAT);
  ushort_t* WL2t = allocB((size_t)128 * kHID);
  ushort_t* WD2t = allocB((size_t)128 * kHID);
  ushort_t* WM2t = allocB((size_t)128 * kHID);
  ushort_t* W3t1 = allocB((size_t)kOUTF * kHID);
  ushort_t* W3t3 = allocB((size_t)kOUTF * kHID);
  ushort_t* f1t  = allocB((size_t)256 * kXIN);
  ushort_t* f2t  = allocB((size_t)512 * 256);
  ushort_t* f3t  = allocB((size_t)1024 * 512);
  ushort_t* f4t  = allocB((size_t)kITEMS * 1024);
  ushort_t* x1b  = allocB((size_t)kSIZE * 256);
  ushort_t* x2b  = allocB((size_t)kSIZE * 512);
  ushort_t* x3b  = allocB((size_t)kSIZE * 1024);

  // shared split-K partials: f1 S=11 (5.77M), f2 S=4 (4.19M), f3 S=2 (4.19M)
  int S1 = 1, S2 = 1, S3 = 1;
  float* partK = nullptr;
  size_t avail = (ws_size / 4 > off) ? ws_size / 4 - off - 64 : 0;
  size_t needBig = (size_t)11 * kSIZE * 256;           // 5.77M floats
  size_t needStd = (size_t)4 * kSIZE * 512;            // 4.19M floats
  if (avail >= needBig + 16) {
    partK = allocF(needBig);
    S1 = 11; S2 = 4; S3 = 2;
  } else if (avail >= needStd + 16) {
    partK = allocF(needStd);
    S1 = 6; S2 = 4; S3 = 2;
  }

  // z buffers alias `part` (dead after chunkofs/fill)
  ushort_t* zL  = (ushort_t*)part;                       // 16384 x 128
  ushort_t* zD  = zL + (size_t)kNL * kZS;                // 4096 x 128
  ushort_t* zM  = zD + (size_t)kND * kZS;                // 2048 x 128
  ushort_t* zD3 = zM + (size_t)kNM * kZS;                // 4096 x 128
  ushort_t* zM3 = zD3 + (size_t)kND * kZS;               // 2048 x 128

  I6 ndI; const int ndst_[6] = {kND, kNL, kNM, kNL, kNM, kND};
  for (int t = 0; t < 6; ++t) ndI.v[t] = ndst_[t];
  I6 rpo; { int r = 0; for (int t = 0; t < 6; ++t) { rpo.v[t] = r; r += ndst_[t] + 1; } }
  auto dsc = [&](int k) { return degscale + ((size_t)k << 14); };

  // ---- 1) hist (64KB LDS) then prep (16.6KB LDS) ----
  hist_kernel<<<12 * kHB, 256, 0, stream>>>(ep, part);

  PJobs pj; int nj = 0; int totblk = 0;
  auto addCvt = [&](const float* in, ushort_t* out, size_t n) {
    int n4 = (int)(n / 4);
    pj.j[nj] = {in, out, n4, 0, 0, 0, (n4 + 255) / 256}; totblk += pj.j[nj].nblk; ++nj;
  };
  auto addStrided = [&](const float* in, ushort_t* out, size_t n, int log2RowLen4, int stride) {
    int n4 = (int)(n / 4);
    pj.j[nj] = {in, out, n4, log2RowLen4, stride, 2, (n4 + 255) / 256}; totblk += pj.j[nj].nblk; ++nj;
  };
  auto addT = [&](const float* in, ushort_t* out, int K, int N) {
    pj.j[nj] = {in, out, K, N, 0, 1, (N / 64) * (K / 64)}; totblk += pj.j[nj].nblk; ++nj;
  };
  addCvt(h_L, hLb, (size_t)kNL * kFEAT);
  addCvt(h_D, hDb, (size_t)kND * kFEAT);
  addCvt(h_M, hMb, (size_t)kNM * kFEAT);
  addStrided(Adj, xin, (size_t)kSIZE * kITEMS, 10, kXIN);   // rowLen4 = 1024 = 2^10
  addT(W[0] + (size_t)0 * kFEAT * kHID, WLt + (size_t)0 * kFEAT, kFEAT, kHID);
  addT(W[0] + (size_t)2 * kFEAT * kHID, WLt + (size_t)64 * kFEAT, kFEAT, kHID);
  addT(W[0] + (size_t)1 * kFEAT * kHID, WDt + (size_t)0 * kFEAT, kFEAT, kHID);
  addT(W[0] + (size_t)4 * kFEAT * kHID, WDt + (size_t)64 * kFEAT, kFEAT, kHID);
  addT(W[0] + (size_t)3 * kFEAT * kHID, WMt + (size_t)0 * kFEAT, kFEAT, kHID);
  addT(W[0] + (size_t)5 * kFEAT * kHID, WMt + (size_t)64 * kFEAT, kFEAT, kHID);
  addT(W[1] + (size_t)0 * kHID * kHID, WL2t + (size_t)0 * kHID, kHID, kHID);
  addT(W[1] + (size_t)2 * kHID * kHID, WL2t + (size_t)64 * kHID, kHID, kHID);
  addT(W[1] + (size_t)1 * kHID * kHID, WD2t + (size_t)0 * kHID, kHID, kHID);
  addT(W[1] + (size_t)4 * kHID * kHID, WD2t + (size_t)64 * kHID, kHID, kHID);
  addT(W[1] + (size_t)3 * kHID * kHID, WM2t + (size_t)0 * kHID, kHID, kHID);
  addT(W[1] + (size_t)5 * kHID * kHID, WM2t + (size_t)64 * kHID, kHID, kHID);
  addT(W[2] + (size_t)1 * kHID * kOUTF, W3t1, kHID, kOUTF);
  addT(W[2] + (size_t)3 * kHID * kOUTF, W3t3, kHID, kOUTF);
  addT(f1_w, f1t, kXIN, 256);
  addT(f2_w, f2t, 256, 512);
  addT(f3_w, f3t, 512, 1024);
  addT(f4_w, f4t, 1024, kITEMS);
  pj.n = nj;
  prep_kernel<<<totblk, 256, 0, stream>>>(pj);

  // ---- 2) CSR metadata chain + fill ----
  reduce_finalize_kernel<<<12 * 16384 / 256, 256, 0, stream>>>(part, cnts, degscale);
  scan_kernel<<<6, 1024, 0, stream>>>(cnts, rp_all, rpo, ndI);
  chunkofs_kernel<<<6 * 16384 / 256, 256, 0, stream>>>(part, rp_all, rpo, ndI, ofs);
  fill_kernel<<<6 * kHB, 256, 0, stream>>>(ep, ofs, csr);

  // ---- 3) GNN layers 1 & 2 ----
  const ushort_t* curb[3] = {hLb, hDb, hMb};
  for (int layer = 0; layer < 2; ++layer) {
    int K = (layer == 0) ? kFEAT : kHID;
    const ushort_t* WtL = (layer == 0) ? WLt : WL2t;
    const ushort_t* WtD = (layer == 0) ? WDt : WD2t;
    const ushort_t* WtM = (layer == 0) ? WMt : WM2t;
    const float* bl = Bb[layer];
    ZDescs zd;
    zd.d[0] = {curb[0], WtL, zL, dsc(0), dsc(4),  kNL, K};
    zd.d[1] = {curb[1], WtD, zD, dsc(2), dsc(8),  kND, K};
    zd.d[2] = {curb[2], WtM, zM, dsc(6), dsc(10), kNM, K};
    zgemm_batched_kernel<<<dim3(1, kNL / 128, 3), 256, 0, stream>>>(zd);
    if (layer == 0) {
      GDescs gd;
      gd.d[0] = {zD, rp_all + rpo.v[1], csr + (size_t)1 * kE, dsc(3),
                 zM, rp_all + rpo.v[3], csr + (size_t)3 * kE, dsc(7),
                 bl + 1 * kHID, bl + 3 * kHID, aLb, kNL};
      gd.d[1] = {zL, rp_all + rpo.v[0], csr + (size_t)0 * kE, dsc(1),
                 zM + 64, rp_all + rpo.v[5], csr + (size_t)5 * kE, dsc(11),
                 bl + 0 * kHID, bl + 5 * kHID, aDb, kND};
      gd.d[2] = {zL + 64, rp_all + rpo.v[2], csr + (size_t)2 * kE, dsc(5),
                 zD + 64, rp_all + rpo.v[4], csr + (size_t)4 * kE, dsc(9),
                 bl + 2 * kHID, bl + 4 * kHID, aMb, kNM};
      gather_batched_kernel<<<dim3(kNL / 4, 1, 3), 256, 0, stream>>>(gd);
    } else {
      // layer-3 consumes only aDb/aMb -> skip dead aLb gather (70% of work)
      GDescs gd;
      gd.d[0] = {zL, rp_all + rpo.v[0], csr + (size_t)0 * kE, dsc(1),
                 zM + 64, rp_all + rpo.v[5], csr + (size_t)5 * kE, dsc(11),
                 bl + 0 * kHID, bl + 5 * kHID, aDb, kND};
      gd.d[1] = {zL + 64, rp_all + rpo.v[2], csr + (size_t)2 * kE, dsc(5),
                 zD + 64, rp_all + rpo.v[4], csr + (size_t)4 * kE, dsc(9),
                 bl + 2 * kHID, bl + 4 * kHID, aMb, kNM};
      gd.d[2] = gd.d[1];
      gather_batched_kernel<<<dim3(kND / 4, 1, 2), 256, 0, stream>>>(gd);
    }
    curb[0] = aLb; curb[1] = aDb; curb[2] = aMb;
  }

  // ---- 4) layer 3 (types 1: D->L, 3: M->L; rows < 2048) + L1 norm ----
  float* emb  = (float*)d_out;
  float* outx = (float*)d_out + (size_t)kSIZE * kOUTF;
  {
    ZDescs zd;
    zd.d[0] = {curb[1], W3t1, zD3, dsc(2), dsc(2), kND, kHID};
    zd.d[1] = {curb[2], W3t3, zM3, dsc(6), dsc(6), kNM, kHID};
    zd.d[2] = zd.d[1];
    zgemm_batched_kernel<<<dim3(1, kND / 128, 2), 256, 0, stream>>>(zd);
    gather128_l1_kernel<<<kSIZE / 4, 256, 0, stream>>>(
        zD3, rp_all + rpo.v[1], csr + (size_t)1 * kE, dsc(3),
        zM3, rp_all + rpo.v[3], csr + (size_t)3 * kE, dsc(7),
        Bb[2] + 1 * kOUTF, Bb[2] + 3 * kOUTF, emb, xin + kITEMS, kXIN);
  }

  // ---- 5) MLP ----
  if (S1 > 1) {
    gemm_bf16_kernel<<<dim3(2, 16, S1), 256, 0, stream>>>(
        xin, f1t, nullptr, nullptr, 0, kSIZE, 256, kXIN, kXIN,
        nullptr, 0, kXIN / S1, partK);
    int n4 = kSIZE * 256 / 4;
    reducek_kernel<<<(n4 + 255) / 256, 256, 0, stream>>>(
        partK, x1b, 1, n4, S1, 256, f1_b, 1);
  } else {
    gemm_bf16_kernel<<<dim3(2, 16, 1), 256, 0, stream>>>(
        xin, f1t, nullptr, x1b, 1, kSIZE, 256, kXIN, kXIN, f1_b, 1, 0, nullptr);
  }
  if (S2 > 1) {
    gemm_bf16_kernel<<<dim3(4, 16, S2), 256, 0, stream>>>(
        x1b, f2t, nullptr, nullptr, 0, kSIZE, 512, 256, 256,
        nullptr, 0, 256 / S2, partK);
    int n4 = kSIZE * 512 / 4;
    reducek_kernel<<<(n4 + 255) / 256, 256, 0, stream>>>(
        partK, x2b, 1, n4, S2, 512, f2_b, 1);
  } else {
    gemm_bf16_kernel<<<dim3(4, 16, 1), 256, 0, stream>>>(
        x1b, f2t, nullptr, x2b, 1, kSIZE, 512, 256, 256, f2_b, 1, 0, nullptr);
  }
  if (S3 > 1) {
    gemm_bf16_kernel<<<dim3(8, 16, S3), 256, 0, stream>>>(
        x2b, f3t, nullptr, nullptr, 0, kSIZE, 1024, 512, 512,
        nullptr, 0, 512 / S3, partK);
    int n4 = kSIZE * 1024 / 4;
    reducek_kernel<<<(n4 + 255) / 256, 256, 0, stream>>>(
        partK, x3b, 1, n4, S3, 1024, f3_b, 1);
  } else {
    gemm_bf16_kernel<<<dim3(8, 16, 1), 256, 0, stream>>>(
        x2b, f3t, nullptr, x3b, 1, kSIZE, 1024, 512, 512, f3_b, 1, 0, nullptr);
  }
  // f4: m201-schedule 256x128 kernel, fused bias+sigmoid, fp32 out
  gemm256_kernel<<<dim3(kITEMS / 128, kSIZE / 256), 512, 0, stream>>>(
      x3b, f4t, outx, kSIZE, kITEMS, 1024, f4_b);
}

// Round 24
// 249.625 us; speedup vs baseline: 1.2924x; 1.0063x over previous
//
#include <hip/hip_runtime.h>

constexpr int kNL = 16384, kND = 4096, kNM = 2048;
constexpr int kE = 262144;              // 2^18
constexpr int kFEAT = 256, kHID = 64, kOUTF = 128;
constexpr int kITEMS = 4096, kSIZE = 2048;
constexpr int kHB = 16;                 // histogram chunks per index array
constexpr int kZS = 128;                // z row stride (merged 2-type layout)
constexpr int kXIN = kITEMS + kOUTF;    // 4224

typedef unsigned short ushort_t;
typedef unsigned int uint_t;
typedef __attribute__((ext_vector_type(8))) short short8v;
typedef __attribute__((ext_vector_type(4))) float f32x4;
typedef __attribute__((ext_vector_type(4))) uint_t uint4v;
typedef __attribute__((ext_vector_type(2))) uint_t uint2v;
typedef __attribute__((ext_vector_type(4))) int int4v;

struct EdgePtrs { const int* p[12]; };
struct I6 { int v[6]; };

__device__ inline ushort_t f2bf(float f) {
  unsigned u = __builtin_bit_cast(unsigned, f);
  unsigned r = u + 0x7fffu + ((u >> 16) & 1u);
  return (ushort_t)(r >> 16);
}
__device__ inline float bf2f(ushort_t b) {
  unsigned u = ((unsigned)b) << 16;
  return __builtin_bit_cast(float, u);
}
__device__ inline float bf2f_lo(uint_t v) { return __builtin_bit_cast(float, v << 16); }
__device__ inline float bf2f_hi(uint_t v) { return __builtin_bit_cast(float, v & 0xffff0000u); }

// async global->LDS, 16 B per lane (global_load_lds_dwordx4)
__device__ __forceinline__ void gload16(const ushort_t* g, ushort_t* l) {
  __builtin_amdgcn_global_load_lds(
      (const __attribute__((address_space(1))) void*)g,
      (__attribute__((address_space(3))) void*)l, 16, 0, 0);
}

// bijective XCD swizzle (m204)
__device__ __forceinline__ void xcd_swizzle(int& bx, int& by) {
  int gx = gridDim.x, gy = gridDim.y;
  int nwg = gx * gy;
  int orig = by * gx + bx;
  int q = nwg >> 3, r = nwg & 7;
  int xcd = orig & 7, loc = orig >> 3;
  int s = ((xcd < r) ? xcd * (q + 1) : r * (q + 1) + (xcd - r) * q) + loc;
  by = s % gy;
  bx = s / gy;
}

// ===== hist: standalone (64 KB LDS only here), int4 edge loads =============
__global__ __launch_bounds__(256) void hist_kernel(EdgePtrs ep, uint_t* __restrict__ part) {
  __shared__ uint_t bins[16384];
  int k = blockIdx.x >> 4, chunk = blockIdx.x & (kHB - 1);
  uint4v zero = {0, 0, 0, 0};
  for (int i = threadIdx.x; i < 4096; i += 256) ((uint4v*)bins)[i] = zero;
  __syncthreads();
  const int4v* arr = (const int4v*)(ep.p[k] + chunk * (kE / kHB));
  for (int i = threadIdx.x; i < kE / kHB / 4; i += 256) {
    int4v e4 = arr[i];
    atomicAdd(&bins[e4[0]], 1u);
    atomicAdd(&bins[e4[1]], 1u);
    atomicAdd(&bins[e4[2]], 1u);
    atomicAdd(&bins[e4[3]], 1u);
  }
  __syncthreads();
  uint4v* o = (uint4v*)(part + ((size_t)blockIdx.x << 14));
  for (int i = threadIdx.x; i < 4096; i += 256) o[i] = ((uint4v*)bins)[i];
}

// ===== prep: converts/transposes ONLY =====================================
// kind 0: flat convert (A=n4). kind 2: strided convert, B=log2(rowLen4).
// kind 1: 64x64 transpose tile, float4 loads, ushort4 (8B) stores.
struct PJob { const float* in; ushort_t* out; int A; int B; int C; int kind; int nblk; };
struct PJobs { PJob j[24]; int n; };

__global__ __launch_bounds__(256) void prep_kernel(PJobs jobs) {
  __shared__ float t64[64][65];
  int b = blockIdx.x;
  int ji = 0;
  while (ji < jobs.n && b >= jobs.j[ji].nblk) { b -= jobs.j[ji].nblk; ++ji; }
  if (ji >= jobs.n) return;
  PJob jb = jobs.j[ji];
  if (jb.kind == 0) {                       // flat convert, A = n4
    int idx = b * 256 + threadIdx.x;
    if (idx >= jb.A) return;
    float4 v = ((const float4*)jb.in)[idx];
    uint2v pk;
    pk[0] = (uint_t)f2bf(v.x) | ((uint_t)f2bf(v.y) << 16);
    pk[1] = (uint_t)f2bf(v.z) | ((uint_t)f2bf(v.w) << 16);
    *(uint2v*)(jb.out + (size_t)idx * 4) = pk;
  } else if (jb.kind == 2) {                // strided convert: A=n4, B=log2(rowLen4), C=outStride
    int idx = b * 256 + threadIdx.x;
    if (idx >= jb.A) return;
    float4 v = ((const float4*)jb.in)[idx];
    int row = idx >> jb.B, col4 = idx & ((1 << jb.B) - 1);
    uint2v pk;
    pk[0] = (uint_t)f2bf(v.x) | ((uint_t)f2bf(v.y) << 16);
    pk[1] = (uint_t)f2bf(v.z) | ((uint_t)f2bf(v.w) << 16);
    *(uint2v*)(jb.out + (size_t)row * jb.C + (size_t)col4 * 4) = pk;
  } else {                                  // transpose: in [K][N] -> out [N][K]; A=K, B=N (both %64==0)
    int K = jb.A, N = jb.B;
    int tpr = N >> 6;
    int n0 = (b % tpr) * 64, k0 = (b / tpr) * 64;
    int tx = threadIdx.x & 15, ty = threadIdx.x >> 4;   // tx: float4 col group, ty: row
#pragma unroll
    for (int i = 0; i < 64; i += 16) {
      float4 v = *(const float4*)(&jb.in[(size_t)(k0 + ty + i) * N + n0 + 4 * tx]);
      t64[ty + i][4 * tx + 0] = v.x;
      t64[ty + i][4 * tx + 1] = v.y;
      t64[ty + i][4 * tx + 2] = v.z;
      t64[ty + i][4 * tx + 3] = v.w;
    }
    __syncthreads();
#pragma unroll
    for (int i = 0; i < 64; i += 16) {
      int n = n0 + ty + i;
      float a0 = t64[4 * tx + 0][ty + i];
      float a1 = t64[4 * tx + 1][ty + i];
      float a2 = t64[4 * tx + 2][ty + i];
      float a3 = t64[4 * tx + 3][ty + i];
      uint2v pk;
      pk[0] = (uint_t)f2bf(a0) | ((uint_t)f2bf(a1) << 16);
      pk[1] = (uint_t)f2bf(a2) | ((uint_t)f2bf(a3) << 16);
      *(uint2v*)(&jb.out[(size_t)n * K + k0 + 4 * tx]) = pk;
    }
  }
}

// ===== CSR metadata chain (R12-proven: wide grids) =========================
__global__ void reduce_finalize_kernel(const uint_t* __restrict__ part,
                                       uint_t* __restrict__ cnts,
                                       float* __restrict__ degscale) {
  int idx = blockIdx.x * 256 + threadIdx.x;   // grid = 12*16384/256
  int k = idx >> 14, bin = idx & 16383;
  uint_t s = 0;
  for (int c = 0; c < kHB; ++c) s += part[((size_t)(k * kHB + c) << 14) + bin];
  cnts[idx] = s;
  degscale[idx] = rsqrtf((float)max(s, 1u));
}

__global__ __launch_bounds__(1024) void scan_kernel(const uint_t* __restrict__ cnts,
                                                    uint_t* __restrict__ rp_all,
                                                    I6 rpoff, I6 nd) {
  __shared__ uint_t sums[1024];
  int t = blockIdx.x;
  int n = nd.v[t];
  const uint_t* c = cnts + ((size_t)(2 * t + 1) << 14);
  uint_t* rp = rp_all + rpoff.v[t];
  int tid = threadIdx.x;
  int seg = n >> 10;
  uint_t s = 0;
  for (int j = 0; j < seg; ++j) s += c[tid * seg + j];
  sums[tid] = s;
  __syncthreads();
  for (int o = 1; o < 1024; o <<= 1) {
    uint_t v = (tid >= o) ? sums[tid - o] : 0u;
    __syncthreads();
    sums[tid] += v;
    __syncthreads();
  }
  uint_t run = sums[tid] - s;   // exclusive
  for (int j = 0; j < seg; ++j) { rp[tid * seg + j] = run; run += c[tid * seg + j]; }
  if (tid == 1023) rp[n] = run;
}

__global__ void chunkofs_kernel(const uint_t* __restrict__ part,
                                const uint_t* __restrict__ rp_all,
                                I6 rpoff, I6 nd, uint_t* __restrict__ ofs) {
  int idx = blockIdx.x * 256 + threadIdx.x;   // grid = 6*16384/256
  int t = idx >> 14, bin = idx & 16383;
  if (bin >= nd.v[t]) return;
  uint_t run = (rp_all + rpoff.v[t])[bin];
  for (int c = 0; c < kHB; ++c) {
    ofs[((size_t)(t * kHB + c) << 14) + bin] = run;
    run += part[((size_t)((2 * t + 1) * kHB + c) << 14) + bin];
  }
}

__global__ __launch_bounds__(256) void fill_kernel(EdgePtrs ep,
                                                   const uint_t* __restrict__ ofs,
                                                   ushort_t* __restrict__ csr_all) {
  __shared__ uint_t cursor[16384];
  int t = blockIdx.x >> 4, chunk = blockIdx.x & (kHB - 1);
  const uint_t* o = ofs + ((size_t)(t * kHB + chunk) << 14);
  for (int i = threadIdx.x; i < 16384; i += 256) cursor[i] = o[i];
  __syncthreads();
  int base = chunk * (kE / kHB);
  const int4v* srcp = (const int4v*)(ep.p[2 * t] + base);
  const int4v* dstp = (const int4v*)(ep.p[2 * t + 1] + base);
  ushort_t* csr = csr_all + (size_t)t * kE;
  for (int i = threadIdx.x; i < kE / kHB / 4; i += 256) {
    int4v d4 = dstp[i];
    int4v s4 = srcp[i];
#pragma unroll
    for (int j = 0; j < 4; ++j) {
      uint_t pos = atomicAdd(&cursor[d4[j]], 1u);
      csr[pos] = (ushort_t)s4[j];
    }
  }
}

// ===== generic bf16 MFMA GEMM, 128x128 tile, BK=64, 2-buffer (R8) ==========
__global__ __launch_bounds__(256) void gemm_bf16_kernel(
    const ushort_t* __restrict__ A, const ushort_t* __restrict__ Bt,
    const float* __restrict__ Cin, void* __restrict__ out, int outBf16,
    int M, int N, int K, int ldb,
    const float* __restrict__ bias, int act,
    int kChunk, float* __restrict__ partOut) {
  __shared__ ushort_t As[2][8192];   // 2 x 16 KB
  __shared__ ushort_t Bs[2][8192];
  int tid = threadIdx.x;
  int wave = tid >> 6, lane = tid & 63;
  int bx = blockIdx.x, by = blockIdx.y;
  xcd_swizzle(bx, by);
  int brow = by * 128, bcol = bx * 128;
  int kStart = partOut ? blockIdx.z * kChunk : 0;
  int kLen = partOut ? kChunk : K;
  int nsteps = kLen >> 6;              // BK = 64

  int rowBase = tid >> 3;              // 0..31
  int u = (tid & 7) ^ (rowBase & 7);
  const ushort_t* gA = A + (size_t)(brow + rowBase) * K + kStart + u * 8;
  const ushort_t* gB = Bt + (size_t)(bcol + rowBase) * ldb + kStart + u * 8;

  int fr = lane & 15, fq = lane >> 4;
  f32x4 acc[2][8] = {};

#define STAGE_G(buf, koff)                                              \
  do {                                                                  \
    _Pragma("unroll")                                                   \
    for (int j = 0; j < 4; ++j) {                                       \
      gload16(gA + (size_t)j * 32 * K + (koff), &As[buf][j * 2048 + tid * 8]);   \
      gload16(gB + (size_t)j * 32 * ldb + (koff), &Bs[buf][j * 2048 + tid * 8]); \
    }                                                                   \
  } while (0)

  STAGE_G(0, 0);
  int cur = 0;
  for (int i = 0; i < nsteps; ++i) {
    __syncthreads();
    if (i + 1 < nsteps) STAGE_G(cur ^ 1, (i + 1) * 64);
#pragma unroll
    for (int kk = 0; kk < 2; ++kk) {
      short8v af[2], bfr[8];
#pragma unroll
      for (int mi = 0; mi < 2; ++mi) {
        int row = wave * 32 + mi * 16 + fr;
        af[mi] = *(const short8v*)(&As[cur][row * 64 + (((kk * 4 + fq) ^ (row & 7)) * 8)]);
      }
#pragma unroll
      for (int ni = 0; ni < 8; ++ni) {
        int row = ni * 16 + fr;
        bfr[ni] = *(const short8v*)(&Bs[cur][row * 64 + (((kk * 4 + fq) ^ (row & 7)) * 8)]);
      }
#pragma unroll
      for (int mi = 0; mi < 2; ++mi)
#pragma unroll
        for (int ni = 0; ni < 8; ++ni)
          acc[mi][ni] = __builtin_amdgcn_mfma_f32_16x16x32_bf16(af[mi], bfr[ni], acc[mi][ni], 0, 0, 0);
    }
    cur ^= 1;
  }
#undef STAGE_G

  if (partOut) {
    float* o = partOut + (size_t)blockIdx.z * M * N;
#pragma unroll
    for (int mi = 0; mi < 2; ++mi)
#pragma unroll
      for (int ni = 0; ni < 8; ++ni)
#pragma unroll
        for (int r = 0; r < 4; ++r) {
          int row = brow + wave * 32 + mi * 16 + fq * 4 + r;
          int col = bcol + ni * 16 + fr;
          o[(size_t)row * N + col] = acc[mi][ni][r];
        }
    return;
  }
#pragma unroll
  for (int mi = 0; mi < 2; ++mi)
#pragma unroll
    for (int ni = 0; ni < 8; ++ni)
#pragma unroll
      for (int r = 0; r < 4; ++r) {
        int row = brow + wave * 32 + mi * 16 + fq * 4 + r;
        int col = bcol + ni * 16 + fr;
        float v = acc[mi][ni][r];
        if (Cin) v += Cin[(size_t)row * N + col];
        if (bias) v += bias[col];
        if (act == 1) v = fmaxf(v, 0.0f);
        else if (act == 2) v = 1.0f / (1.0f + expf(-v));
        if (outBf16) ((ushort_t*)out)[(size_t)row * N + col] = f2bf(v);
        else ((float*)out)[(size_t)row * N + col] = v;
      }
}

// ===== m201-schedule GEMM for f4: BM=256 BN=128 BK=64, 512 thr, 3-buf ======
// XCD mapping: each XCD owns an 8bx x 4by rectangle -> per-XCD L2 working
// set = 8 B-panels (2.1MB) + 4 A-panels (2.1MB) = 4.19MB ~= L2 capacity
// (vs 5.2MB with the generic swizzle -> L3 thrash, MfmaUtil 11%).
__global__ __launch_bounds__(512) void gemm256_kernel(
    const ushort_t* __restrict__ A, const ushort_t* __restrict__ Bt,
    float* __restrict__ out, int M, int N, int K,
    const float* __restrict__ bias) {
  __shared__ ushort_t As[3][16384];   // 3 x 32 KB
  __shared__ ushort_t Bs[3][8192];    // 3 x 16 KB
  int tid = threadIdx.x;
  int wave = tid >> 6, lane = tid & 63;
  int bx = blockIdx.x, by = blockIdx.y;
  if (gridDim.x == 32 && gridDim.y == 8) {
    // rect mapping (assumes HW XCD = orig % 8): bijective by construction
    int o = by * 32 + bx;
    int X = o & 7, loc = o >> 3;          // loc in 0..31
    bx = (X & 3) * 8 + (loc & 7);         // 4 rects in x, 8 wide
    by = (X >> 2) * 4 + (loc >> 3);       // 2 rects in y, 4 tall
  } else {
    xcd_swizzle(bx, by);
  }
  int fr = lane & 15, fq = lane >> 4;
  int wm = wave >> 2, wn = wave & 3;

  int rquot = tid >> 3;                // 0..63
  int uslot = (tid & 7) ^ (rquot & 7); // pre-swizzled global slot
  const ushort_t* gA = A + (size_t)(by * 256 + rquot) * K + uslot * 8;
  const ushort_t* gB = Bt + (size_t)(bx * 128 + rquot) * K + uslot * 8;

  f32x4 acc[8][2] = {};
  int nsteps = K >> 6;

#define SG_A(b_, t_, j_) gload16(gA + (size_t)(j_) * 64 * K + (size_t)(t_) * 64, &As[b_][(j_) * 4096 + tid * 8])
#define SG_B(b_, t_, j_) gload16(gB + (size_t)(j_) * 64 * K + (size_t)(t_) * 64, &Bs[b_][(j_) * 4096 + tid * 8])

  SG_A(0, 0, 0); SG_A(0, 0, 1); SG_A(0, 0, 2); SG_A(0, 0, 3); SG_B(0, 0, 0); SG_B(0, 0, 1);
  SG_A(1, 1, 0); SG_A(1, 1, 1); SG_A(1, 1, 2); SG_A(1, 1, 3); SG_B(1, 1, 0); SG_B(1, 1, 1);
  asm volatile("s_waitcnt vmcnt(6)" ::: "memory");
  __builtin_amdgcn_s_barrier();

  short8v bf[2][2];

#define PHASE(p_)                                                            \
  {                                                                          \
    short8v af[4][2];                                                        \
    _Pragma("unroll")                                                        \
    for (int q = 0; q < 4; ++q) {                                            \
      int row = wm * 128 + (4 * (p_) + q) * 16 + fr;                         \
      int base = row * 64;                                                   \
      af[q][0] = *(const short8v*)(&As[b][base + ((fq ^ (row & 7)) * 8)]);   \
      af[q][1] = *(const short8v*)(&As[b][base + (((4 + fq) ^ (row & 7)) * 8)]); \
    }                                                                        \
    if ((p_) == 0) {                                                         \
      _Pragma("unroll")                                                      \
      for (int q = 0; q < 2; ++q) {                                          \
        int row = wn * 32 + q * 16 + fr;                                     \
        int base = row * 64;                                                 \
        bf[q][0] = *(const short8v*)(&Bs[b][base + ((fq ^ (row & 7)) * 8)]); \
        bf[q][1] = *(const short8v*)(&Bs[b][base + (((4 + fq) ^ (row & 7)) * 8)]); \
      }                                                                      \
      if (doStage) { SG_A(sb, t + 2, 0); SG_A(sb, t + 2, 1); SG_A(sb, t + 2, 2); SG_A(sb, t + 2, 3); } \
    } else {                                                                 \
      if (doStage) { SG_B(sb, t + 2, 0); SG_B(sb, t + 2, 1); }               \
      if (t + 2 < nsteps)      asm volatile("s_waitcnt vmcnt(6)" ::: "memory"); \
      else if (t + 1 < nsteps) asm volatile("s_waitcnt vmcnt(0)" ::: "memory"); \
    }                                                                        \
    __builtin_amdgcn_s_barrier();                                            \
    asm volatile("s_waitcnt lgkmcnt(0)" ::: "memory");                       \
    __builtin_amdgcn_s_setprio(1);                                           \
    _Pragma("unroll")                                                        \
    for (int kk = 0; kk < 2; ++kk)                                           \
      _Pragma("unroll")                                                      \
      for (int q = 0; q < 4; ++q)                                            \
        _Pragma("unroll")                                                    \
        for (int ni = 0; ni < 2; ++ni)                                       \
          acc[4 * (p_) + q][ni] = __builtin_amdgcn_mfma_f32_16x16x32_bf16(af[q][kk], bf[ni][kk], acc[4 * (p_) + q][ni], 0, 0, 0); \
    __builtin_amdgcn_s_setprio(0);                                           \
    __builtin_amdgcn_s_barrier();                                            \
  }

  for (int t = 0; t < nsteps; ++t) {
    int b = t % 3, sb = (t + 2) % 3;
    bool doStage = (t + 2 < nsteps);
    PHASE(0);
    PHASE(1);
  }
#undef PHASE
#undef SG_A
#undef SG_B

#pragma unroll
  for (int mi = 0; mi < 8; ++mi)
#pragma unroll
    for (int ni = 0; ni < 2; ++ni)
#pragma unroll
      for (int r = 0; r < 4; ++r) {
        int row = by * 256 + wm * 128 + mi * 16 + fq * 4 + r;
        int col = bx * 128 + wn * 32 + ni * 16 + fr;
        float v = acc[mi][ni][r] + bias[col];
        out[(size_t)row * N + col] = 1.0f / (1.0f + expf(-v));
      }
}

// ===== batched z GEMM (R16-proven): N=128, BK=64, 2-buffer LDS =============
struct ZDesc { const ushort_t* A; const ushort_t* Bt; ushort_t* out;
               const float* rs0; const float* rs1; int M; int K; };
struct ZDescs { ZDesc d[3]; };

__global__ __launch_bounds__(256) void zgemm_batched_kernel(ZDescs ds) {
  __shared__ ushort_t As[2][8192];
  __shared__ ushort_t Bs[2][8192];
  ZDesc de = ds.d[blockIdx.z];
  int gy = gridDim.y;
  int yq = gy >> 3;
  int ys = (blockIdx.y & 7) * yq + (blockIdx.y >> 3);
  int brow = ys * 128;
  if (brow >= de.M) return;
  int K = de.K;
  int nsteps = K >> 6;
  if (nsteps == 0) nsteps = 1;
  int kkMax = (K >= 64) ? 2 : 1;
  int tid = threadIdx.x;
  int wave = tid >> 6, lane = tid & 63;

  int rowBase = tid >> 3;
  int u = (tid & 7) ^ (rowBase & 7);
  const ushort_t* gA = de.A + (size_t)(brow + rowBase) * K + u * 8;
  const ushort_t* gB = de.Bt + (size_t)rowBase * K + u * 8;

  int fr = lane & 15, fq = lane >> 4;
  f32x4 acc[2][8] = {};

#define STAGE_Z(buf, koff)                                              \
  do {                                                                  \
    _Pragma("unroll")                                                   \
    for (int j = 0; j < 4; ++j) {                                       \
      gload16(gA + (size_t)j * 32 * K + (koff), &As[buf][j * 2048 + tid * 8]); \
      gload16(gB + (size_t)j * 32 * K + (koff), &Bs[buf][j * 2048 + tid * 8]); \
    }                                                                   \
  } while (0)

  STAGE_Z(0, 0);
  int cur = 0;
  for (int i = 0; i < nsteps; ++i) {
    __syncthreads();
    if (i + 1 < nsteps) STAGE_Z(cur ^ 1, (i + 1) * 64);
#pragma unroll
    for (int kk = 0; kk < 2; ++kk) {
      if (kk >= kkMax) break;
      short8v af[2], bfr[8];
#pragma unroll
      for (int mi = 0; mi < 2; ++mi) {
        int row = wave * 32 + mi * 16 + fr;
        af[mi] = *(const short8v*)(&As[cur][row * 64 + (((kk * 4 + fq) ^ (row & 7)) * 8)]);
      }
#pragma unroll
      for (int ni = 0; ni < 8; ++ni) {
        int row = ni * 16 + fr;
        bfr[ni] = *(const short8v*)(&Bs[cur][row * 64 + (((kk * 4 + fq) ^ (row & 7)) * 8)]);
      }
#pragma unroll
      for (int mi = 0; mi < 2; ++mi)
#pragma unroll
        for (int ni = 0; ni < 8; ++ni)
          acc[mi][ni] = __builtin_amdgcn_mfma_f32_16x16x32_bf16(af[mi], bfr[ni], acc[mi][ni], 0, 0, 0);
    }
    cur ^= 1;
  }
#undef STAGE_Z

#pragma unroll
  for (int mi = 0; mi < 2; ++mi)
#pragma unroll
    for (int ni = 0; ni < 8; ++ni) {
      const float* rs = (ni < 4) ? de.rs0 : de.rs1;
#pragma unroll
      for (int r = 0; r < 4; ++r) {
        int row = brow + wave * 32 + mi * 16 + fq * 4 + r;
        int col = ni * 16 + fr;
        de.out[(size_t)row * 128 + col] = f2bf(acc[mi][ni][r] * rs[row]);
      }
    }
}

// ===== batched CSR gather: dwordx4 per edge-slot (u16 indices) =============
struct GDesc { const ushort_t* z0; const uint_t* rp0; const ushort_t* cs0; const float* s0;
               const ushort_t* z1; const uint_t* rp1; const ushort_t* cs1; const float* s1;
               const float* b0; const float* b1; ushort_t* out; int nd; };
struct GDescs { GDesc d[3]; };

__device__ __forceinline__ void acc8(float* __restrict__ a, uint4v v) {
  a[0] += bf2f_lo(v[0]); a[1] += bf2f_hi(v[0]);
  a[2] += bf2f_lo(v[1]); a[3] += bf2f_hi(v[1]);
  a[4] += bf2f_lo(v[2]); a[5] += bf2f_hi(v[2]);
  a[6] += bf2f_lo(v[3]); a[7] += bf2f_hi(v[3]);
}

// width-64 z (stride kZS): 8 edge slots (h=lane>>3), col group c=lane&7
__device__ __forceinline__ void gsum64(const ushort_t* __restrict__ z,
                                       const ushort_t* __restrict__ cs,
                                       uint_t e, uint_t ee, int h, int off,
                                       float* __restrict__ a) {
  for (; e + 16 <= ee; e += 16) {
    uint_t sA = cs[e + h], sB = cs[e + 8 + h];
    uint4v vA = *(const uint4v*)(z + (size_t)sA * kZS + off);
    uint4v vB = *(const uint4v*)(z + (size_t)sB * kZS + off);
    acc8(a, vA); acc8(a, vB);
  }
  for (; e + 8 <= ee; e += 8) {
    uint4v v = *(const uint4v*)(z + (size_t)cs[e + h] * kZS + off);
    acc8(a, v);
  }
  if ((uint_t)h < ee - e) {
    uint4v v = *(const uint4v*)(z + (size_t)cs[e + h] * kZS + off);
    acc8(a, v);
  }
}

__global__ __launch_bounds__(256) void gather_batched_kernel(GDescs ds) {
  GDesc de = ds.d[blockIdx.z];
  int d = blockIdx.x * 4 + (threadIdx.x >> 6);
  if (d >= de.nd) return;
  int lane = threadIdx.x & 63;
  int h = lane >> 3, c = lane & 7;
  int off = 8 * c;
  float a0[8] = {}, a1[8] = {};
  gsum64(de.z0, de.cs0, de.rp0[d], de.rp0[d + 1], h, off, a0);
  gsum64(de.z1, de.cs1, de.rp1[d], de.rp1[d + 1], h, off, a1);
  float s0 = de.s0[d], s1 = de.s1[d];
  float v[8];
#pragma unroll
  for (int j = 0; j < 8; ++j) {
    v[j] = a0[j] * s0 + a1[j] * s1;
    v[j] += __shfl_xor(v[j], 8);
    v[j] += __shfl_xor(v[j], 16);
    v[j] += __shfl_xor(v[j], 32);
  }
  if (h == 0) {
    int c0 = off;
    uint4v pack;
#pragma unroll
    for (int j = 0; j < 4; ++j) {
      float x = v[2 * j] + de.b0[c0 + 2 * j] + de.b1[c0 + 2 * j];
      float y = v[2 * j + 1] + de.b0[c0 + 2 * j + 1] + de.b1[c0 + 2 * j + 1];
      pack[j] = (uint_t)f2bf(x) | ((uint_t)f2bf(y) << 16);
    }
    *(uint4v*)(de.out + (size_t)d * 64 + c0) = pack;
  }
}

// width-128 z (stride 128): 4 edge slots (h=lane>>4), col group c=lane&15
__device__ __forceinline__ void gsum128(const ushort_t* __restrict__ z,
                                        const ushort_t* __restrict__ cs,
                                        uint_t e, uint_t ee, int h, int off,
                                        float* __restrict__ a) {
  for (; e + 8 <= ee; e += 8) {
    uint_t sA = cs[e + h], sB = cs[e + 4 + h];
    uint4v vA = *(const uint4v*)(z + (size_t)sA * 128 + off);
    uint4v vB = *(const uint4v*)(z + (size_t)sB * 128 + off);
    acc8(a, vA); acc8(a, vB);
  }
  for (; e + 4 <= ee; e += 4) {
    uint4v v = *(const uint4v*)(z + (size_t)cs[e + h] * 128 + off);
    acc8(a, v);
  }
  if ((uint_t)h < ee - e) {
    uint4v v = *(const uint4v*)(z + (size_t)cs[e + h] * 128 + off);
    acc8(a, v);
  }
}

__global__ __launch_bounds__(256) void gather128_l1_kernel(
    const ushort_t* __restrict__ zD, const uint_t* __restrict__ rpD, const ushort_t* __restrict__ csD,
    const float* __restrict__ sInD,
    const ushort_t* __restrict__ zM, const uint_t* __restrict__ rpM, const ushort_t* __restrict__ csM,
    const float* __restrict__ sInM,
    const float* __restrict__ bD, const float* __restrict__ bM,
    float* __restrict__ emb, ushort_t* __restrict__ embb, int embStride) {
  int d = blockIdx.x * 4 + (threadIdx.x >> 6);
  int lane = threadIdx.x & 63;
  int h = lane >> 4, c = lane & 15;
  int off = 8 * c;                   // cols [8c, 8c+8)
  float aD[8] = {}, aM[8] = {};
  gsum128(zD, csD, rpD[d], rpD[d + 1], h, off, aD);
  gsum128(zM, csM, rpM[d], rpM[d + 1], h, off, aM);
  float sD = sInD[d], sM = sInM[d];
  float v[8];
#pragma unroll
  for (int j = 0; j < 8; ++j) {
    v[j] = aD[j] * sD + aM[j] * sM + bD[off + j] + bM[off + j];
    v[j] += __shfl_xor(v[j], 16);
    v[j] += __shfl_xor(v[j], 32);
  }
  float a = 0;
#pragma unroll
  for (int j = 0; j < 8; ++j) a += fabsf(v[j]);
#pragma unroll
  for (int o = 8; o > 0; o >>= 1) a += __shfl_xor(a, o);
  float l1 = fmaxf(a, 1e-12f);
  if (h == 0) {
    float e0[8];
#pragma unroll
    for (int j = 0; j < 8; ++j) e0[j] = v[j] / l1;
    float* ep_ = emb + (size_t)d * kOUTF + off;
    *(f32x4*)ep_ = {e0[0], e0[1], e0[2], e0[3]};
    *(f32x4*)(ep_ + 4) = {e0[4], e0[5], e0[6], e0[7]};
    uint4v pack;
#pragma unroll
    for (int j = 0; j < 4; ++j)
      pack[j] = (uint_t)f2bf(e0[2 * j]) | ((uint_t)f2bf(e0[2 * j + 1]) << 16);
    *(uint4v*)(embb + (size_t)d * embStride + off) = pack;
  }
}

// ===== split-K reduce with fused bias/act/bf16-out =========================
__global__ void reducek_kernel(const float* __restrict__ P, void* __restrict__ out,
                               int outBf16, int n4, int S, int N,
                               const float* __restrict__ bias, int act) {
  int idx = blockIdx.x * 256 + threadIdx.x;
  if (idx >= n4) return;
  float4 a = ((const float4*)P)[idx];
  for (int s = 1; s < S; ++s) {
    float4 b = ((const float4*)P)[(size_t)s * n4 + idx];
    a.x += b.x; a.y += b.y; a.z += b.z; a.w += b.w;
  }
  float v[4] = {a.x, a.y, a.z, a.w};
  int c0 = (idx * 4) % N;
#pragma unroll
  for (int j = 0; j < 4; ++j) {
    if (bias) v[j] += bias[c0 + j];
    if (act == 1) v[j] = fmaxf(v[j], 0.0f);
    else if (act == 2) v[j] = 1.0f / (1.0f + expf(-v[j]));
  }
  if (outBf16) {
    ushort_t* o = (ushort_t*)out + (size_t)idx * 4;
    o[0] = f2bf(v[0]); o[1] = f2bf(v[1]); o[2] = f2bf(v[2]); o[3] = f2bf(v[3]);
  } else {
    float4 r = {v[0], v[1], v[2], v[3]};
    ((float4*)out)[idx] = r;
  }
}

extern "C" void kernel_launch(void* const* d_in, const int* in_sizes, int n_in,
                              void* d_out, int out_size, void* d_ws, size_t ws_size,
                              hipStream_t stream) {
  const float* h_L = (const float*)d_in[0];
  const float* h_D = (const float*)d_in[1];
  const float* h_M = (const float*)d_in[2];
  const float* Adj = (const float*)d_in[3];
  EdgePtrs ep;
  for (int i = 0; i < 12; ++i) ep.p[i] = (const int*)d_in[4 + i];
  const float* W[3]  = {(const float*)d_in[16], (const float*)d_in[18], (const float*)d_in[20]};
  const float* Bb[3] = {(const float*)d_in[17], (const float*)d_in[19], (const float*)d_in[21]};
  const float* f1_w = (const float*)d_in[22];
  const float* f1_b = (const float*)d_in[23];
  const float* f2_w = (const float*)d_in[24];
  const float* f2_b = (const float*)d_in[25];
  const float* f3_w = (const float*)d_in[26];
  const float* f3_b = (const float*)d_in[27];
  const float* f4_w = (const float*)d_in[28];
  const float* f4_b = (const float*)d_in[29];

  // ---- workspace layout ----
  float* ws = (float*)d_ws;
  size_t off = 0;
  auto allocF = [&](size_t n) { float* p = ws + off; off += (n + 3) & ~(size_t)3; return p; };
  auto allocU = [&](size_t n) { return (uint_t*)allocF(n); };
  auto allocB = [&](size_t n) { return (ushort_t*)allocF((n + 1) / 2); };

  uint_t* part   = allocU((size_t)12 * kHB * 16384);   // 12.6 MB, reused as z bufs
  uint_t* cnts   = allocU((size_t)12 * 16384);
  float*  degscale = allocF((size_t)12 * 16384);
  uint_t* rp_all = allocU(45062 + 2);
  uint_t* ofs    = allocU((size_t)6 * kHB * 16384);
  ushort_t* csr  = allocB((size_t)6 * kE);            // u16 CSR (src ids < 16384)
  ushort_t* hLb  = allocB((size_t)kNL * kFEAT);
  ushort_t* hDb  = allocB((size_t)kND * kFEAT);
  ushort_t* hMb  = allocB((size_t)kNM * kFEAT);
  ushort_t* xin  = allocB((size_t)kSIZE * kXIN);   // [Adj | emb] bf16, stride 4224
  ushort_t* aLb  = allocB((size_t)kNL * kHID);
  ushort_t* aDb  = allocB((size_t)kND * kHID);
  ushort_t* aMb  = allocB((size_t)kNM * kHID);
  ushort_t* WLt  = allocB((size_t)128 * kFEAT);
  ushort_t* WDt  = allocB((size_t)128 * kFEAT);
  ushort_t* WMt  = allocB((size_t)128 * kFEAT);
  ushort_t* WL2t = allocB((size_t)128 * kHID);
  ushort_t* WD2t = allocB((size_t)128 * kHID);
  ushort_t* WM2t = allocB((size_t)128 * kHID);
  ushort_t* W3t1 = allocB((size_t)kOUTF * kHID);
  ushort_t* W3t3 = allocB((size_t)kOUTF * kHID);
  ushort_t* f1t  = allocB((size_t)256 * kXIN);
  ushort_t* f2t  = allocB((size_t)512 * 256);
  ushort_t* f3t  = allocB((size_t)1024 * 512);
  ushort_t* f4t  = allocB((size_t)kITEMS * 1024);
  ushort_t* x1b  = allocB((size_t)kSIZE * 256);
  ushort_t* x2b  = allocB((size_t)kSIZE * 512);
  ushort_t* x3b  = allocB((size_t)kSIZE * 1024);

  // shared split-K partials: f1 S=11 (5.77M), f2 S=4 (4.19M), f3 S=2 (4.19M)
  int S1 = 1, S2 = 1, S3 = 1;
  float* partK = nullptr;
  size_t avail = (ws_size / 4 > off) ? ws_size / 4 - off - 64 : 0;
  size_t needBig = (size_t)11 * kSIZE * 256;           // 5.77M floats
  size_t needStd = (size_t)4 * kSIZE * 512;            // 4.19M floats
  if (avail >= needBig + 16) {
    partK = allocF(needBig);
    S1 = 11; S2 = 4; S3 = 2;
  } else if (avail >= needStd + 16) {
    partK = allocF(needStd);
    S1 = 6; S2 = 4; S3 = 2;
  }

  // z buffers alias `part` (dead after chunkofs/fill)
  ushort_t* zL  = (ushort_t*)part;                       // 16384 x 128
  ushort_t* zD  = zL + (size_t)kNL * kZS;                // 4096 x 128
  ushort_t* zM  = zD + (size_t)kND * kZS;                // 2048 x 128
  ushort_t* zD3 = zM + (size_t)kNM * kZS;                // 4096 x 128
  ushort_t* zM3 = zD3 + (size_t)kND * kZS;               // 2048 x 128

  I6 ndI; const int ndst_[6] = {kND, kNL, kNM, kNL, kNM, kND};
  for (int t = 0; t < 6; ++t) ndI.v[t] = ndst_[t];
  I6 rpo; { int r = 0; for (int t = 0; t < 6; ++t) { rpo.v[t] = r; r += ndst_[t] + 1; } }
  auto dsc = [&](int k) { return degscale + ((size_t)k << 14); };

  // ---- 1) hist (64KB LDS) then prep (16.6KB LDS) ----
  hist_kernel<<<12 * kHB, 256, 0, stream>>>(ep, part);

  PJobs pj; int nj = 0; int totblk = 0;
  auto addCvt = [&](const float* in, ushort_t* out, size_t n) {
    int n4 = (int)(n / 4);
    pj.j[nj] = {in, out, n4, 0, 0, 0, (n4 + 255) / 256}; totblk += pj.j[nj].nblk; ++nj;
  };
  auto addStrided = [&](const float* in, ushort_t* out, size_t n, int log2RowLen4, int stride) {
    int n4 = (int)(n / 4);
    pj.j[nj] = {in, out, n4, log2RowLen4, stride, 2, (n4 + 255) / 256}; totblk += pj.j[nj].nblk; ++nj;
  };
  auto addT = [&](const float* in, ushort_t* out, int K, int N) {
    pj.j[nj] = {in, out, K, N, 0, 1, (N / 64) * (K / 64)}; totblk += pj.j[nj].nblk; ++nj;
  };
  addCvt(h_L, hLb, (size_t)kNL * kFEAT);
  addCvt(h_D, hDb, (size_t)kND * kFEAT);
  addCvt(h_M, hMb, (size_t)kNM * kFEAT);
  addStrided(Adj, xin, (size_t)kSIZE * kITEMS, 10, kXIN);   // rowLen4 = 1024 = 2^10
  addT(W[0] + (size_t)0 * kFEAT * kHID, WLt + (size_t)0 * kFEAT, kFEAT, kHID);
  addT(W[0] + (size_t)2 * kFEAT * kHID, WLt + (size_t)64 * kFEAT, kFEAT, kHID);
  addT(W[0] + (size_t)1 * kFEAT * kHID, WDt + (size_t)0 * kFEAT, kFEAT, kHID);
  addT(W[0] + (size_t)4 * kFEAT * kHID, WDt + (size_t)64 * kFEAT, kFEAT, kHID);
  addT(W[0] + (size_t)3 * kFEAT * kHID, WMt + (size_t)0 * kFEAT, kFEAT, kHID);
  addT(W[0] + (size_t)5 * kFEAT * kHID, WMt + (size_t)64 * kFEAT, kFEAT, kHID);
  addT(W[1] + (size_t)0 * kHID * kHID, WL2t + (size_t)0 * kHID, kHID, kHID);
  addT(W[1] + (size_t)2 * kHID * kHID, WL2t + (size_t)64 * kHID, kHID, kHID);
  addT(W[1] + (size_t)1 * kHID * kHID, WD2t + (size_t)0 * kHID, kHID, kHID);
  addT(W[1] + (size_t)4 * kHID * kHID, WD2t + (size_t)64 * kHID, kHID, kHID);
  addT(W[1] + (size_t)3 * kHID * kHID, WM2t + (size_t)0 * kHID, kHID, kHID);
  addT(W[1] + (size_t)5 * kHID * kHID, WM2t + (size_t)64 * kHID, kHID, kHID);
  addT(W[2] + (size_t)1 * kHID * kOUTF, W3t1, kHID, kOUTF);
  addT(W[2] + (size_t)3 * kHID * kOUTF, W3t3, kHID, kOUTF);
  addT(f1_w, f1t, kXIN, 256);
  addT(f2_w, f2t, 256, 512);
  addT(f3_w, f3t, 512, 1024);
  addT(f4_w, f4t, 1024, kITEMS);
  pj.n = nj;
  prep_kernel<<<totblk, 256, 0, stream>>>(pj);

  // ---- 2) CSR metadata chain + fill ----
  reduce_finalize_kernel<<<12 * 16384 / 256, 256, 0, stream>>>(part, cnts, degscale);
  scan_kernel<<<6, 1024, 0, stream>>>(cnts, rp_all, rpo, ndI);
  chunkofs_kernel<<<6 * 16384 / 256, 256, 0, stream>>>(part, rp_all, rpo, ndI, ofs);
  fill_kernel<<<6 * kHB, 256, 0, stream>>>(ep, ofs, csr);

  // ---- 3) GNN layers 1 & 2 ----
  const ushort_t* curb[3] = {hLb, hDb, hMb};
  for (int layer = 0; layer < 2; ++layer) {
    int K = (layer == 0) ? kFEAT : kHID;
    const ushort_t* WtL = (layer == 0) ? WLt : WL2t;
    const ushort_t* WtD = (layer == 0) ? WDt : WD2t;
    const ushort_t* WtM = (layer == 0) ? WMt : WM2t;
    const float* bl = Bb[layer];
    ZDescs zd;
    zd.d[0] = {curb[0], WtL, zL, dsc(0), dsc(4),  kNL, K};
    zd.d[1] = {curb[1], WtD, zD, dsc(2), dsc(8),  kND, K};
    zd.d[2] = {curb[2], WtM, zM, dsc(6), dsc(10), kNM, K};
    zgemm_batched_kernel<<<dim3(1, kNL / 128, 3), 256, 0, stream>>>(zd);
    if (layer == 0) {
      GDescs gd;
      gd.d[0] = {zD, rp_all + rpo.v[1], csr + (size_t)1 * kE, dsc(3),
                 zM, rp_all + rpo.v[3], csr + (size_t)3 * kE, dsc(7),
                 bl + 1 * kHID, bl + 3 * kHID, aLb, kNL};
      gd.d[1] = {zL, rp_all + rpo.v[0], csr + (size_t)0 * kE, dsc(1),
                 zM + 64, rp_all + rpo.v[5], csr + (size_t)5 * kE, dsc(11),
                 bl + 0 * kHID, bl + 5 * kHID, aDb, kND};
      gd.d[2] = {zL + 64, rp_all + rpo.v[2], csr + (size_t)2 * kE, dsc(5),
                 zD + 64, rp_all + rpo.v[4], csr + (size_t)4 * kE, dsc(9),
                 bl + 2 * kHID, bl + 4 * kHID, aMb, kNM};
      gather_batched_kernel<<<dim3(kNL / 4, 1, 3), 256, 0, stream>>>(gd);
    } else {
      // layer-3 consumes only aDb/aMb -> skip dead aLb gather (70% of work)
      GDescs gd;
      gd.d[0] = {zL, rp_all + rpo.v[0], csr + (size_t)0 * kE, dsc(1),
                 zM + 64, rp_all + rpo.v[5], csr + (size_t)5 * kE, dsc(11),
                 bl + 0 * kHID, bl + 5 * kHID, aDb, kND};
      gd.d[1] = {zL + 64, rp_all + rpo.v[2], csr + (size_t)2 * kE, dsc(5),
                 zD + 64, rp_all + rpo.v[4], csr + (size_t)4 * kE, dsc(9),
                 bl + 2 * kHID, bl + 4 * kHID, aMb, kNM};
      gd.d[2] = gd.d[1];
      gather_batched_kernel<<<dim3(kND / 4, 1, 2), 256, 0, stream>>>(gd);
    }
    curb[0] = aLb; curb[1] = aDb; curb[2] = aMb;
  }

  // ---- 4) layer 3 (types 1: D->L, 3: M->L; rows < 2048) + L1 norm ----
  float* emb  = (float*)d_out;
  float* outx = (float*)d_out + (size_t)kSIZE * kOUTF;
  {
    ZDescs zd;
    zd.d[0] = {curb[1], W3t1, zD3, dsc(2), dsc(2), kND, kHID};
    zd.d[1] = {curb[2], W3t3, zM3, dsc(6), dsc(6), kNM, kHID};
    zd.d[2] = zd.d[1];
    zgemm_batched_kernel<<<dim3(1, kND / 128, 2), 256, 0, stream>>>(zd);
    gather128_l1_kernel<<<kSIZE / 4, 256, 0, stream>>>(
        zD3, rp_all + rpo.v[1], csr + (size_t)1 * kE, dsc(3),
        zM3, rp_all + rpo.v[3], csr + (size_t)3 * kE, dsc(7),
        Bb[2] + 1 * kOUTF, Bb[2] + 3 * kOUTF, emb, xin + kITEMS, kXIN);
  }

  // ---- 5) MLP ----
  if (S1 > 1) {
    gemm_bf16_kernel<<<dim3(2, 16, S1), 256, 0, stream>>>(
        xin, f1t, nullptr, nullptr, 0, kSIZE, 256, kXIN, kXIN,
        nullptr, 0, kXIN / S1, partK);
    int n4 = kSIZE * 256 / 4;
    reducek_kernel<<<(n4 + 255) / 256, 256, 0, stream>>>(
        partK, x1b, 1, n4, S1, 256, f1_b, 1);
  } else {
    gemm_bf16_kernel<<<dim3(2, 16, 1), 256, 0, stream>>>(
        xin, f1t, nullptr, x1b, 1, kSIZE, 256, kXIN, kXIN, f1_b, 1, 0, nullptr);
  }
  if (S2 > 1) {
    gemm_bf16_kernel<<<dim3(4, 16, S2), 256, 0, stream>>>(
        x1b, f2t, nullptr, nullptr, 0, kSIZE, 512, 256, 256,
        nullptr, 0, 256 / S2, partK);
    int n4 = kSIZE * 512 / 4;
    reducek_kernel<<<(n4 + 255) / 256, 256, 0, stream>>>(
        partK, x2b, 1, n4, S2, 512, f2_b, 1);
  } else {
    gemm_bf16_kernel<<<dim3(4, 16, 1), 256, 0, stream>>>(
        x1b, f2t, nullptr, x2b, 1, kSIZE, 512, 256, 256, f2_b, 1, 0, nullptr);
  }
  if (S3 > 1) {
    gemm_bf16_kernel<<<dim3(8, 16, S3), 256, 0, stream>>>(
        x2b, f3t, nullptr, nullptr, 0, kSIZE, 1024, 512, 512,
        nullptr, 0, 512 / S3, partK);
    int n4 = kSIZE * 1024 / 4;
    reducek_kernel<<<(n4 + 255) / 256, 256, 0, stream>>>(
        partK, x3b, 1, n4, S3, 1024, f3_b, 1);
  } else {
    gemm_bf16_kernel<<<dim3(8, 16, 1), 256, 0, stream>>>(
        x2b, f3t, nullptr, x3b, 1, kSIZE, 1024, 512, 512, f3_b, 1, 0, nullptr);
  }
  // f4: m201-schedule 256x128 kernel, fused bias+sigmoid, fp32 out
  gemm256_kernel<<<dim3(kITEMS / 128, kSIZE / 256), 512, 0, stream>>>(
      x3b, f4t, outx, kSIZE, kITEMS, 1024, f4_b);
}